// Round 1
// 796.717 us; speedup vs baseline: 1.0840x; 1.0840x over previous
//
#include <hip/hip_runtime.h>
#include <hip/hip_bf16.h>

__device__ __forceinline__ float sigf(float x){ return 1.f/(1.f+__expf(-x)); }

#define ALPHA 0.2f
#define NEGV  -9e15f

// N=256 nodes, S=64 sensors, W=256 window, H=32 hidden. All fp32.

// ---- k_mask: pack adjacency fp32 (0/1) -> bitmask via wave ballot ----
__global__ __launch_bounds__(256) void k_mask(const float* __restrict__ src,
                                              unsigned* __restrict__ dst, int nelem){
  const int stride = gridDim.x * blockDim.x;
  const int lane = threadIdx.x & 63;
  for (int e = blockIdx.x*blockDim.x + threadIdx.x; e < nelem; e += stride){
    unsigned long long m = __ballot(src[e] > 0.f);
    if (lane == 0)       dst[e >> 5] = (unsigned)m;
    else if (lane == 32) dst[e >> 5] = (unsigned)(m >> 32);
  }
}

// ---- k3: Wh_T (transposed store) + Tf1/Tf2 partials. grid 512 = n*2 + c-half ----
__global__ __launch_bounds__(256) void k3_wht(const float* __restrict__ x,
                                              const float* __restrict__ TW,
                                              const float* __restrict__ Ta,
                                              float* __restrict__ WhTt,
                                              float* __restrict__ Tf1p,
                                              float* __restrict__ Tf2p){
  const int n = blockIdx.x >> 1, ch = blockIdx.x & 1, c0 = ch*32;
  const int tid = threadIdx.x;
  __shared__ float Wm[64][36];
  __shared__ float as1[32], as2[32];
  for (int idx = tid; idx < 2048; idx += 256){
    int k = idx >> 5, cc = idx & 31;
    Wm[k][cc] = TW[n*4096 + k*64 + c0 + cc];
  }
  if (tid < 32){ as1[tid] = Ta[n*128 + c0 + tid]; as2[tid] = Ta[n*128 + 64 + c0 + tid]; }
  __syncthreads();
  const int i = tid;
  const float* xn = x + n*16384;
  float acc[32];
#pragma unroll
  for (int c = 0; c < 32; ++c) acc[c] = 0.f;
#pragma unroll 2
  for (int k = 0; k < 64; ++k){
    float xv = xn[k*256 + i];                  // coalesced
    const float* wr = &Wm[k][0];               // broadcast b128
#pragma unroll
    for (int c = 0; c < 32; ++c) acc[c] = fmaf(xv, wr[c], acc[c]);
  }
  float f1 = 0.f, f2 = 0.f;
#pragma unroll
  for (int c = 0; c < 32; ++c){ f1 = fmaf(acc[c], as1[c], f1); f2 = fmaf(acc[c], as2[c], f2); }
  Tf1p[ch*65536 + n*256 + i] = f1;
  Tf2p[ch*65536 + n*256 + i] = f2;
  float* o = WhTt + n*16384;
#pragma unroll
  for (int c = 0; c < 32; ++c) o[(c0+c)*256 + i] = acc[c];
}

// ---- k4: time-GAT attention. grid 512 = n*2 + c-half, thread = window row i ----
__global__ __launch_bounds__(256) void k4_tat(const float* __restrict__ WhTt,
                                              const float* __restrict__ Tf1p,
                                              const float* __restrict__ Tf2p,
                                              const unsigned* __restrict__ maskT,
                                              float* __restrict__ TatT){
  const int n = blockIdx.x >> 1, ch = blockIdx.x & 1, c0 = ch*32;
  const int i = threadIdx.x;
  __shared__ float f2s[256];
  __shared__ float wt[64][36];
  const float f1 = Tf1p[n*256 + i] + Tf1p[65536 + n*256 + i];
  f2s[i] = Tf2p[n*256 + i] + Tf2p[65536 + n*256 + i];
  unsigned mw[8];
#pragma unroll
  for (int w = 0; w < 8; ++w) mw[w] = maskT[n*2048 + i*8 + w];
  __syncthreads();
  float m = -INFINITY;
  for (int w = 0; w < 8; ++w){
    const unsigned mk = mw[w];
#pragma unroll
    for (int bb = 0; bb < 32; ++bb){
      float e = f1 + f2s[(w<<5)+bb]; e = (e > 0.f) ? e : ALPHA*e;
      e = ((mk >> bb) & 1u) ? e : NEGV;
      m = fmaxf(m, e);
    }
  }
  float s = 0.f;
  for (int w = 0; w < 8; ++w){
    const unsigned mk = mw[w];
#pragma unroll
    for (int bb = 0; bb < 32; ++bb){
      float e = f1 + f2s[(w<<5)+bb]; e = (e > 0.f) ? e : ALPHA*e;
      e = ((mk >> bb) & 1u) ? e : NEGV;
      s += __expf(e - m);
    }
  }
  const float inv = 1.f / s;
  float acc[32];
#pragma unroll
  for (int c = 0; c < 32; ++c) acc[c] = 0.f;
  for (int jt = 0; jt < 4; ++jt){
    __syncthreads();
    for (int idx = i; idx < 2048; idx += 256){
      int cc = idx >> 6, jj = idx & 63;
      wt[jj][cc] = WhTt[n*16384 + (c0+cc)*256 + (jt<<6) + jj];   // coalesced
    }
    __syncthreads();
    for (int jj = 0; jj < 64; ++jj){
      const int j = (jt<<6) + jj;
      float e = f1 + f2s[j]; e = (e > 0.f) ? e : ALPHA*e;
      e = ((mw[j>>5] >> (j & 31)) & 1u) ? e : NEGV;
      const float p = __expf(e - m) * inv;
      const float* wr = &wt[jj][0];            // broadcast b128
#pragma unroll
      for (int c = 0; c < 32; ++c) acc[c] = fmaf(p, wr[c], acc[c]);
    }
  }
  float* o = TatT + n*16384;
#pragma unroll
  for (int c = 0; c < 32; ++c) o[(c0+c)*256 + i] = acc[c];
}

// ---- k1: Wh_F = x @ Fatt_W. grid 256, block 512 (two k-halves, LDS reduce) ----
__global__ __launch_bounds__(512) void k1_whf(const float* __restrict__ x,
                                              const float* __restrict__ FW,
                                              float* __restrict__ WhF){
  const int n = blockIdx.x, tid = threadIdx.x;
  __shared__ float xt[256][64];                // 64 KB; rotated layout (bank-friendly)
  const float* xn = x + n*16384;
  for (int idx = tid; idx < 16384; idx += 512){
    int i = idx >> 8, k = idx & 255;
    xt[k][(i + (k & 60)) & 63] = xn[idx];      // coalesced read
  }
  __syncthreads();
  const int c = tid & 255, kg = tid >> 8;
  const float* Wn = FW + (size_t)n*65536;
  float acc[64];
#pragma unroll
  for (int i = 0; i < 64; ++i) acc[i] = 0.f;
  const int kbeg = kg*128, kend = kbeg + 128;
#pragma unroll 2
  for (int k = kbeg; k < kend; ++k){
    float w = Wn[k*256 + c];                   // coalesced
    const float4* xr = (const float4*)&xt[k][0];
    const int r4 = (k >> 2) & 15;
#pragma unroll
    for (int g = 0; g < 16; ++g){
      float4 v = xr[(g + r4) & 15];            // broadcast b128, uniform rotated index
      acc[4*g+0] = fmaf(v.x, w, acc[4*g+0]);
      acc[4*g+1] = fmaf(v.y, w, acc[4*g+1]);
      acc[4*g+2] = fmaf(v.z, w, acc[4*g+2]);
      acc[4*g+3] = fmaf(v.w, w, acc[4*g+3]);
    }
  }
  __syncthreads();
  float* buf = &xt[0][0];                      // reuse LDS as 64x256 reduce buffer
  if (kg == 1){
#pragma unroll
    for (int i = 0; i < 64; ++i) buf[i*256 + c] = acc[i];
  }
  __syncthreads();
  if (kg == 0){
    float* o = WhF + n*16384;
#pragma unroll
    for (int i = 0; i < 64; ++i) o[i*256 + c] = acc[i] + buf[i*256 + c];
  }
}

// ---- k2: feature-GAT softmax + Fat = att @ Wh. grid 256, block 512 (i-split) ----
__global__ __launch_bounds__(512) void k2_fat(const float* __restrict__ WhF,
                                              const float* __restrict__ Fa,
                                              const float* __restrict__ Fadj,
                                              float* __restrict__ Fat){
  const int n = blockIdx.x, tid = threadIdx.x;
  __shared__ float attT[64][68];               // attT[j][i]
  __shared__ float f1s[64], f2s[64];
  __shared__ float part[64][8][2];
  const float* Wh = WhF + n*16384;
  { // f1/f2: thread (i=tid>>3, q=tid&7) partial over 32 cols
    int i = tid >> 3, q = tid & 7;
    const float* an = Fa + n*512;
    float p1 = 0.f, p2 = 0.f;
    for (int cc = 0; cc < 32; ++cc){
      int c2 = q*32 + cc;
      float w = Wh[i*256 + c2];
      p1 = fmaf(w, an[c2], p1);
      p2 = fmaf(w, an[256 + c2], p2);
    }
    part[i][q][0] = p1; part[i][q][1] = p2;
  }
  __syncthreads();
  if (tid < 64){
    float s1 = 0.f, s2 = 0.f;
#pragma unroll
    for (int q = 0; q < 8; ++q){ s1 += part[tid][q][0]; s2 += part[tid][q][1]; }
    f1s[tid] = s1; f2s[tid] = s2;
  }
  __syncthreads();
  if (tid < 64){                               // masked softmax row -> attT column
    const int r = tid;
    const float f1 = f1s[r];
    const float* adjr = Fadj + n*4096 + r*64;
    unsigned m0 = 0, m1 = 0;
#pragma unroll
    for (int j = 0; j < 32; ++j) if (adjr[j] > 0.f) m0 |= (1u << j);
#pragma unroll
    for (int j = 0; j < 32; ++j) if (adjr[32+j] > 0.f) m1 |= (1u << j);
    float m = -INFINITY;
#pragma unroll
    for (int j = 0; j < 64; ++j){
      float e = f1 + f2s[j]; e = (e > 0.f) ? e : ALPHA*e;
      unsigned bit = (j < 32) ? ((m0 >> j) & 1u) : ((m1 >> (j-32)) & 1u);
      e = bit ? e : NEGV;
      m = fmaxf(m, e);
    }
    float s = 0.f;
#pragma unroll
    for (int j = 0; j < 64; ++j){
      float e = f1 + f2s[j]; e = (e > 0.f) ? e : ALPHA*e;
      unsigned bit = (j < 32) ? ((m0 >> j) & 1u) : ((m1 >> (j-32)) & 1u);
      e = bit ? e : NEGV;
      s += __expf(e - m);
    }
    const float inv = 1.f / s;
#pragma unroll
    for (int j = 0; j < 64; ++j){
      float e = f1 + f2s[j]; e = (e > 0.f) ? e : ALPHA*e;
      unsigned bit = (j < 32) ? ((m0 >> j) & 1u) : ((m1 >> (j-32)) & 1u);
      e = bit ? e : NEGV;
      attT[j][r] = __expf(e - m) * inv;
    }
  }
  __syncthreads();
  const int c = tid & 255, ih = tid >> 8;      // ih: 32-row half of output
  float acc[32];
#pragma unroll
  for (int i = 0; i < 32; ++i) acc[i] = 0.f;
#pragma unroll 2
  for (int j = 0; j < 64; ++j){
    float w = Wh[j*256 + c];                   // coalesced, L2-hot
    const float* ar = &attT[j][ih*32];         // broadcast b128 (16B-aligned)
#pragma unroll
    for (int i = 0; i < 32; ++i) acc[i] = fmaf(ar[i], w, acc[i]);
  }
  float* o = Fat + n*16384;
#pragma unroll
  for (int i = 0; i < 32; ++i) o[(ih*32 + i)*256 + c] = acc[i];
}

// ---- k5: partial Gi0 = cat_seg @ Wih0_seg^T. grid 768 = s*256 + n ----
// s=0: Fat (k 0..255), s=1: TatT (k 256..511), s=2: x (k 512..767).
// Double-buffered global_load_lds staging (counted vmcnt(5), raw barriers),
// source-side XOR swizzle on the cat tile so ds_read_b128 column reads are
// bank-conflict-free. Thread = (a: t-pair, b: 12-gate group), acc 12x2.
__device__ __forceinline__ void gl2lds16(const float* g, float* l){
  __builtin_amdgcn_global_load_lds(
      (const __attribute__((address_space(1))) void*)g,
      (__attribute__((address_space(3))) void*)l, 16, 0, 0);
}

__global__ __launch_bounds__(256) void k5_gi0(const float* __restrict__ Fat,
                                              const float* __restrict__ TatT,
                                              const float* __restrict__ x,
                                              const float* __restrict__ Wih0,
                                              float* __restrict__ P0,
                                              float* __restrict__ P1,
                                              float* __restrict__ P2){
  const int n = blockIdx.x & 255, s = blockIdx.x >> 8;
  const int tid = threadIdx.x;
  const int l = tid & 63, w = tid >> 6;        // lane, wave
  const int a = tid & 31, b = tid >> 5;        // t-pair lane, gate group (0..7)
  __shared__ float cl[2][2048];                // cat tile [64 t][32 k], dbuf, 16 KB
  __shared__ float wl[2][3072];                // W tile  [96 g][32 k], dbuf, 24 KB
  const float* src = (s == 0) ? (Fat + n*16384)
                   : (s == 1) ? (TatT + n*16384)
                              : (x + n*16384);
  const float* Wseg = Wih0 + (size_t)n*73728 + s*256;
  // staging lane mapping: each wave stages 2 cat chunks + 3 W chunks (1 KB each)
  const int lr = l >> 3, lc = l & 7, sc = lc ^ lr;       // sc: swizzled cat col4
  const float* cg0 = src + (16*w + lr)*256 + sc*4;       // cat rows 16w..16w+7
  const float* cg1 = cg0 + 8*256;                        // cat rows +8
  const float* wg0 = Wseg + (size_t)(24*w + lr)*768 + lc*4;  // W rows 24w..+7
  const float* wg1 = wg0 + (size_t)8*768;
  const float* wg2 = wg0 + (size_t)16*768;

#define K5_STAGE(BF, K0) do {                       \
    gl2lds16(cg0 + (K0), &cl[BF][512*w]);           \
    gl2lds16(cg1 + (K0), &cl[BF][512*w + 256]);     \
    gl2lds16(wg0 + (K0), &wl[BF][768*w]);           \
    gl2lds16(wg1 + (K0), &wl[BF][768*w + 256]);     \
    gl2lds16(wg2 + (K0), &wl[BF][768*w + 512]);     \
  } while (0)

  float acc[12][2];
#pragma unroll
  for (int gi = 0; gi < 12; ++gi){ acc[gi][0] = 0.f; acc[gi][1] = 0.f; }

  int bf = 0;
  K5_STAGE(0, 0);
  const int ax4 = (a & 7) << 2;
#pragma unroll 1
  for (int kt = 0; kt < 8; ++kt){
    if (kt < 7){
      K5_STAGE(bf ^ 1, (kt + 1) * 32);
      asm volatile("s_waitcnt vmcnt(5)" ::: "memory");  // current tile landed
    } else {
      asm volatile("s_waitcnt vmcnt(0)" ::: "memory");
    }
    __builtin_amdgcn_s_barrier();
    const float* clb  = &cl[bf][a*32];
    const float* clb2 = &cl[bf][(a+32)*32];
    const float* wlb  = &wl[bf][b*384];
#pragma unroll
    for (int k4 = 0; k4 < 8; ++k4){
      const int j4 = (k4 << 2) ^ ax4;                   // swizzled read col
      const float4 c0 = *(const float4*)&clb[j4];
      const float4 c1 = *(const float4*)&clb2[j4];
#pragma unroll
      for (int gi = 0; gi < 12; ++gi){
        const float4 wv = *(const float4*)&wlb[gi*32 + (k4 << 2)];
        float a0 = acc[gi][0], a1 = acc[gi][1];
        a0 = fmaf(wv.x, c0.x, a0); a1 = fmaf(wv.x, c1.x, a1);
        a0 = fmaf(wv.y, c0.y, a0); a1 = fmaf(wv.y, c1.y, a1);
        a0 = fmaf(wv.z, c0.z, a0); a1 = fmaf(wv.z, c1.z, a1);
        a0 = fmaf(wv.w, c0.w, a0); a1 = fmaf(wv.w, c1.w, a1);
        acc[gi][0] = a0; acc[gi][1] = a1;
      }
    }
    __builtin_amdgcn_s_barrier();
    bf ^= 1;
  }
#undef K5_STAGE
  // partial output [t][96]; overwrites own (dead, only-reader) input region
  float* o = (s == 0) ? (P0 + n*16384)
           : (s == 1) ? (P1 + n*16384)
                      : (P2 + n*8192);
#pragma unroll
  for (int q = 0; q < 3; ++q){
    *(float4*)&o[a*96 + b*12 + q*4] =
        make_float4(acc[4*q][0], acc[4*q+1][0], acc[4*q+2][0], acc[4*q+3][0]);
    *(float4*)&o[(a+32)*96 + b*12 + q*4] =
        make_float4(acc[4*q][1], acc[4*q+1][1], acc[4*q+2][1], acc[4*q+3][1]);
  }
}

// ---- k6: 2-layer GRU (64 steps), spill-free distributed-register design ----
// One wave per node. Sums the 3 k5 partials during the (latency-hidden)
// per-step prefetch. Lane l = (g2 = l&31, hh = l>>5).
__global__ __launch_bounds__(64) void k6_gru(const float* __restrict__ G0,
                                             const float* __restrict__ G1,
                                             const float* __restrict__ G2,
                                             const float* __restrict__ Hpre,
                                             const float* __restrict__ Whh0,
                                             const float* __restrict__ bih0,
                                             const float* __restrict__ bhh0,
                                             const float* __restrict__ Wih1,
                                             const float* __restrict__ Whh1,
                                             const float* __restrict__ bih1,
                                             const float* __restrict__ bhh1,
                                             const float* __restrict__ fc1w,
                                             const float* __restrict__ fc1b,
                                             const float* __restrict__ fc2w,
                                             const float* __restrict__ fc2b,
                                             const float* __restrict__ fc3w,
                                             const float* __restrict__ fc3b,
                                             float* __restrict__ ct,
                                             float* __restrict__ dout){
  const int n = blockIdx.x, l = threadIdx.x;
  const int g2 = l & 31, hh = l >> 5, co = hh * 16;
  __shared__ float h0sh[32], h1sh[32];
  __shared__ float hist[64][33];
  __shared__ float Wst[32][33];
  __shared__ float b1s[32], b2s[32], w3s[32];
  // ---- weight slices (144 VGPRs) ----
  float w0r[16], w0z[16], w0n[16];
  float wi1r[16], wi1z[16], wi1n[16];
  float wh1r[16], wh1z[16], wh1n[16];
  {
    const float* W0  = Whh0 + n*3072;
    const float* Wi1 = Wih1 + n*3072;
    const float* Wh1 = Whh1 + n*3072;
#pragma unroll
    for (int q = 0; q < 4; ++q){
      float4 v;
      v = *(const float4*)(W0 + g2*32 + co + 4*q);        w0r[4*q]=v.x; w0r[4*q+1]=v.y; w0r[4*q+2]=v.z; w0r[4*q+3]=v.w;
      v = *(const float4*)(W0 + (32+g2)*32 + co + 4*q);   w0z[4*q]=v.x; w0z[4*q+1]=v.y; w0z[4*q+2]=v.z; w0z[4*q+3]=v.w;
      v = *(const float4*)(W0 + (64+g2)*32 + co + 4*q);   w0n[4*q]=v.x; w0n[4*q+1]=v.y; w0n[4*q+2]=v.z; w0n[4*q+3]=v.w;
      v = *(const float4*)(Wi1 + g2*32 + co + 4*q);       wi1r[4*q]=v.x; wi1r[4*q+1]=v.y; wi1r[4*q+2]=v.z; wi1r[4*q+3]=v.w;
      v = *(const float4*)(Wi1 + (32+g2)*32 + co + 4*q);  wi1z[4*q]=v.x; wi1z[4*q+1]=v.y; wi1z[4*q+2]=v.z; wi1z[4*q+3]=v.w;
      v = *(const float4*)(Wi1 + (64+g2)*32 + co + 4*q);  wi1n[4*q]=v.x; wi1n[4*q+1]=v.y; wi1n[4*q+2]=v.z; wi1n[4*q+3]=v.w;
      v = *(const float4*)(Wh1 + g2*32 + co + 4*q);       wh1r[4*q]=v.x; wh1r[4*q+1]=v.y; wh1r[4*q+2]=v.z; wh1r[4*q+3]=v.w;
      v = *(const float4*)(Wh1 + (32+g2)*32 + co + 4*q);  wh1z[4*q]=v.x; wh1z[4*q+1]=v.y; wh1z[4*q+2]=v.z; wh1z[4*q+3]=v.w;
      v = *(const float4*)(Wh1 + (64+g2)*32 + co + 4*q);  wh1n[4*q]=v.x; wh1n[4*q+1]=v.y; wh1n[4*q+2]=v.z; wh1n[4*q+3]=v.w;
    }
  }
  const float bi0r = bih0[n*96 + g2], bi0z = bih0[n*96 + 32 + g2], bi0n = bih0[n*96 + 64 + g2];
  const float bh0r = bhh0[n*96 + g2], bh0z = bhh0[n*96 + 32 + g2], bh0n = bhh0[n*96 + 64 + g2];
  const float bi1r = bih1[n*96 + g2], bi1z = bih1[n*96 + 32 + g2], bi1n = bih1[n*96 + 64 + g2];
  const float bh1r = bhh1[n*96 + g2], bh1z = bhh1[n*96 + 32 + g2], bh1n = bhh1[n*96 + 64 + g2];
  // ---- state ----
  float h0own = Hpre[n*32 + g2];
  float h1own = Hpre[8192 + n*32 + g2];
  if (l < 32){ h0sh[l] = h0own; h1sh[l] = h1own; }
  __syncthreads();
  float h0s[16], h1s[16];
#pragma unroll
  for (int q = 0; q < 4; ++q){
    float4 v0 = *(const float4*)&h0sh[co + 4*q];
    float4 v1 = *(const float4*)&h1sh[co + 4*q];
    h0s[4*q]=v0.x; h0s[4*q+1]=v0.y; h0s[4*q+2]=v0.z; h0s[4*q+3]=v0.w;
    h1s[4*q]=v1.x; h1s[4*q+1]=v1.y; h1s[4*q+2]=v1.z; h1s[4*q+3]=v1.w;
  }
  const float* gin0 = G0 + n*16384;
  const float* gin1 = G1 + n*16384;
  const float* gin2 = G2 + n*8192;
  float gir  = gin0[g2]      + gin1[g2]      + gin2[g2];
  float giz  = gin0[32 + g2] + gin1[32 + g2] + gin2[32 + g2];
  float ginn = gin0[64 + g2] + gin1[64 + g2] + gin2[64 + g2];
  for (int t = 0; t < 64; ++t){
    float gir_n = 0.f, giz_n = 0.f, ginn_n = 0.f;
    if (t < 63){
      const int off = (t+1)*96;
      gir_n  = gin0[off + g2]      + gin1[off + g2]      + gin2[off + g2];
      giz_n  = gin0[off + 32 + g2] + gin1[off + 32 + g2] + gin2[off + 32 + g2];
      ginn_n = gin0[off + 64 + g2] + gin1[off + 64 + g2] + gin2[off + 64 + g2];
    }
    // ---- layer 0 ----
    float pr = 0.f, pz = 0.f, pn = 0.f;
#pragma unroll
    for (int j = 0; j < 16; ++j){
      pr = fmaf(w0r[j], h0s[j], pr);
      pz = fmaf(w0z[j], h0s[j], pz);
      pn = fmaf(w0n[j], h0s[j], pn);
    }
    pr += __shfl_xor(pr, 32);
    pz += __shfl_xor(pz, 32);
    pn += __shfl_xor(pn, 32);
    float r = sigf(gir + bi0r + pr + bh0r);
    float z = sigf(giz + bi0z + pz + bh0z);
    float nn = tanhf(ginn + bi0n + r*(pn + bh0n));
    float h0new = (1.f - z)*nn + z*h0own;
    h0own = h0new;
    if (l < 32) h0sh[g2] = h0new;
    __syncthreads();
#pragma unroll
    for (int q = 0; q < 4; ++q){
      float4 v0 = *(const float4*)&h0sh[co + 4*q];
      h0s[4*q]=v0.x; h0s[4*q+1]=v0.y; h0s[4*q+2]=v0.z; h0s[4*q+3]=v0.w;
    }
    // ---- layer 1 ----
    float qr = 0.f, qz = 0.f, qn = 0.f, sr = 0.f, sz = 0.f, sn = 0.f;
#pragma unroll
    for (int j = 0; j < 16; ++j){
      qr = fmaf(wi1r[j], h0s[j], qr);  sr = fmaf(wh1r[j], h1s[j], sr);
      qz = fmaf(wi1z[j], h0s[j], qz);  sz = fmaf(wh1z[j], h1s[j], sz);
      qn = fmaf(wi1n[j], h0s[j], qn);  sn = fmaf(wh1n[j], h1s[j], sn);
    }
    float vr = qr + sr; vr += __shfl_xor(vr, 32);
    float vz = qz + sz; vz += __shfl_xor(vz, 32);
    qn += __shfl_xor(qn, 32);
    sn += __shfl_xor(sn, 32);
    float r1 = sigf(vr + bi1r + bh1r);
    float z1 = sigf(vz + bi1z + bh1z);
    float n1 = tanhf(qn + bi1n + r1*(sn + bh1n));
    float h1new = (1.f - z1)*n1 + z1*h1own;
    h1own = h1new;
    if (l < 32){ h1sh[g2] = h1new; hist[t][g2] = h1new; }
    __syncthreads();
#pragma unroll
    for (int q = 0; q < 4; ++q){
      float4 v1 = *(const float4*)&h1sh[co + 4*q];
      h1s[4*q]=v1.x; h1s[4*q+1]=v1.y; h1s[4*q+2]=v1.z; h1s[4*q+3]=v1.w;
    }
    gir = gir_n; giz = giz_n; ginn = ginn_n;
  }
  if (l < 32){
    dout[16384 + n*32 + l]        = h0own;            // cat_H[0]
    dout[16384 + 8192 + n*32 + l] = h1own;            // cat_H[1]
  }
  // ---- fused FC head: lane = sensor s (64) ----
  if (l < 32){
    b1s[l] = fc1b[n*32 + l];
    b2s[l] = fc2b[n*32 + l];
    w3s[l] = fc3w[n*32 + l];
  }
  for (int idx = l; idx < 1024; idx += 64) Wst[idx>>5][idx&31] = fc1w[n*1024 + idx];
  __syncthreads();
  float hr[32];
#pragma unroll
  for (int k = 0; k < 32; ++k) hr[k] = hist[l][k];
  float r1a[32];
#pragma unroll
  for (int k = 0; k < 32; ++k){
    float a0=0.f,a1=0.f,a2=0.f,a3=0.f;
#pragma unroll
    for (int q = 0; q < 32; q += 4){
      a0 = fmaf(hr[q],   Wst[k][q],   a0);
      a1 = fmaf(hr[q+1], Wst[k][q+1], a1);
      a2 = fmaf(hr[q+2], Wst[k][q+2], a2);
      a3 = fmaf(hr[q+3], Wst[k][q+3], a3);
    }
    float v = b1s[k] + ((a0+a1)+(a2+a3));
    r1a[k] = v > 0.f ? v : 0.f;
  }
  __syncthreads();
  for (int idx = l; idx < 1024; idx += 64) Wst[idx>>5][idx&31] = fc2w[n*1024 + idx];
  __syncthreads();
  float r2a[32];
#pragma unroll
  for (int k = 0; k < 32; ++k){
    float a0=0.f,a1=0.f,a2=0.f,a3=0.f;
#pragma unroll
    for (int q = 0; q < 32; q += 4){
      a0 = fmaf(r1a[q],   Wst[k][q],   a0);
      a1 = fmaf(r1a[q+1], Wst[k][q+1], a1);
      a2 = fmaf(r1a[q+2], Wst[k][q+2], a2);
      a3 = fmaf(r1a[q+3], Wst[k][q+3], a3);
    }
    float v = b2s[k] + ((a0+a1)+(a2+a3));
    r2a[k] = v > 0.f ? v : 0.f;
  }
  float v = fc3b[n];
#pragma unroll
  for (int k = 0; k < 32; ++k) v = fmaf(r2a[k], w3s[k], v);
  ct[n*64 + l] = v;
}

// ---- k8a: Wh (transposed) + f1/f2 for out & out1. grid 8 = gat*4 + row-quarter ----
__global__ __launch_bounds__(256) void k8a(const float* __restrict__ ct,
                                           const float* __restrict__ W0,
                                           const float* __restrict__ a0,
                                           const float* __restrict__ W1,
                                           const float* __restrict__ a1,
                                           float* __restrict__ WhABt,
                                           float* __restrict__ OF1,
                                           float* __restrict__ OF2){
  const int gat = blockIdx.x >> 2, rq = blockIdx.x & 3, r0 = rq*64;
  const int tid = threadIdx.x;
  const int ii = tid & 63, cq = tid >> 6;
  __shared__ float ctl[64][65];
  __shared__ float Wl[64][68];
  __shared__ float a1s[64], a2s[64];
  __shared__ float red[64][4][2];
  const float* W = gat ? W1 : W0;
  const float* aa = gat ? a1 : a0;
  for (int idx = tid; idx < 4096; idx += 256){
    int i2 = idx >> 6, k = idx & 63;
    ctl[i2][k] = ct[(r0 + i2)*64 + k];
  }
  for (int idx = tid; idx < 4096; idx += 256){
    int k = idx >> 6, c = idx & 63;
    Wl[k][c] = W[k*64 + c];
  }
  if (tid < 64){ a1s[tid] = aa[tid]; a2s[tid] = aa[64 + tid]; }
  __syncthreads();
  float acc[16];
#pragma unroll
  for (int c = 0; c < 16; ++c) acc[c] = 0.f;
#pragma unroll 2
  for (int k = 0; k < 64; ++k){
    float v = ctl[ii][k];
    const float* wr = &Wl[k][cq*16];
#pragma unroll
    for (int c = 0; c < 16; ++c) acc[c] = fmaf(v, wr[c], acc[c]);
  }
  float p1 = 0.f, p2 = 0.f;
#pragma unroll
  for (int c = 0; c < 16; ++c){
    p1 = fmaf(acc[c], a1s[cq*16 + c], p1);
    p2 = fmaf(acc[c], a2s[cq*16 + c], p2);
  }
  red[ii][cq][0] = p1; red[ii][cq][1] = p2;
  float* o = WhABt + gat*16384;
#pragma unroll
  for (int c = 0; c < 16; ++c) o[(cq*16 + c)*256 + r0 + ii] = acc[c];
  __syncthreads();
  if (cq == 0){
    OF1[gat*256 + r0 + ii] = red[ii][0][0] + red[ii][1][0] + red[ii][2][0] + red[ii][3][0];
    OF2[gat*256 + r0 + ii] = red[ii][0][1] + red[ii][1][1] + red[ii][2][1] + red[ii][3][1];
  }
}

// ---- k8b: out/out1 attention. grid 8 = gat*4 + c-tile(16) ----
__global__ __launch_bounds__(256) void k8b(const float* __restrict__ WhABt,
                                           const float* __restrict__ OF1,
                                           const float* __restrict__ OF2,
                                           const unsigned* __restrict__ maskA,
                                           float* __restrict__ OUTT){
  const int gat = blockIdx.x >> 2, c0 = (blockIdx.x & 3) * 16;
  const int i = threadIdx.x;
  __shared__ float f2s[256];
  __shared__ float wt[64][36];
  const float f1 = OF1[gat*256 + i];
  f2s[i] = OF2[gat*256 + i];
  unsigned mw[8];
#pragma unroll
  for (int w = 0; w < 8; ++w) mw[w] = maskA[i*8 + w];
  __syncthreads();
  float m = -INFINITY;
  for (int w = 0; w < 8; ++w){
    const unsigned mk = mw[w];
#pragma unroll
    for (int bb = 0; bb < 32; ++bb){
      float e = f1 + f2s[(w<<5)+bb]; e = (e > 0.f) ? e : ALPHA*e;
      e = ((mk >> bb) & 1u) ? e : NEGV;
      m = fmaxf(m, e);
    }
  }
  float s = 0.f;
  for (int w = 0; w < 8; ++w){
    const unsigned mk = mw[w];
#pragma unroll
    for (int bb = 0; bb < 32; ++bb){
      float e = f1 + f2s[(w<<5)+bb]; e = (e > 0.f) ? e : ALPHA*e;
      e = ((mk >> bb) & 1u) ? e : NEGV;
      s += __expf(e - m);
    }
  }
  const float inv = 1.f / s;
  float acc[16];
#pragma unroll
  for (int c = 0; c < 16; ++c) acc[c] = 0.f;
  for (int jt = 0; jt < 4; ++jt){
    __syncthreads();
    for (int idx = i; idx < 1024; idx += 256){
      int cc = idx >> 6, jj = idx & 63;
      wt[jj][cc] = WhABt[gat*16384 + (c0+cc)*256 + (jt<<6) + jj];
    }
    __syncthreads();
    for (int jj = 0; jj < 64; ++jj){
      const int j = (jt<<6) + jj;
      float e = f1 + f2s[j]; e = (e > 0.f) ? e : ALPHA*e;
      e = ((mw[j>>5] >> (j & 31)) & 1u) ? e : NEGV;
      const float p = __expf(e - m) * inv;
      const float* wr = &wt[jj][0];
#pragma unroll
      for (int c = 0; c < 16; ++c) acc[c] = fmaf(p, wr[c], acc[c]);
    }
  }
#pragma unroll
  for (int c = 0; c < 16; ++c) OUTT[gat*16384 + (c0+c)*256 + i] = acc[c];
}

// ---- k8c: Wh2 (transposed) + F1B/F2B. grid 8 = 32-row chunks ----
__global__ __launch_bounds__(256) void k8c(const float* __restrict__ OUTT,
                                           const float* __restrict__ W2,
                                           const float* __restrict__ a2,
                                           float* __restrict__ Wh2,
                                           float* __restrict__ F1B,
                                           float* __restrict__ F2B){
  const int r0 = blockIdx.x * 32;
  const int tid = threadIdx.x;
  const int ii = tid & 31, cq = tid >> 5;      // 8 groups x 8 cols
  __shared__ float W2l[128][68];
  __shared__ float a1s[64], a2s[64];
  __shared__ float red[32][8][2];
  for (int idx = tid; idx < 8192; idx += 256){
    int k = idx >> 6, c = idx & 63;
    W2l[k][c] = W2[k*64 + c];
  }
  if (tid < 64){ a1s[tid] = a2[tid]; a2s[tid] = a2[64 + tid]; }
  __syncthreads();
  float acc[8];
#pragma unroll
  for (int c = 0; c < 8; ++c) acc[c] = 0.f;
#pragma unroll 2
  for (int k = 0; k < 128; ++k){
    float v = OUTT[(k >> 6)*16384 + (k & 63)*256 + r0 + ii];
    const float* wr = &W2l[k][cq*8];
#pragma unroll
    for (int c = 0; c < 8; ++c) acc[c] = fmaf(v, wr[c], acc[c]);
  }
  float p1 = 0.f, p2 = 0.f;
#pragma unroll
  for (int c = 0; c < 8; ++c){
    p1 = fmaf(acc[c], a1s[cq*8 + c], p1);
    p2 = fmaf(acc[c], a2s[cq*8 + c], p2);
  }
  red[ii][cq][0] = p1; red[ii][cq][1] = p2;
#pragma unroll
  for (int c = 0; c < 8; ++c) Wh2[(cq*8 + c)*256 + r0 + ii] = acc[c];
  __syncthreads();
  if (cq == 0){
    float s1 = 0.f, s2 = 0.f;
#pragma unroll
    for (int q = 0; q < 8; ++q){ s1 += red[ii][q][0]; s2 += red[ii][q][1]; }
    F1B[r0 + ii] = s1; F2B[r0 + ii] = s2;
  }
}

// ---- k8d: final GAT -> d_out. grid 4 = c-tiles(16) ----
__global__ __launch_bounds__(256) void k8d(const float* __restrict__ Wh2,
                                           const float* __restrict__ F1B,
                                           const float* __restrict__ F2B,
                                           const unsigned* __restrict__ maskA,
                                           float* __restrict__ dOut){
  const int c0 = blockIdx.x * 16;
  const int i = threadIdx.x;
  __shared__ float f2s[256];
  __shared__ float wt[64][36];
  const float f1 = F1B[i];
  f2s[i] = F2B[i];
  unsigned mw[8];
#pragma unroll
  for (int w = 0; w < 8; ++w) mw[w] = maskA[i*8 + w];
  __syncthreads();
  float m = -INFINITY;
  for (int w = 0; w < 8; ++w){
    const unsigned mk = mw[w];
#pragma unroll
    for (int bb = 0; bb < 32; ++bb){
      float e = f1 + f2s[(w<<5)+bb]; e = (e > 0.f) ? e : ALPHA*e;
      e = ((mk >> bb) & 1u) ? e : NEGV;
      m = fmaxf(m, e);
    }
  }
  float s = 0.f;
  for (int w = 0; w < 8; ++w){
    const unsigned mk = mw[w];
#pragma unroll
    for (int bb = 0; bb < 32; ++bb){
      float e = f1 + f2s[(w<<5)+bb]; e = (e > 0.f) ? e : ALPHA*e;
      e = ((mk >> bb) & 1u) ? e : NEGV;
      s += __expf(e - m);
    }
  }
  const float inv = 1.f / s;
  float acc[16];
#pragma unroll
  for (int c = 0; c < 16; ++c) acc[c] = 0.f;
  for (int jt = 0; jt < 4; ++jt){
    __syncthreads();
    for (int idx = i; idx < 1024; idx += 256){
      int cc = idx >> 6, jj = idx & 63;
      wt[jj][cc] = Wh2[(c0+cc)*256 + (jt<<6) + jj];
    }
    __syncthreads();
    for (int jj = 0; jj < 64; ++jj){
      const int j = (jt<<6) + jj;
      float e = f1 + f2s[j]; e = (e > 0.f) ? e : ALPHA*e;
      e = ((mw[j>>5] >> (j & 31)) & 1u) ? e : NEGV;
      const float p = __expf(e - m) * inv;
      const float* wr = &wt[jj][0];
#pragma unroll
      for (int c = 0; c < 16; ++c) acc[c] = fmaf(p, wr[c], acc[c]);
    }
  }
#pragma unroll
  for (int c = 0; c < 16; ++c) dOut[i*64 + c0 + c] = acc[c];
}

extern "C" void kernel_launch(void* const* d_in, const int* in_sizes, int n_in,
                              void* d_out, int out_size, void* d_ws, size_t ws_size,
                              hipStream_t stream){
  (void)in_sizes; (void)n_in; (void)out_size; (void)ws_size;
  const float* x     = (const float*)d_in[0];
  const float* Fadj  = (const float*)d_in[1];
  const float* Tadj  = (const float*)d_in[2];
  const float* adj   = (const float*)d_in[3];
  const float* Hpre  = (const float*)d_in[4];
  const float* FattW = (const float*)d_in[5];
  const float* Fatta = (const float*)d_in[6];
  const float* TattW = (const float*)d_in[7];
  const float* Tatta = (const float*)d_in[8];
  const float* Wih0  = (const float*)d_in[9];
  const float* Whh0  = (const float*)d_in[10];
  const float* bih0  = (const float*)d_in[11];
  const float* bhh0  = (const float*)d_in[12];
  const float* Wih1  = (const float*)d_in[13];
  const float* Whh1  = (const float*)d_in[14];
  const float* bih1  = (const float*)d_in[15];
  const float* bhh1  = (const float*)d_in[16];
  const float* fc1w  = (const float*)d_in[17];
  const float* fc1b  = (const float*)d_in[18];
  const float* fc2w  = (const float*)d_in[19];
  const float* fc2b  = (const float*)d_in[20];
  const float* fc3w  = (const float*)d_in[21];
  const float* fc3b  = (const float*)d_in[22];
  const float* oW    = (const float*)d_in[23];
  const float* oa    = (const float*)d_in[24];
  const float* o1W   = (const float*)d_in[25];
  const float* o1a   = (const float*)d_in[26];
  const float* o2W   = (const float*)d_in[27];
  const float* o2a   = (const float*)d_in[28];
  float* out = (float*)d_out;

  float* ws = (float*)d_ws;
  float* R0 = ws;
  float* R1 = ws + 4194304;
  float* R2 = ws + 8388608;
  unsigned* maskT = (unsigned*)R2;             // 524288 words
  float* Tf1p = R2 + 524288;                   // 2 x 65536
  float* Tf2p = R2 + 655360;                   // 2 x 65536
  unsigned* maskA = (unsigned*)(ws + 12582912);// 2048 words
  float* WhTt = R0;
  float* WhF  = R0;
  float* TatT = R1;
  float* Fat  = R2;
  // k5 partials: P0 over Fat slots (stride 16384, only-reader-is-writer),
  // P1 over TatT slots (stride 16384), P2 compact in R0 (stride 8192).
  float* P0 = R2;
  float* P1 = R1;
  float* P2 = R0;
  float* ctb   = R0 + 2097152;                 // above P2's 2.1M-float span
  float* WhABt = R1 + 16384;
  float* OF1   = R1 + 49152;
  float* OF2   = R1 + 49664;
  float* OUTT  = R1 + 50176;
  float* WH2   = R1 + 82944;
  float* F1B   = R1 + 99328;
  float* F2B   = R1 + 99584;

  k_mask<<<1024, 256, 0, stream>>>(Tadj, maskT, 16777216);
  k_mask<<<32, 256, 0, stream>>>(adj, maskA, 65536);
  k3_wht<<<512, 256, 0, stream>>>(x, TattW, Tatta, WhTt, Tf1p, Tf2p);
  k4_tat<<<512, 256, 0, stream>>>(WhTt, Tf1p, Tf2p, maskT, TatT);
  k1_whf<<<256, 512, 0, stream>>>(x, FattW, WhF);
  k2_fat<<<256, 512, 0, stream>>>(WhF, Fatta, Fadj, Fat);
  k5_gi0<<<768, 256, 0, stream>>>(Fat, TatT, x, Wih0, P0, P1, P2);
  k6_gru<<<256, 64, 0, stream>>>(P0, P1, P2, Hpre, Whh0, bih0, bhh0, Wih1, Whh1, bih1, bhh1,
                                 fc1w, fc1b, fc2w, fc2b, fc3w, fc3b, ctb, out);
  k8a<<<8, 256, 0, stream>>>(ctb, oW, oa, o1W, o1a, WhABt, OF1, OF2);
  k8b<<<8, 256, 0, stream>>>(WhABt, OF1, OF2, maskA, OUTT);
  k8c<<<8, 256, 0, stream>>>(OUTT, o2W, o2a, WH2, F1B, F2B);
  k8d<<<4, 256, 0, stream>>>(WH2, F1B, F2B, maskA, out);
}

// Round 2
// 791.575 us; speedup vs baseline: 1.0911x; 1.0065x over previous
//
#include <hip/hip_runtime.h>
#include <hip/hip_bf16.h>

__device__ __forceinline__ float sigf(float x){ return __builtin_amdgcn_rcpf(1.f+__expf(-x)); }
__device__ __forceinline__ float tanhfa(float x){
  return 1.f - 2.f*__builtin_amdgcn_rcpf(1.f + __expf(2.f*x));
}

#define ALPHA 0.2f
#define NEGV  -9e15f

// N=256 nodes, S=64 sensors, W=256 window, H=32 hidden. All fp32.

// ---- k_mask: pack adjacency fp32 (0/1) -> bitmask via wave ballot ----
__global__ __launch_bounds__(256) void k_mask(const float* __restrict__ src,
                                              unsigned* __restrict__ dst, int nelem){
  const int stride = gridDim.x * blockDim.x;
  const int lane = threadIdx.x & 63;
  for (int e = blockIdx.x*blockDim.x + threadIdx.x; e < nelem; e += stride){
    unsigned long long m = __ballot(src[e] > 0.f);
    if (lane == 0)       dst[e >> 5] = (unsigned)m;
    else if (lane == 32) dst[e >> 5] = (unsigned)(m >> 32);
  }
}

// ---- k3: Wh_T (transposed store) + Tf1/Tf2 partials. grid 512 = n*2 + c-half ----
__global__ __launch_bounds__(256) void k3_wht(const float* __restrict__ x,
                                              const float* __restrict__ TW,
                                              const float* __restrict__ Ta,
                                              float* __restrict__ WhTt,
                                              float* __restrict__ Tf1p,
                                              float* __restrict__ Tf2p){
  const int n = blockIdx.x >> 1, ch = blockIdx.x & 1, c0 = ch*32;
  const int tid = threadIdx.x;
  __shared__ float Wm[64][36];
  __shared__ float as1[32], as2[32];
  for (int idx = tid; idx < 2048; idx += 256){
    int k = idx >> 5, cc = idx & 31;
    Wm[k][cc] = TW[n*4096 + k*64 + c0 + cc];
  }
  if (tid < 32){ as1[tid] = Ta[n*128 + c0 + tid]; as2[tid] = Ta[n*128 + 64 + c0 + tid]; }
  __syncthreads();
  const int i = tid;
  const float* xn = x + n*16384;
  float acc[32];
#pragma unroll
  for (int c = 0; c < 32; ++c) acc[c] = 0.f;
#pragma unroll 2
  for (int k = 0; k < 64; ++k){
    float xv = xn[k*256 + i];                  // coalesced
    const float* wr = &Wm[k][0];               // broadcast b128
#pragma unroll
    for (int c = 0; c < 32; ++c) acc[c] = fmaf(xv, wr[c], acc[c]);
  }
  float f1 = 0.f, f2 = 0.f;
#pragma unroll
  for (int c = 0; c < 32; ++c){ f1 = fmaf(acc[c], as1[c], f1); f2 = fmaf(acc[c], as2[c], f2); }
  Tf1p[ch*65536 + n*256 + i] = f1;
  Tf2p[ch*65536 + n*256 + i] = f2;
  float* o = WhTt + n*16384;
#pragma unroll
  for (int c = 0; c < 32; ++c) o[(c0+c)*256 + i] = acc[c];
}

// ---- k4: time-GAT attention. grid 512 = n*2 + c-half, thread = window row i ----
__global__ __launch_bounds__(256) void k4_tat(const float* __restrict__ WhTt,
                                              const float* __restrict__ Tf1p,
                                              const float* __restrict__ Tf2p,
                                              const unsigned* __restrict__ maskT,
                                              float* __restrict__ TatT){
  const int n = blockIdx.x >> 1, ch = blockIdx.x & 1, c0 = ch*32;
  const int i = threadIdx.x;
  __shared__ float f2s[256];
  __shared__ float wt[64][36];
  const float f1 = Tf1p[n*256 + i] + Tf1p[65536 + n*256 + i];
  f2s[i] = Tf2p[n*256 + i] + Tf2p[65536 + n*256 + i];
  unsigned mw[8];
#pragma unroll
  for (int w = 0; w < 8; ++w) mw[w] = maskT[n*2048 + i*8 + w];
  __syncthreads();
  float m = -INFINITY;
  for (int w = 0; w < 8; ++w){
    const unsigned mk = mw[w];
#pragma unroll
    for (int bb = 0; bb < 32; ++bb){
      float e = f1 + f2s[(w<<5)+bb]; e = (e > 0.f) ? e : ALPHA*e;
      e = ((mk >> bb) & 1u) ? e : NEGV;
      m = fmaxf(m, e);
    }
  }
  float s = 0.f;
  for (int w = 0; w < 8; ++w){
    const unsigned mk = mw[w];
#pragma unroll
    for (int bb = 0; bb < 32; ++bb){
      float e = f1 + f2s[(w<<5)+bb]; e = (e > 0.f) ? e : ALPHA*e;
      e = ((mk >> bb) & 1u) ? e : NEGV;
      s += __expf(e - m);
    }
  }
  const float inv = 1.f / s;
  float acc[32];
#pragma unroll
  for (int c = 0; c < 32; ++c) acc[c] = 0.f;
  for (int jt = 0; jt < 4; ++jt){
    __syncthreads();
    for (int idx = i; idx < 2048; idx += 256){
      int cc = idx >> 6, jj = idx & 63;
      wt[jj][cc] = WhTt[n*16384 + (c0+cc)*256 + (jt<<6) + jj];   // coalesced
    }
    __syncthreads();
    for (int jj = 0; jj < 64; ++jj){
      const int j = (jt<<6) + jj;
      float e = f1 + f2s[j]; e = (e > 0.f) ? e : ALPHA*e;
      e = ((mw[j>>5] >> (j & 31)) & 1u) ? e : NEGV;
      const float p = __expf(e - m) * inv;
      const float* wr = &wt[jj][0];            // broadcast b128
#pragma unroll
      for (int c = 0; c < 32; ++c) acc[c] = fmaf(p, wr[c], acc[c]);
    }
  }
  float* o = TatT + n*16384;
#pragma unroll
  for (int c = 0; c < 32; ++c) o[(c0+c)*256 + i] = acc[c];
}

// ---- k1: Wh_F = x @ Fatt_W. grid 256, block 512 (two k-halves, LDS reduce) ----
__global__ __launch_bounds__(512) void k1_whf(const float* __restrict__ x,
                                              const float* __restrict__ FW,
                                              float* __restrict__ WhF){
  const int n = blockIdx.x, tid = threadIdx.x;
  __shared__ float xt[256][64];                // 64 KB; rotated layout (bank-friendly)
  const float* xn = x + n*16384;
  for (int idx = tid; idx < 16384; idx += 512){
    int i = idx >> 8, k = idx & 255;
    xt[k][(i + (k & 60)) & 63] = xn[idx];      // coalesced read
  }
  __syncthreads();
  const int c = tid & 255, kg = tid >> 8;
  const float* Wn = FW + (size_t)n*65536;
  float acc[64];
#pragma unroll
  for (int i = 0; i < 64; ++i) acc[i] = 0.f;
  const int kbeg = kg*128, kend = kbeg + 128;
#pragma unroll 2
  for (int k = kbeg; k < kend; ++k){
    float w = Wn[k*256 + c];                   // coalesced
    const float4* xr = (const float4*)&xt[k][0];
    const int r4 = (k >> 2) & 15;
#pragma unroll
    for (int g = 0; g < 16; ++g){
      float4 v = xr[(g + r4) & 15];            // broadcast b128, uniform rotated index
      acc[4*g+0] = fmaf(v.x, w, acc[4*g+0]);
      acc[4*g+1] = fmaf(v.y, w, acc[4*g+1]);
      acc[4*g+2] = fmaf(v.z, w, acc[4*g+2]);
      acc[4*g+3] = fmaf(v.w, w, acc[4*g+3]);
    }
  }
  __syncthreads();
  float* buf = &xt[0][0];                      // reuse LDS as 64x256 reduce buffer
  if (kg == 1){
#pragma unroll
    for (int i = 0; i < 64; ++i) buf[i*256 + c] = acc[i];
  }
  __syncthreads();
  if (kg == 0){
    float* o = WhF + n*16384;
#pragma unroll
    for (int i = 0; i < 64; ++i) o[i*256 + c] = acc[i] + buf[i*256 + c];
  }
}

// ---- k2: feature-GAT softmax + Fat = att @ Wh. grid 256, block 512 (i-split) ----
__global__ __launch_bounds__(512) void k2_fat(const float* __restrict__ WhF,
                                              const float* __restrict__ Fa,
                                              const float* __restrict__ Fadj,
                                              float* __restrict__ Fat){
  const int n = blockIdx.x, tid = threadIdx.x;
  __shared__ float attT[64][68];               // attT[j][i]
  __shared__ float f1s[64], f2s[64];
  __shared__ float part[64][8][2];
  const float* Wh = WhF + n*16384;
  { // f1/f2: thread (i=tid>>3, q=tid&7) partial over 32 cols
    int i = tid >> 3, q = tid & 7;
    const float* an = Fa + n*512;
    float p1 = 0.f, p2 = 0.f;
    for (int cc = 0; cc < 32; ++cc){
      int c2 = q*32 + cc;
      float w = Wh[i*256 + c2];
      p1 = fmaf(w, an[c2], p1);
      p2 = fmaf(w, an[256 + c2], p2);
    }
    part[i][q][0] = p1; part[i][q][1] = p2;
  }
  __syncthreads();
  if (tid < 64){
    float s1 = 0.f, s2 = 0.f;
#pragma unroll
    for (int q = 0; q < 8; ++q){ s1 += part[tid][q][0]; s2 += part[tid][q][1]; }
    f1s[tid] = s1; f2s[tid] = s2;
  }
  __syncthreads();
  if (tid < 64){                               // masked softmax row -> attT column
    const int r = tid;
    const float f1 = f1s[r];
    const float* adjr = Fadj + n*4096 + r*64;
    unsigned m0 = 0, m1 = 0;
#pragma unroll
    for (int j = 0; j < 32; ++j) if (adjr[j] > 0.f) m0 |= (1u << j);
#pragma unroll
    for (int j = 0; j < 32; ++j) if (adjr[32+j] > 0.f) m1 |= (1u << j);
    float m = -INFINITY;
#pragma unroll
    for (int j = 0; j < 64; ++j){
      float e = f1 + f2s[j]; e = (e > 0.f) ? e : ALPHA*e;
      unsigned bit = (j < 32) ? ((m0 >> j) & 1u) : ((m1 >> (j-32)) & 1u);
      e = bit ? e : NEGV;
      m = fmaxf(m, e);
    }
    float s = 0.f;
#pragma unroll
    for (int j = 0; j < 64; ++j){
      float e = f1 + f2s[j]; e = (e > 0.f) ? e : ALPHA*e;
      unsigned bit = (j < 32) ? ((m0 >> j) & 1u) : ((m1 >> (j-32)) & 1u);
      e = bit ? e : NEGV;
      s += __expf(e - m);
    }
    const float inv = 1.f / s;
#pragma unroll
    for (int j = 0; j < 64; ++j){
      float e = f1 + f2s[j]; e = (e > 0.f) ? e : ALPHA*e;
      unsigned bit = (j < 32) ? ((m0 >> j) & 1u) : ((m1 >> (j-32)) & 1u);
      e = bit ? e : NEGV;
      attT[j][r] = __expf(e - m) * inv;
    }
  }
  __syncthreads();
  const int c = tid & 255, ih = tid >> 8;      // ih: 32-row half of output
  float acc[32];
#pragma unroll
  for (int i = 0; i < 32; ++i) acc[i] = 0.f;
#pragma unroll 2
  for (int j = 0; j < 64; ++j){
    float w = Wh[j*256 + c];                   // coalesced, L2-hot
    const float* ar = &attT[j][ih*32];         // broadcast b128 (16B-aligned)
#pragma unroll
    for (int i = 0; i < 32; ++i) acc[i] = fmaf(ar[i], w, acc[i]);
  }
  float* o = Fat + n*16384;
#pragma unroll
  for (int i = 0; i < 32; ++i) o[(ih*32 + i)*256 + c] = acc[i];
}

// ---- k5: partial Gi0 = cat_seg @ Wih0_seg^T. grid 768 = s*256 + n ----
// s=0: Fat (k 0..255), s=1: TatT (k 256..511), s=2: x (k 512..767).
// Double-buffered global_load_lds staging (counted vmcnt(5), raw barriers),
// source-side XOR swizzle on the cat tile so ds_read_b128 column reads are
// bank-conflict-free. Thread = (a: t-pair, b: 12-gate group), acc 12x2.
__device__ __forceinline__ void gl2lds16(const float* g, float* l){
  __builtin_amdgcn_global_load_lds(
      (const __attribute__((address_space(1))) void*)g,
      (__attribute__((address_space(3))) void*)l, 16, 0, 0);
}

__global__ __launch_bounds__(256) void k5_gi0(const float* __restrict__ Fat,
                                              const float* __restrict__ TatT,
                                              const float* __restrict__ x,
                                              const float* __restrict__ Wih0,
                                              float* __restrict__ P0,
                                              float* __restrict__ P1,
                                              float* __restrict__ P2){
  const int n = blockIdx.x & 255, s = blockIdx.x >> 8;
  const int tid = threadIdx.x;
  const int l = tid & 63, w = tid >> 6;        // lane, wave
  const int a = tid & 31, b = tid >> 5;        // t-pair lane, gate group (0..7)
  __shared__ float cl[2][2048];                // cat tile [64 t][32 k], dbuf, 16 KB
  __shared__ float wl[2][3072];                // W tile  [96 g][32 k], dbuf, 24 KB
  const float* src = (s == 0) ? (Fat + n*16384)
                   : (s == 1) ? (TatT + n*16384)
                              : (x + n*16384);
  const float* Wseg = Wih0 + (size_t)n*73728 + s*256;
  // staging lane mapping: each wave stages 2 cat chunks + 3 W chunks (1 KB each)
  const int lr = l >> 3, lc = l & 7, sc = lc ^ lr;       // sc: swizzled cat col4
  const float* cg0 = src + (16*w + lr)*256 + sc*4;       // cat rows 16w..16w+7
  const float* cg1 = cg0 + 8*256;                        // cat rows +8
  const float* wg0 = Wseg + (size_t)(24*w + lr)*768 + lc*4;  // W rows 24w..+7
  const float* wg1 = wg0 + (size_t)8*768;
  const float* wg2 = wg0 + (size_t)16*768;

#define K5_STAGE(BF, K0) do {                       \
    gl2lds16(cg0 + (K0), &cl[BF][512*w]);           \
    gl2lds16(cg1 + (K0), &cl[BF][512*w + 256]);     \
    gl2lds16(wg0 + (K0), &wl[BF][768*w]);           \
    gl2lds16(wg1 + (K0), &wl[BF][768*w + 256]);     \
    gl2lds16(wg2 + (K0), &wl[BF][768*w + 512]);     \
  } while (0)

  float acc[12][2];
#pragma unroll
  for (int gi = 0; gi < 12; ++gi){ acc[gi][0] = 0.f; acc[gi][1] = 0.f; }

  int bf = 0;
  K5_STAGE(0, 0);
  const int ax4 = (a & 7) << 2;
#pragma unroll 1
  for (int kt = 0; kt < 8; ++kt){
    if (kt < 7){
      K5_STAGE(bf ^ 1, (kt + 1) * 32);
      asm volatile("s_waitcnt vmcnt(5)" ::: "memory");  // current tile landed
    } else {
      asm volatile("s_waitcnt vmcnt(0)" ::: "memory");
    }
    __builtin_amdgcn_s_barrier();
    const float* clb  = &cl[bf][a*32];
    const float* clb2 = &cl[bf][(a+32)*32];
    const float* wlb  = &wl[bf][b*384];
#pragma unroll
    for (int k4 = 0; k4 < 8; ++k4){
      const int j4 = (k4 << 2) ^ ax4;                   // swizzled read col
      const float4 c0 = *(const float4*)&clb[j4];
      const float4 c1 = *(const float4*)&clb2[j4];
#pragma unroll
      for (int gi = 0; gi < 12; ++gi){
        const float4 wv = *(const float4*)&wlb[gi*32 + (k4 << 2)];
        float a0 = acc[gi][0], a1 = acc[gi][1];
        a0 = fmaf(wv.x, c0.x, a0); a1 = fmaf(wv.x, c1.x, a1);
        a0 = fmaf(wv.y, c0.y, a0); a1 = fmaf(wv.y, c1.y, a1);
        a0 = fmaf(wv.z, c0.z, a0); a1 = fmaf(wv.z, c1.z, a1);
        a0 = fmaf(wv.w, c0.w, a0); a1 = fmaf(wv.w, c1.w, a1);
        acc[gi][0] = a0; acc[gi][1] = a1;
      }
    }
    __builtin_amdgcn_s_barrier();
    bf ^= 1;
  }
#undef K5_STAGE
  // partial output [t][96]; overwrites own (dead, only-reader) input region
  float* o = (s == 0) ? (P0 + n*16384)
           : (s == 1) ? (P1 + n*16384)
                      : (P2 + n*8192);
#pragma unroll
  for (int q = 0; q < 3; ++q){
    *(float4*)&o[a*96 + b*12 + q*4] =
        make_float4(acc[4*q][0], acc[4*q+1][0], acc[4*q+2][0], acc[4*q+3][0]);
    *(float4*)&o[(a+32)*96 + b*12 + q*4] =
        make_float4(acc[4*q][1], acc[4*q+1][1], acc[4*q+2][1], acc[4*q+3][1]);
  }
}

// ---- k6: 2-layer GRU (64 steps). One wave per node, all gate inputs staged
// to LDS up front (zero global traffic in the recurrent loop). Lane l =
// (g2 = l&31, hh = l>>5); 144 weight VGPRs; fast rcp-based sigmoid/tanh.
__global__ __launch_bounds__(64) __attribute__((amdgpu_waves_per_eu(1)))
void k6_gru(const float* __restrict__ G0,
            const float* __restrict__ G1,
            const float* __restrict__ G2,
            const float* __restrict__ Hpre,
            const float* __restrict__ Whh0,
            const float* __restrict__ bih0,
            const float* __restrict__ bhh0,
            const float* __restrict__ Wih1,
            const float* __restrict__ Whh1,
            const float* __restrict__ bih1,
            const float* __restrict__ bhh1,
            const float* __restrict__ fc1w,
            const float* __restrict__ fc1b,
            const float* __restrict__ fc2w,
            const float* __restrict__ fc2b,
            const float* __restrict__ fc3w,
            const float* __restrict__ fc3b,
            float* __restrict__ ct,
            float* __restrict__ dout){
  const int n = blockIdx.x, l = threadIdx.x;
  const int g2 = l & 31, hh = l >> 5, co = hh * 16;
  __shared__ float ginS[6144];                 // 24 KB: summed gate inputs [t][96]
  __shared__ float h0sh[32], h1sh[32];
  __shared__ float hist[64][33];
  __shared__ float Wst[32][33];
  __shared__ float b1s[32], b2s[32], w3s[32];
  // ---- stage gin = G0+G1+G2 into LDS (independent float4 streams) ----
  {
    const float4* p0 = (const float4*)(G0 + n*16384);
    const float4* p1 = (const float4*)(G1 + n*16384);
    const float4* p2 = (const float4*)(G2 + n*8192);
    float4* gs = (float4*)ginS;
#pragma unroll 6
    for (int j = 0; j < 24; ++j){
      int idx = j*64 + l;
      float4 a = p0[idx], b = p1[idx], c = p2[idx];
      gs[idx] = make_float4(a.x+b.x+c.x, a.y+b.y+c.y, a.z+b.z+c.z, a.w+b.w+c.w);
    }
  }
  // ---- weight slices (144 VGPRs) ----
  float w0r[16], w0z[16], w0n[16];
  float wi1r[16], wi1z[16], wi1n[16];
  float wh1r[16], wh1z[16], wh1n[16];
  {
    const float* W0  = Whh0 + n*3072;
    const float* Wi1 = Wih1 + n*3072;
    const float* Wh1 = Whh1 + n*3072;
#pragma unroll
    for (int q = 0; q < 4; ++q){
      float4 v;
      v = *(const float4*)(W0 + g2*32 + co + 4*q);        w0r[4*q]=v.x; w0r[4*q+1]=v.y; w0r[4*q+2]=v.z; w0r[4*q+3]=v.w;
      v = *(const float4*)(W0 + (32+g2)*32 + co + 4*q);   w0z[4*q]=v.x; w0z[4*q+1]=v.y; w0z[4*q+2]=v.z; w0z[4*q+3]=v.w;
      v = *(const float4*)(W0 + (64+g2)*32 + co + 4*q);   w0n[4*q]=v.x; w0n[4*q+1]=v.y; w0n[4*q+2]=v.z; w0n[4*q+3]=v.w;
      v = *(const float4*)(Wi1 + g2*32 + co + 4*q);       wi1r[4*q]=v.x; wi1r[4*q+1]=v.y; wi1r[4*q+2]=v.z; wi1r[4*q+3]=v.w;
      v = *(const float4*)(Wi1 + (32+g2)*32 + co + 4*q);  wi1z[4*q]=v.x; wi1z[4*q+1]=v.y; wi1z[4*q+2]=v.z; wi1z[4*q+3]=v.w;
      v = *(const float4*)(Wi1 + (64+g2)*32 + co + 4*q);  wi1n[4*q]=v.x; wi1n[4*q+1]=v.y; wi1n[4*q+2]=v.z; wi1n[4*q+3]=v.w;
      v = *(const float4*)(Wh1 + g2*32 + co + 4*q);       wh1r[4*q]=v.x; wh1r[4*q+1]=v.y; wh1r[4*q+2]=v.z; wh1r[4*q+3]=v.w;
      v = *(const float4*)(Wh1 + (32+g2)*32 + co + 4*q);  wh1z[4*q]=v.x; wh1z[4*q+1]=v.y; wh1z[4*q+2]=v.z; wh1z[4*q+3]=v.w;
      v = *(const float4*)(Wh1 + (64+g2)*32 + co + 4*q);  wh1n[4*q]=v.x; wh1n[4*q+1]=v.y; wh1n[4*q+2]=v.z; wh1n[4*q+3]=v.w;
    }
  }
  const float bi0r = bih0[n*96 + g2], bi0z = bih0[n*96 + 32 + g2], bi0n = bih0[n*96 + 64 + g2];
  const float bh0r = bhh0[n*96 + g2], bh0z = bhh0[n*96 + 32 + g2], bh0n = bhh0[n*96 + 64 + g2];
  const float bi1r = bih1[n*96 + g2], bi1z = bih1[n*96 + 32 + g2], bi1n = bih1[n*96 + 64 + g2];
  const float bh1r = bhh1[n*96 + g2], bh1z = bhh1[n*96 + 32 + g2], bh1n = bhh1[n*96 + 64 + g2];
  // ---- FC-head staging hoisted before the recurrent loop ----
  if (l < 32){
    b1s[l] = fc1b[n*32 + l];
    b2s[l] = fc2b[n*32 + l];
    w3s[l] = fc3w[n*32 + l];
  }
  for (int idx = l; idx < 1024; idx += 64) Wst[idx>>5][idx&31] = fc1w[n*1024 + idx];
  // ---- state ----
  float h0own = Hpre[n*32 + g2];
  float h1own = Hpre[8192 + n*32 + g2];
  if (l < 32){ h0sh[l] = h0own; h1sh[l] = h1own; }
  __syncthreads();
  float h0s[16], h1s[16];
#pragma unroll
  for (int q = 0; q < 4; ++q){
    float4 v0 = *(const float4*)&h0sh[co + 4*q];
    float4 v1 = *(const float4*)&h1sh[co + 4*q];
    h0s[4*q]=v0.x; h0s[4*q+1]=v0.y; h0s[4*q+2]=v0.z; h0s[4*q+3]=v0.w;
    h1s[4*q]=v1.x; h1s[4*q+1]=v1.y; h1s[4*q+2]=v1.z; h1s[4*q+3]=v1.w;
  }
  for (int t = 0; t < 64; ++t){
    const float gir  = ginS[t*96 + g2];
    const float giz  = ginS[t*96 + 32 + g2];
    const float ginn = ginS[t*96 + 64 + g2];
    // ---- layer 0 ----
    float pr = 0.f, pz = 0.f, pn = 0.f;
#pragma unroll
    for (int j = 0; j < 16; ++j){
      pr = fmaf(w0r[j], h0s[j], pr);
      pz = fmaf(w0z[j], h0s[j], pz);
      pn = fmaf(w0n[j], h0s[j], pn);
    }
    pr += __shfl_xor(pr, 32);
    pz += __shfl_xor(pz, 32);
    pn += __shfl_xor(pn, 32);
    float r = sigf(gir + bi0r + pr + bh0r);
    float z = sigf(giz + bi0z + pz + bh0z);
    float nn = tanhfa(ginn + bi0n + r*(pn + bh0n));
    float h0new = (1.f - z)*nn + z*h0own;
    h0own = h0new;
    if (l < 32) h0sh[g2] = h0new;
    __syncthreads();
#pragma unroll
    for (int q = 0; q < 4; ++q){
      float4 v0 = *(const float4*)&h0sh[co + 4*q];
      h0s[4*q]=v0.x; h0s[4*q+1]=v0.y; h0s[4*q+2]=v0.z; h0s[4*q+3]=v0.w;
    }
    // ---- layer 1 ----
    float qr = 0.f, qz = 0.f, qn = 0.f, sr = 0.f, sz = 0.f, sn = 0.f;
#pragma unroll
    for (int j = 0; j < 16; ++j){
      qr = fmaf(wi1r[j], h0s[j], qr);  sr = fmaf(wh1r[j], h1s[j], sr);
      qz = fmaf(wi1z[j], h0s[j], qz);  sz = fmaf(wh1z[j], h1s[j], sz);
      qn = fmaf(wi1n[j], h0s[j], qn);  sn = fmaf(wh1n[j], h1s[j], sn);
    }
    float vr = qr + sr; vr += __shfl_xor(vr, 32);
    float vz = qz + sz; vz += __shfl_xor(vz, 32);
    qn += __shfl_xor(qn, 32);
    sn += __shfl_xor(sn, 32);
    float r1 = sigf(vr + bi1r + bh1r);
    float z1 = sigf(vz + bi1z + bh1z);
    float n1 = tanhfa(qn + bi1n + r1*(sn + bh1n));
    float h1new = (1.f - z1)*n1 + z1*h1own;
    h1own = h1new;
    if (l < 32){ h1sh[g2] = h1new; hist[t][g2] = h1new; }
    __syncthreads();
#pragma unroll
    for (int q = 0; q < 4; ++q){
      float4 v1 = *(const float4*)&h1sh[co + 4*q];
      h1s[4*q]=v1.x; h1s[4*q+1]=v1.y; h1s[4*q+2]=v1.z; h1s[4*q+3]=v1.w;
    }
  }
  if (l < 32){
    dout[16384 + n*32 + l]        = h0own;            // cat_H[0]
    dout[16384 + 8192 + n*32 + l] = h1own;            // cat_H[1]
  }
  // ---- fused FC head: lane = sensor s (64) ----
  float hr[32];
#pragma unroll
  for (int k = 0; k < 32; ++k) hr[k] = hist[l][k];
  float r1a[32];
#pragma unroll
  for (int k = 0; k < 32; ++k){
    float a0=0.f,a1=0.f,a2=0.f,a3=0.f;
#pragma unroll
    for (int q = 0; q < 32; q += 4){
      a0 = fmaf(hr[q],   Wst[k][q],   a0);
      a1 = fmaf(hr[q+1], Wst[k][q+1], a1);
      a2 = fmaf(hr[q+2], Wst[k][q+2], a2);
      a3 = fmaf(hr[q+3], Wst[k][q+3], a3);
    }
    float v = b1s[k] + ((a0+a1)+(a2+a3));
    r1a[k] = v > 0.f ? v : 0.f;
  }
  __syncthreads();
  for (int idx = l; idx < 1024; idx += 64) Wst[idx>>5][idx&31] = fc2w[n*1024 + idx];
  __syncthreads();
  float r2a[32];
#pragma unroll
  for (int k = 0; k < 32; ++k){
    float a0=0.f,a1=0.f,a2=0.f,a3=0.f;
#pragma unroll
    for (int q = 0; q < 32; q += 4){
      a0 = fmaf(r1a[q],   Wst[k][q],   a0);
      a1 = fmaf(r1a[q+1], Wst[k][q+1], a1);
      a2 = fmaf(r1a[q+2], Wst[k][q+2], a2);
      a3 = fmaf(r1a[q+3], Wst[k][q+3], a3);
    }
    float v = b2s[k] + ((a0+a1)+(a2+a3));
    r2a[k] = v > 0.f ? v : 0.f;
  }
  float v = fc3b[n];
#pragma unroll
  for (int k = 0; k < 32; ++k) v = fmaf(r2a[k], w3s[k], v);
  ct[n*64 + l] = v;
}

// ---- k8a: Wh (transposed) + f1/f2 for out & out1. grid 8 = gat*4 + row-quarter ----
__global__ __launch_bounds__(256) void k8a(const float* __restrict__ ct,
                                           const float* __restrict__ W0,
                                           const float* __restrict__ a0,
                                           const float* __restrict__ W1,
                                           const float* __restrict__ a1,
                                           float* __restrict__ WhABt,
                                           float* __restrict__ OF1,
                                           float* __restrict__ OF2){
  const int gat = blockIdx.x >> 2, rq = blockIdx.x & 3, r0 = rq*64;
  const int tid = threadIdx.x;
  const int ii = tid & 63, cq = tid >> 6;
  __shared__ float ctl[64][65];
  __shared__ float Wl[64][68];
  __shared__ float a1s[64], a2s[64];
  __shared__ float red[64][4][2];
  const float* W = gat ? W1 : W0;
  const float* aa = gat ? a1 : a0;
  for (int idx = tid; idx < 4096; idx += 256){
    int i2 = idx >> 6, k = idx & 63;
    ctl[i2][k] = ct[(r0 + i2)*64 + k];
  }
  for (int idx = tid; idx < 4096; idx += 256){
    int k = idx >> 6, c = idx & 63;
    Wl[k][c] = W[k*64 + c];
  }
  if (tid < 64){ a1s[tid] = aa[tid]; a2s[tid] = aa[64 + tid]; }
  __syncthreads();
  float acc[16];
#pragma unroll
  for (int c = 0; c < 16; ++c) acc[c] = 0.f;
#pragma unroll 2
  for (int k = 0; k < 64; ++k){
    float v = ctl[ii][k];
    const float* wr = &Wl[k][cq*16];
#pragma unroll
    for (int c = 0; c < 16; ++c) acc[c] = fmaf(v, wr[c], acc[c]);
  }
  float p1 = 0.f, p2 = 0.f;
#pragma unroll
  for (int c = 0; c < 16; ++c){
    p1 = fmaf(acc[c], a1s[cq*16 + c], p1);
    p2 = fmaf(acc[c], a2s[cq*16 + c], p2);
  }
  red[ii][cq][0] = p1; red[ii][cq][1] = p2;
  float* o = WhABt + gat*16384;
#pragma unroll
  for (int c = 0; c < 16; ++c) o[(cq*16 + c)*256 + r0 + ii] = acc[c];
  __syncthreads();
  if (cq == 0){
    OF1[gat*256 + r0 + ii] = red[ii][0][0] + red[ii][1][0] + red[ii][2][0] + red[ii][3][0];
    OF2[gat*256 + r0 + ii] = red[ii][0][1] + red[ii][1][1] + red[ii][2][1] + red[ii][3][1];
  }
}

// ---- k8b: out/out1 attention. grid 8 = gat*4 + c-tile(16) ----
__global__ __launch_bounds__(256) void k8b(const float* __restrict__ WhABt,
                                           const float* __restrict__ OF1,
                                           const float* __restrict__ OF2,
                                           const unsigned* __restrict__ maskA,
                                           float* __restrict__ OUTT){
  const int gat = blockIdx.x >> 2, c0 = (blockIdx.x & 3) * 16;
  const int i = threadIdx.x;
  __shared__ float f2s[256];
  __shared__ float wt[64][36];
  const float f1 = OF1[gat*256 + i];
  f2s[i] = OF2[gat*256 + i];
  unsigned mw[8];
#pragma unroll
  for (int w = 0; w < 8; ++w) mw[w] = maskA[i*8 + w];
  __syncthreads();
  float m = -INFINITY;
  for (int w = 0; w < 8; ++w){
    const unsigned mk = mw[w];
#pragma unroll
    for (int bb = 0; bb < 32; ++bb){
      float e = f1 + f2s[(w<<5)+bb]; e = (e > 0.f) ? e : ALPHA*e;
      e = ((mk >> bb) & 1u) ? e : NEGV;
      m = fmaxf(m, e);
    }
  }
  float s = 0.f;
  for (int w = 0; w < 8; ++w){
    const unsigned mk = mw[w];
#pragma unroll
    for (int bb = 0; bb < 32; ++bb){
      float e = f1 + f2s[(w<<5)+bb]; e = (e > 0.f) ? e : ALPHA*e;
      e = ((mk >> bb) & 1u) ? e : NEGV;
      s += __expf(e - m);
    }
  }
  const float inv = 1.f / s;
  float acc[16];
#pragma unroll
  for (int c = 0; c < 16; ++c) acc[c] = 0.f;
  for (int jt = 0; jt < 4; ++jt){
    __syncthreads();
    for (int idx = i; idx < 1024; idx += 256){
      int cc = idx >> 6, jj = idx & 63;
      wt[jj][cc] = WhABt[gat*16384 + (c0+cc)*256 + (jt<<6) + jj];
    }
    __syncthreads();
    for (int jj = 0; jj < 64; ++jj){
      const int j = (jt<<6) + jj;
      float e = f1 + f2s[j]; e = (e > 0.f) ? e : ALPHA*e;
      e = ((mw[j>>5] >> (j & 31)) & 1u) ? e : NEGV;
      const float p = __expf(e - m) * inv;
      const float* wr = &wt[jj][0];
#pragma unroll
      for (int c = 0; c < 16; ++c) acc[c] = fmaf(p, wr[c], acc[c]);
    }
  }
#pragma unroll
  for (int c = 0; c < 16; ++c) OUTT[gat*16384 + (c0+c)*256 + i] = acc[c];
}

// ---- k8c: Wh2 (transposed) + F1B/F2B. grid 8 = 32-row chunks ----
__global__ __launch_bounds__(256) void k8c(const float* __restrict__ OUTT,
                                           const float* __restrict__ W2,
                                           const float* __restrict__ a2,
                                           float* __restrict__ Wh2,
                                           float* __restrict__ F1B,
                                           float* __restrict__ F2B){
  const int r0 = blockIdx.x * 32;
  const int tid = threadIdx.x;
  const int ii = tid & 31, cq = tid >> 5;      // 8 groups x 8 cols
  __shared__ float W2l[128][68];
  __shared__ float a1s[64], a2s[64];
  __shared__ float red[32][8][2];
  for (int idx = tid; idx < 8192; idx += 256){
    int k = idx >> 6, c = idx & 63;
    W2l[k][c] = W2[k*64 + c];
  }
  if (tid < 64){ a1s[tid] = a2[tid]; a2s[tid] = a2[64 + tid]; }
  __syncthreads();
  float acc[8];
#pragma unroll
  for (int c = 0; c < 8; ++c) acc[c] = 0.f;
#pragma unroll 2
  for (int k = 0; k < 128; ++k){
    float v = OUTT[(k >> 6)*16384 + (k & 63)*256 + r0 + ii];
    const float* wr = &W2l[k][cq*8];
#pragma unroll
    for (int c = 0; c < 8; ++c) acc[c] = fmaf(v, wr[c], acc[c]);
  }
  float p1 = 0.f, p2 = 0.f;
#pragma unroll
  for (int c = 0; c < 8; ++c){
    p1 = fmaf(acc[c], a1s[cq*8 + c], p1);
    p2 = fmaf(acc[c], a2s[cq*8 + c], p2);
  }
  red[ii][cq][0] = p1; red[ii][cq][1] = p2;
#pragma unroll
  for (int c = 0; c < 8; ++c) Wh2[(cq*8 + c)*256 + r0 + ii] = acc[c];
  __syncthreads();
  if (cq == 0){
    float s1 = 0.f, s2 = 0.f;
#pragma unroll
    for (int q = 0; q < 8; ++q){ s1 += red[ii][q][0]; s2 += red[ii][q][1]; }
    F1B[r0 + ii] = s1; F2B[r0 + ii] = s2;
  }
}

// ---- k8d: final GAT -> d_out. grid 4 = c-tiles(16) ----
__global__ __launch_bounds__(256) void k8d(const float* __restrict__ Wh2,
                                           const float* __restrict__ F1B,
                                           const float* __restrict__ F2B,
                                           const unsigned* __restrict__ maskA,
                                           float* __restrict__ dOut){
  const int c0 = blockIdx.x * 16;
  const int i = threadIdx.x;
  __shared__ float f2s[256];
  __shared__ float wt[64][36];
  const float f1 = F1B[i];
  f2s[i] = F2B[i];
  unsigned mw[8];
#pragma unroll
  for (int w = 0; w < 8; ++w) mw[w] = maskA[i*8 + w];
  __syncthreads();
  float m = -INFINITY;
  for (int w = 0; w < 8; ++w){
    const unsigned mk = mw[w];
#pragma unroll
    for (int bb = 0; bb < 32; ++bb){
      float e = f1 + f2s[(w<<5)+bb]; e = (e > 0.f) ? e : ALPHA*e;
      e = ((mk >> bb) & 1u) ? e : NEGV;
      m = fmaxf(m, e);
    }
  }
  float s = 0.f;
  for (int w = 0; w < 8; ++w){
    const unsigned mk = mw[w];
#pragma unroll
    for (int bb = 0; bb < 32; ++bb){
      float e = f1 + f2s[(w<<5)+bb]; e = (e > 0.f) ? e : ALPHA*e;
      e = ((mk >> bb) & 1u) ? e : NEGV;
      s += __expf(e - m);
    }
  }
  const float inv = 1.f / s;
  float acc[16];
#pragma unroll
  for (int c = 0; c < 16; ++c) acc[c] = 0.f;
  for (int jt = 0; jt < 4; ++jt){
    __syncthreads();
    for (int idx = i; idx < 1024; idx += 256){
      int cc = idx >> 6, jj = idx & 63;
      wt[jj][cc] = Wh2[(c0+cc)*256 + (jt<<6) + jj];
    }
    __syncthreads();
    for (int jj = 0; jj < 64; ++jj){
      const int j = (jt<<6) + jj;
      float e = f1 + f2s[j]; e = (e > 0.f) ? e : ALPHA*e;
      e = ((mw[j>>5] >> (j & 31)) & 1u) ? e : NEGV;
      const float p = __expf(e - m) * inv;
      const float* wr = &wt[jj][0];
#pragma unroll
      for (int c = 0; c < 16; ++c) acc[c] = fmaf(p, wr[c], acc[c]);
    }
  }
#pragma unroll
  for (int c = 0; c < 16; ++c) dOut[i*64 + c0 + c] = acc[c];
}

extern "C" void kernel_launch(void* const* d_in, const int* in_sizes, int n_in,
                              void* d_out, int out_size, void* d_ws, size_t ws_size,
                              hipStream_t stream){
  (void)in_sizes; (void)n_in; (void)out_size; (void)ws_size;
  const float* x     = (const float*)d_in[0];
  const float* Fadj  = (const float*)d_in[1];
  const float* Tadj  = (const float*)d_in[2];
  const float* adj   = (const float*)d_in[3];
  const float* Hpre  = (const float*)d_in[4];
  const float* FattW = (const float*)d_in[5];
  const float* Fatta = (const float*)d_in[6];
  const float* TattW = (const float*)d_in[7];
  const float* Tatta = (const float*)d_in[8];
  const float* Wih0  = (const float*)d_in[9];
  const float* Whh0  = (const float*)d_in[10];
  const float* bih0  = (const float*)d_in[11];
  const float* bhh0  = (const float*)d_in[12];
  const float* Wih1  = (const float*)d_in[13];
  const float* Whh1  = (const float*)d_in[14];
  const float* bih1  = (const float*)d_in[15];
  const float* bhh1  = (const float*)d_in[16];
  const float* fc1w  = (const float*)d_in[17];
  const float* fc1b  = (const float*)d_in[18];
  const float* fc2w  = (const float*)d_in[19];
  const float* fc2b  = (const float*)d_in[20];
  const float* fc3w  = (const float*)d_in[21];
  const float* fc3b  = (const float*)d_in[22];
  const float* oW    = (const float*)d_in[23];
  const float* oa    = (const float*)d_in[24];
  const float* o1W   = (const float*)d_in[25];
  const float* o1a   = (const float*)d_in[26];
  const float* o2W   = (const float*)d_in[27];
  const float* o2a   = (const float*)d_in[28];
  float* out = (float*)d_out;

  float* ws = (float*)d_ws;
  float* R0 = ws;
  float* R1 = ws + 4194304;
  float* R2 = ws + 8388608;
  unsigned* maskT = (unsigned*)R2;             // 524288 words
  float* Tf1p = R2 + 524288;                   // 2 x 65536
  float* Tf2p = R2 + 655360;                   // 2 x 65536
  unsigned* maskA = (unsigned*)(ws + 12582912);// 2048 words
  float* WhTt = R0;
  float* WhF  = R0;
  float* TatT = R1;
  float* Fat  = R2;
  // k5 partials: P0 over Fat slots (stride 16384, only-reader-is-writer),
  // P1 over TatT slots (stride 16384), P2 compact in R0 (stride 8192).
  float* P0 = R2;
  float* P1 = R1;
  float* P2 = R0;
  float* ctb   = R0 + 2097152;                 // above P2's 2.1M-float span
  float* WhABt = R1 + 16384;
  float* OF1   = R1 + 49152;
  float* OF2   = R1 + 49664;
  float* OUTT  = R1 + 50176;
  float* WH2   = R1 + 82944;
  float* F1B   = R1 + 99328;
  float* F2B   = R1 + 99584;

  k_mask<<<1024, 256, 0, stream>>>(Tadj, maskT, 16777216);
  k_mask<<<32, 256, 0, stream>>>(adj, maskA, 65536);
  k3_wht<<<512, 256, 0, stream>>>(x, TattW, Tatta, WhTt, Tf1p, Tf2p);
  k4_tat<<<512, 256, 0, stream>>>(WhTt, Tf1p, Tf2p, maskT, TatT);
  k1_whf<<<256, 512, 0, stream>>>(x, FattW, WhF);
  k2_fat<<<256, 512, 0, stream>>>(WhF, Fatta, Fadj, Fat);
  k5_gi0<<<768, 256, 0, stream>>>(Fat, TatT, x, Wih0, P0, P1, P2);
  k6_gru<<<256, 64, 0, stream>>>(P0, P1, P2, Hpre, Whh0, bih0, bhh0, Wih1, Whh1, bih1, bhh1,
                                 fc1w, fc1b, fc2w, fc2b, fc3w, fc3b, ctb, out);
  k8a<<<8, 256, 0, stream>>>(ctb, oW, oa, o1W, o1a, WhABt, OF1, OF2);
  k8b<<<8, 256, 0, stream>>>(WhABt, OF1, OF2, maskA, OUTT);
  k8c<<<8, 256, 0, stream>>>(OUTT, o2W, o2a, WH2, F1B, F2B);
  k8d<<<4, 256, 0, stream>>>(WH2, F1B, F2B, maskA, out);
}

// Round 3
// 672.662 us; speedup vs baseline: 1.2840x; 1.1768x over previous
//
#include <hip/hip_runtime.h>
#include <hip/hip_bf16.h>

__device__ __forceinline__ float sigf(float x){ return __builtin_amdgcn_rcpf(1.f+__expf(-x)); }
__device__ __forceinline__ float tanhfa(float x){
  return 1.f - 2.f*__builtin_amdgcn_rcpf(1.f + __expf(2.f*x));
}

#define ALPHA 0.2f
#define NEGV  -9e15f

// N=256 nodes, S=64 sensors, W=256 window, H=32 hidden. All fp32.

__device__ __forceinline__ void gl2lds16(const float* g, float* l){
  __builtin_amdgcn_global_load_lds(
      (const __attribute__((address_space(1))) void*)g,
      (__attribute__((address_space(3))) void*)l, 16, 0, 0);
}

// ---- k_mask: pack adjacency fp32 (0/1) -> bitmask via wave ballot ----
__global__ __launch_bounds__(256) void k_mask(const float* __restrict__ src,
                                              unsigned* __restrict__ dst, int nelem){
  const int stride = gridDim.x * blockDim.x;
  const int lane = threadIdx.x & 63;
  for (int e = blockIdx.x*blockDim.x + threadIdx.x; e < nelem; e += stride){
    unsigned long long m = __ballot(src[e] > 0.f);
    if (lane == 0)       dst[e >> 5] = (unsigned)m;
    else if (lane == 32) dst[e >> 5] = (unsigned)(m >> 32);
  }
}

// ---- k3: Wh_T (transposed store) + Tf1/Tf2 partials. grid 512 = n*2 + c-half ----
__global__ __launch_bounds__(256) void k3_wht(const float* __restrict__ x,
                                              const float* __restrict__ TW,
                                              const float* __restrict__ Ta,
                                              float* __restrict__ WhTt,
                                              float* __restrict__ Tf1p,
                                              float* __restrict__ Tf2p){
  const int n = blockIdx.x >> 1, ch = blockIdx.x & 1, c0 = ch*32;
  const int tid = threadIdx.x;
  __shared__ float Wm[64][36];
  __shared__ float as1[32], as2[32];
  for (int idx = tid; idx < 2048; idx += 256){
    int k = idx >> 5, cc = idx & 31;
    Wm[k][cc] = TW[n*4096 + k*64 + c0 + cc];
  }
  if (tid < 32){ as1[tid] = Ta[n*128 + c0 + tid]; as2[tid] = Ta[n*128 + 64 + c0 + tid]; }
  __syncthreads();
  const int i = tid;
  const float* xn = x + n*16384;
  float acc[32];
#pragma unroll
  for (int c = 0; c < 32; ++c) acc[c] = 0.f;
#pragma unroll 2
  for (int k = 0; k < 64; ++k){
    float xv = xn[k*256 + i];                  // coalesced
    const float* wr = &Wm[k][0];               // broadcast b128
#pragma unroll
    for (int c = 0; c < 32; ++c) acc[c] = fmaf(xv, wr[c], acc[c]);
  }
  float f1 = 0.f, f2 = 0.f;
#pragma unroll
  for (int c = 0; c < 32; ++c){ f1 = fmaf(acc[c], as1[c], f1); f2 = fmaf(acc[c], as2[c], f2); }
  Tf1p[ch*65536 + n*256 + i] = f1;
  Tf2p[ch*65536 + n*256 + i] = f2;
  float* o = WhTt + n*16384;
#pragma unroll
  for (int c = 0; c < 32; ++c) o[(c0+c)*256 + i] = acc[c];
}

// ---- k4: time-GAT attention. grid 512 = n*2 + c-half, thread = window row i ----
__global__ __launch_bounds__(256) void k4_tat(const float* __restrict__ WhTt,
                                              const float* __restrict__ Tf1p,
                                              const float* __restrict__ Tf2p,
                                              const unsigned* __restrict__ maskT,
                                              float* __restrict__ TatT){
  const int n = blockIdx.x >> 1, ch = blockIdx.x & 1, c0 = ch*32;
  const int i = threadIdx.x;
  __shared__ float f2s[256];
  __shared__ float wt[64][36];
  const float f1 = Tf1p[n*256 + i] + Tf1p[65536 + n*256 + i];
  f2s[i] = Tf2p[n*256 + i] + Tf2p[65536 + n*256 + i];
  unsigned mw[8];
#pragma unroll
  for (int w = 0; w < 8; ++w) mw[w] = maskT[n*2048 + i*8 + w];
  __syncthreads();
  float m = -INFINITY;
  for (int w = 0; w < 8; ++w){
    const unsigned mk = mw[w];
#pragma unroll
    for (int bb = 0; bb < 32; ++bb){
      float e = f1 + f2s[(w<<5)+bb]; e = (e > 0.f) ? e : ALPHA*e;
      e = ((mk >> bb) & 1u) ? e : NEGV;
      m = fmaxf(m, e);
    }
  }
  float s = 0.f;
  for (int w = 0; w < 8; ++w){
    const unsigned mk = mw[w];
#pragma unroll
    for (int bb = 0; bb < 32; ++bb){
      float e = f1 + f2s[(w<<5)+bb]; e = (e > 0.f) ? e : ALPHA*e;
      e = ((mk >> bb) & 1u) ? e : NEGV;
      s += __expf(e - m);
    }
  }
  const float inv = 1.f / s;
  float acc[32];
#pragma unroll
  for (int c = 0; c < 32; ++c) acc[c] = 0.f;
  for (int jt = 0; jt < 4; ++jt){
    __syncthreads();
    for (int idx = i; idx < 2048; idx += 256){
      int cc = idx >> 6, jj = idx & 63;
      wt[jj][cc] = WhTt[n*16384 + (c0+cc)*256 + (jt<<6) + jj];   // coalesced
    }
    __syncthreads();
    for (int jj = 0; jj < 64; ++jj){
      const int j = (jt<<6) + jj;
      float e = f1 + f2s[j]; e = (e > 0.f) ? e : ALPHA*e;
      e = ((mw[j>>5] >> (j & 31)) & 1u) ? e : NEGV;
      const float p = __expf(e - m) * inv;
      const float* wr = &wt[jj][0];            // broadcast b128
#pragma unroll
      for (int c = 0; c < 32; ++c) acc[c] = fmaf(p, wr[c], acc[c]);
    }
  }
  float* o = TatT + n*16384;
#pragma unroll
  for (int c = 0; c < 32; ++c) o[(c0+c)*256 + i] = acc[c];
}

// ---- k1: Wh_F = x @ Fatt_W. grid 512 = n*2 + c-half(128), block 256 ----
// x staged linearly to LDS via global_load_lds; thread tiles 8i x 4c; inner
// loop per 4-k chunk: 8 ds_read_b128 (2 addrs/wave -> broadcast) + 4 float4
// coalesced W loads + 128 FMA (FMA:LDS-float = 4:1).
__global__ __launch_bounds__(256) void k1_whf(const float* __restrict__ x,
                                              const float* __restrict__ FW,
                                              float* __restrict__ WhF){
  const int n = blockIdx.x >> 1, ch = blockIdx.x & 1, c0 = ch*128;
  const int tid = threadIdx.x;
  __shared__ float xt[16384];                  // [i][k] linear, 64 KB
  {
    const int w = tid >> 6, l = tid & 63;
    const float* xg = x + n*16384 + w*4096 + l*4;
    float* ld = &xt[w*4096];
#pragma unroll
    for (int j = 0; j < 16; ++j) gl2lds16(xg + j*256, ld + j*256);
  }
  asm volatile("s_waitcnt vmcnt(0)" ::: "memory");
  __syncthreads();
  const int cq = tid & 31, iq = tid >> 5;      // c-quad, i-group(8 rows)
  const int cc = c0 + cq*4;
  const float* Wn = FW + (size_t)n*65536 + cc;
  const float* xrow = &xt[iq*8*256];
  float acc[8][4];
#pragma unroll
  for (int i = 0; i < 8; ++i)
#pragma unroll
    for (int c = 0; c < 4; ++c) acc[i][c] = 0.f;
#pragma unroll 2
  for (int k4 = 0; k4 < 64; ++k4){
    const float4 w0 = *(const float4*)&Wn[(4*k4+0)*256];
    const float4 w1 = *(const float4*)&Wn[(4*k4+1)*256];
    const float4 w2 = *(const float4*)&Wn[(4*k4+2)*256];
    const float4 w3 = *(const float4*)&Wn[(4*k4+3)*256];
#pragma unroll
    for (int i = 0; i < 8; ++i){
      const float4 xv = *(const float4*)&xrow[i*256 + 4*k4];
      acc[i][0] = fmaf(xv.x, w0.x, acc[i][0]); acc[i][0] = fmaf(xv.y, w1.x, acc[i][0]);
      acc[i][0] = fmaf(xv.z, w2.x, acc[i][0]); acc[i][0] = fmaf(xv.w, w3.x, acc[i][0]);
      acc[i][1] = fmaf(xv.x, w0.y, acc[i][1]); acc[i][1] = fmaf(xv.y, w1.y, acc[i][1]);
      acc[i][1] = fmaf(xv.z, w2.y, acc[i][1]); acc[i][1] = fmaf(xv.w, w3.y, acc[i][1]);
      acc[i][2] = fmaf(xv.x, w0.z, acc[i][2]); acc[i][2] = fmaf(xv.y, w1.z, acc[i][2]);
      acc[i][2] = fmaf(xv.z, w2.z, acc[i][2]); acc[i][2] = fmaf(xv.w, w3.z, acc[i][2]);
      acc[i][3] = fmaf(xv.x, w0.w, acc[i][3]); acc[i][3] = fmaf(xv.y, w1.w, acc[i][3]);
      acc[i][3] = fmaf(xv.z, w2.w, acc[i][3]); acc[i][3] = fmaf(xv.w, w3.w, acc[i][3]);
    }
  }
  float* o = WhF + n*16384 + cc;
#pragma unroll
  for (int i = 0; i < 8; ++i)
    *(float4*)&o[(iq*8 + i)*256] = make_float4(acc[i][0], acc[i][1], acc[i][2], acc[i][3]);
}

// ---- k2: feature-GAT softmax + Fat = att @ Wh. grid 256, block 512 (i-split) ----
__global__ __launch_bounds__(512) void k2_fat(const float* __restrict__ WhF,
                                              const float* __restrict__ Fa,
                                              const float* __restrict__ Fadj,
                                              float* __restrict__ Fat){
  const int n = blockIdx.x, tid = threadIdx.x;
  __shared__ float attT[64][68];               // attT[j][i]
  __shared__ float f1s[64], f2s[64];
  __shared__ float part[64][8][2];
  const float* Wh = WhF + n*16384;
  { // f1/f2: thread (i=tid>>3, q=tid&7) partial over 32 cols
    int i = tid >> 3, q = tid & 7;
    const float* an = Fa + n*512;
    float p1 = 0.f, p2 = 0.f;
    for (int cc = 0; cc < 32; ++cc){
      int c2 = q*32 + cc;
      float w = Wh[i*256 + c2];
      p1 = fmaf(w, an[c2], p1);
      p2 = fmaf(w, an[256 + c2], p2);
    }
    part[i][q][0] = p1; part[i][q][1] = p2;
  }
  __syncthreads();
  if (tid < 64){
    float s1 = 0.f, s2 = 0.f;
#pragma unroll
    for (int q = 0; q < 8; ++q){ s1 += part[tid][q][0]; s2 += part[tid][q][1]; }
    f1s[tid] = s1; f2s[tid] = s2;
  }
  __syncthreads();
  if (tid < 64){                               // masked softmax row -> attT column
    const int r = tid;
    const float f1 = f1s[r];
    const float* adjr = Fadj + n*4096 + r*64;
    unsigned m0 = 0, m1 = 0;
#pragma unroll
    for (int j = 0; j < 32; ++j) if (adjr[j] > 0.f) m0 |= (1u << j);
#pragma unroll
    for (int j = 0; j < 32; ++j) if (adjr[32+j] > 0.f) m1 |= (1u << j);
    float m = -INFINITY;
#pragma unroll
    for (int j = 0; j < 64; ++j){
      float e = f1 + f2s[j]; e = (e > 0.f) ? e : ALPHA*e;
      unsigned bit = (j < 32) ? ((m0 >> j) & 1u) : ((m1 >> (j-32)) & 1u);
      e = bit ? e : NEGV;
      m = fmaxf(m, e);
    }
    float s = 0.f;
#pragma unroll
    for (int j = 0; j < 64; ++j){
      float e = f1 + f2s[j]; e = (e > 0.f) ? e : ALPHA*e;
      unsigned bit = (j < 32) ? ((m0 >> j) & 1u) : ((m1 >> (j-32)) & 1u);
      e = bit ? e : NEGV;
      s += __expf(e - m);
    }
    const float inv = 1.f / s;
#pragma unroll
    for (int j = 0; j < 64; ++j){
      float e = f1 + f2s[j]; e = (e > 0.f) ? e : ALPHA*e;
      unsigned bit = (j < 32) ? ((m0 >> j) & 1u) : ((m1 >> (j-32)) & 1u);
      e = bit ? e : NEGV;
      attT[j][r] = __expf(e - m) * inv;
    }
  }
  __syncthreads();
  const int c = tid & 255, ih = tid >> 8;      // ih: 32-row half of output
  float acc[32];
#pragma unroll
  for (int i = 0; i < 32; ++i) acc[i] = 0.f;
#pragma unroll 2
  for (int j = 0; j < 64; ++j){
    float w = Wh[j*256 + c];                   // coalesced, L2-hot
    const float* ar = &attT[j][ih*32];         // broadcast b128 (16B-aligned)
#pragma unroll
    for (int i = 0; i < 32; ++i) acc[i] = fmaf(ar[i], w, acc[i]);
  }
  float* o = Fat + n*16384;
#pragma unroll
  for (int i = 0; i < 32; ++i) o[(ih*32 + i)*256 + c] = acc[i];
}

// ---- k5: partial Gi0 = cat_seg @ Wih0_seg^T. grid 768 = s*256 + n ----
__global__ __launch_bounds__(256) void k5_gi0(const float* __restrict__ Fat,
                                              const float* __restrict__ TatT,
                                              const float* __restrict__ x,
                                              const float* __restrict__ Wih0,
                                              float* __restrict__ P0,
                                              float* __restrict__ P1,
                                              float* __restrict__ P2){
  const int n = blockIdx.x & 255, s = blockIdx.x >> 8;
  const int tid = threadIdx.x;
  const int l = tid & 63, w = tid >> 6;        // lane, wave
  const int a = tid & 31, b = tid >> 5;        // t-pair lane, gate group (0..7)
  __shared__ float cl[2][2048];                // cat tile [64 t][32 k], dbuf, 16 KB
  __shared__ float wl[2][3072];                // W tile  [96 g][32 k], dbuf, 24 KB
  const float* src = (s == 0) ? (Fat + n*16384)
                   : (s == 1) ? (TatT + n*16384)
                              : (x + n*16384);
  const float* Wseg = Wih0 + (size_t)n*73728 + s*256;
  const int lr = l >> 3, lc = l & 7, sc = lc ^ lr;       // sc: swizzled cat col4
  const float* cg0 = src + (16*w + lr)*256 + sc*4;       // cat rows 16w..16w+7
  const float* cg1 = cg0 + 8*256;                        // cat rows +8
  const float* wg0 = Wseg + (size_t)(24*w + lr)*768 + lc*4;  // W rows 24w..+7
  const float* wg1 = wg0 + (size_t)8*768;
  const float* wg2 = wg0 + (size_t)16*768;

#define K5_STAGE(BF, K0) do {                       \
    gl2lds16(cg0 + (K0), &cl[BF][512*w]);           \
    gl2lds16(cg1 + (K0), &cl[BF][512*w + 256]);     \
    gl2lds16(wg0 + (K0), &wl[BF][768*w]);           \
    gl2lds16(wg1 + (K0), &wl[BF][768*w + 256]);     \
    gl2lds16(wg2 + (K0), &wl[BF][768*w + 512]);     \
  } while (0)

  float acc[12][2];
#pragma unroll
  for (int gi = 0; gi < 12; ++gi){ acc[gi][0] = 0.f; acc[gi][1] = 0.f; }

  int bf = 0;
  K5_STAGE(0, 0);
  const int ax4 = (a & 7) << 2;
#pragma unroll 1
  for (int kt = 0; kt < 8; ++kt){
    if (kt < 7){
      K5_STAGE(bf ^ 1, (kt + 1) * 32);
      asm volatile("s_waitcnt vmcnt(5)" ::: "memory");  // current tile landed
    } else {
      asm volatile("s_waitcnt vmcnt(0)" ::: "memory");
    }
    __builtin_amdgcn_s_barrier();
    const float* clb  = &cl[bf][a*32];
    const float* clb2 = &cl[bf][(a+32)*32];
    const float* wlb  = &wl[bf][b*384];
#pragma unroll
    for (int k4 = 0; k4 < 8; ++k4){
      const int j4 = (k4 << 2) ^ ax4;                   // swizzled read col
      const float4 c0 = *(const float4*)&clb[j4];
      const float4 c1 = *(const float4*)&clb2[j4];
#pragma unroll
      for (int gi = 0; gi < 12; ++gi){
        const float4 wv = *(const float4*)&wlb[gi*32 + (k4 << 2)];
        float a0 = acc[gi][0], a1 = acc[gi][1];
        a0 = fmaf(wv.x, c0.x, a0); a1 = fmaf(wv.x, c1.x, a1);
        a0 = fmaf(wv.y, c0.y, a0); a1 = fmaf(wv.y, c1.y, a1);
        a0 = fmaf(wv.z, c0.z, a0); a1 = fmaf(wv.z, c1.z, a1);
        a0 = fmaf(wv.w, c0.w, a0); a1 = fmaf(wv.w, c1.w, a1);
        acc[gi][0] = a0; acc[gi][1] = a1;
      }
    }
    __builtin_amdgcn_s_barrier();
    bf ^= 1;
  }
#undef K5_STAGE
  float* o = (s == 0) ? (P0 + n*16384)
           : (s == 1) ? (P1 + n*16384)
                      : (P2 + n*8192);
#pragma unroll
  for (int q = 0; q < 3; ++q){
    *(float4*)&o[a*96 + b*12 + q*4] =
        make_float4(acc[4*q][0], acc[4*q+1][0], acc[4*q+2][0], acc[4*q+3][0]);
    *(float4*)&o[(a+32)*96 + b*12 + q*4] =
        make_float4(acc[4*q][1], acc[4*q+1][1], acc[4*q+2][1], acc[4*q+3][1]);
  }
}

// ---- k6: 2-layer GRU, wave-pipelined. block 128 = wave0 (layer0) + wave1
// (layer1, one step behind). Handoff via double-buffered 32-float LDS slots,
// one barrier per slot. Each wave holds only its layer's weights -> no spill.
__global__ __launch_bounds__(128) void k6_gru(const float* __restrict__ G0,
                                              const float* __restrict__ G1,
                                              const float* __restrict__ G2,
                                              const float* __restrict__ Hpre,
                                              const float* __restrict__ Whh0,
                                              const float* __restrict__ bih0,
                                              const float* __restrict__ bhh0,
                                              const float* __restrict__ Wih1,
                                              const float* __restrict__ Whh1,
                                              const float* __restrict__ bih1,
                                              const float* __restrict__ bhh1,
                                              const float* __restrict__ fc1w,
                                              const float* __restrict__ fc1b,
                                              const float* __restrict__ fc2w,
                                              const float* __restrict__ fc2b,
                                              const float* __restrict__ fc3w,
                                              const float* __restrict__ fc3b,
                                              float* __restrict__ ct,
                                              float* __restrict__ dout){
  const int n = blockIdx.x, tid = threadIdx.x;
  const int wid = tid >> 6, l = tid & 63;
  const int g2 = l & 31, co = (l >> 5) * 16;
  __shared__ float ginS[6144];                 // 24 KB summed gate inputs [t][96]
  __shared__ float h0buf[2][32];
  __shared__ float h1buf[2][32];
  __shared__ float hist[64][33];
  __shared__ float Wst[32][33];
  __shared__ float b1s[32], b2s[32], w3s[32];
  // ---- stage gin = G0+G1+G2 (128 threads, 12 float4 each) ----
  {
    const float4* p0 = (const float4*)(G0 + n*16384);
    const float4* p1 = (const float4*)(G1 + n*16384);
    const float4* p2 = (const float4*)(G2 + n*8192);
    float4* gs = (float4*)ginS;
#pragma unroll
    for (int j = 0; j < 12; ++j){
      int idx = j*128 + tid;
      float4 a = p0[idx], b = p1[idx], c = p2[idx];
      gs[idx] = make_float4(a.x+b.x+c.x, a.y+b.y+c.y, a.z+b.z+c.z, a.w+b.w+c.w);
    }
  }
  // ---- FC-head staging ----
  if (tid < 32){
    b1s[tid] = fc1b[n*32 + tid];
    b2s[tid] = fc2b[n*32 + tid];
    w3s[tid] = fc3w[n*32 + tid];
  }
  for (int idx = tid; idx < 1024; idx += 128) Wst[idx>>5][idx&31] = fc1w[n*1024 + idx];
  // ---- per-wave weights (wave0: Whh0; wave1: Wih1 + Whh1) ----
  float wr_[16], wz_[16], wn_[16];
  float ur_[16], uz_[16], un_[16];
  {
    const float* WA = (wid == 0) ? (Whh0 + n*3072) : (Wih1 + n*3072);
#pragma unroll
    for (int q = 0; q < 4; ++q){
      float4 v;
      v = *(const float4*)(WA + g2*32 + co + 4*q);       wr_[4*q]=v.x; wr_[4*q+1]=v.y; wr_[4*q+2]=v.z; wr_[4*q+3]=v.w;
      v = *(const float4*)(WA + (32+g2)*32 + co + 4*q);  wz_[4*q]=v.x; wz_[4*q+1]=v.y; wz_[4*q+2]=v.z; wz_[4*q+3]=v.w;
      v = *(const float4*)(WA + (64+g2)*32 + co + 4*q);  wn_[4*q]=v.x; wn_[4*q+1]=v.y; wn_[4*q+2]=v.z; wn_[4*q+3]=v.w;
    }
    if (wid == 1){
      const float* WB = Whh1 + n*3072;
#pragma unroll
      for (int q = 0; q < 4; ++q){
        float4 v;
        v = *(const float4*)(WB + g2*32 + co + 4*q);       ur_[4*q]=v.x; ur_[4*q+1]=v.y; ur_[4*q+2]=v.z; ur_[4*q+3]=v.w;
        v = *(const float4*)(WB + (32+g2)*32 + co + 4*q);  uz_[4*q]=v.x; uz_[4*q+1]=v.y; uz_[4*q+2]=v.z; uz_[4*q+3]=v.w;
        v = *(const float4*)(WB + (64+g2)*32 + co + 4*q);  un_[4*q]=v.x; un_[4*q+1]=v.y; un_[4*q+2]=v.z; un_[4*q+3]=v.w;
      }
    }
  }
  const float* bip = (wid == 0) ? bih0 : bih1;
  const float* bhp = (wid == 0) ? bhh0 : bhh1;
  const float br = bip[n*96 + g2], bz = bip[n*96 + 32 + g2], bn = bip[n*96 + 64 + g2];
  const float cr = bhp[n*96 + g2], cz = bhp[n*96 + 32 + g2], cn = bhp[n*96 + 64 + g2];
  // ---- initial state: hs = own-layer h(prev) slice; hown = own h value ----
  const float* hp = (wid == 0) ? (Hpre + n*32) : (Hpre + 8192 + n*32);
  float hown = hp[g2];
  float hs[16];
#pragma unroll
  for (int q = 0; q < 4; ++q){
    float4 v = *(const float4*)&hp[co + 4*q];
    hs[4*q]=v.x; hs[4*q+1]=v.y; hs[4*q+2]=v.z; hs[4*q+3]=v.w;
  }
  // ---- pipelined slot loop: wave0 computes h0(s) for s<64; wave1 h1(s-1) ----
  for (int s = 0; s < 65; ++s){
    __syncthreads();
    if (wid == 0){
      if (s < 64){
        const float gr = ginS[s*96 + g2], gz = ginS[s*96 + 32 + g2], gn = ginS[s*96 + 64 + g2];
        if (s > 0){
#pragma unroll
          for (int q = 0; q < 4; ++q){
            float4 v = *(const float4*)&h0buf[(s-1)&1][co + 4*q];
            hs[4*q]=v.x; hs[4*q+1]=v.y; hs[4*q+2]=v.z; hs[4*q+3]=v.w;
          }
        }
        float pr = 0.f, pz = 0.f, pn = 0.f;
#pragma unroll
        for (int j = 0; j < 16; ++j){
          pr = fmaf(wr_[j], hs[j], pr);
          pz = fmaf(wz_[j], hs[j], pz);
          pn = fmaf(wn_[j], hs[j], pn);
        }
        pr += __shfl_xor(pr, 32);
        pz += __shfl_xor(pz, 32);
        pn += __shfl_xor(pn, 32);
        const float r = sigf(gr + br + pr + cr);
        const float z = sigf(gz + bz + pz + cz);
        const float nn = tanhfa(gn + bn + r*(pn + cn));
        hown = (1.f - z)*nn + z*hown;
        if (l < 32) h0buf[s & 1][g2] = hown;
      }
    } else {
      if (s >= 1){
        const int t = s - 1;
        if (s > 1){
#pragma unroll
          for (int q = 0; q < 4; ++q){
            float4 v = *(const float4*)&h1buf[(s-1)&1][co + 4*q];
            hs[4*q]=v.x; hs[4*q+1]=v.y; hs[4*q+2]=v.z; hs[4*q+3]=v.w;
          }
        }
        float hx[16];
#pragma unroll
        for (int q = 0; q < 4; ++q){
          float4 v = *(const float4*)&h0buf[(s-1)&1][co + 4*q];
          hx[4*q]=v.x; hx[4*q+1]=v.y; hx[4*q+2]=v.z; hx[4*q+3]=v.w;
        }
        float qr = 0.f, qz = 0.f, qn = 0.f, sr = 0.f, sz = 0.f, sn = 0.f;
#pragma unroll
        for (int j = 0; j < 16; ++j){
          qr = fmaf(wr_[j], hx[j], qr);  sr = fmaf(ur_[j], hs[j], sr);
          qz = fmaf(wz_[j], hx[j], qz);  sz = fmaf(uz_[j], hs[j], sz);
          qn = fmaf(wn_[j], hx[j], qn);  sn = fmaf(un_[j], hs[j], sn);
        }
        float vr = qr + sr; vr += __shfl_xor(vr, 32);
        float vz = qz + sz; vz += __shfl_xor(vz, 32);
        qn += __shfl_xor(qn, 32);
        sn += __shfl_xor(sn, 32);
        const float r1 = sigf(vr + br + cr);
        const float z1 = sigf(vz + bz + cz);
        const float n1 = tanhfa(qn + bn + r1*(sn + cn));
        hown = (1.f - z1)*n1 + z1*hown;
        if (l < 32){ h1buf[s & 1][g2] = hown; hist[t][g2] = hown; }
      }
    }
  }
  // cat_H outputs: wave0 -> h0 final, wave1 -> h1 final
  if (wid == 0 && l < 32) dout[16384 + n*32 + g2] = hown;
  if (wid == 1 && l < 32) dout[16384 + 8192 + n*32 + g2] = hown;
  __syncthreads();
  // ---- fused FC head on first 64 threads (sensor = tid) ----
  float r1a[32];
  if (tid < 64){
    float hr[32];
#pragma unroll
    for (int k = 0; k < 32; ++k) hr[k] = hist[tid][k];
#pragma unroll
    for (int k = 0; k < 32; ++k){
      float a0=0.f,a1=0.f,a2=0.f,a3=0.f;
#pragma unroll
      for (int q = 0; q < 32; q += 4){
        a0 = fmaf(hr[q],   Wst[k][q],   a0);
        a1 = fmaf(hr[q+1], Wst[k][q+1], a1);
        a2 = fmaf(hr[q+2], Wst[k][q+2], a2);
        a3 = fmaf(hr[q+3], Wst[k][q+3], a3);
      }
      float v = b1s[k] + ((a0+a1)+(a2+a3));
      r1a[k] = v > 0.f ? v : 0.f;
    }
  }
  __syncthreads();
  for (int idx = tid; idx < 1024; idx += 128) Wst[idx>>5][idx&31] = fc2w[n*1024 + idx];
  __syncthreads();
  if (tid < 64){
    float r2a[32];
#pragma unroll
    for (int k = 0; k < 32; ++k){
      float a0=0.f,a1=0.f,a2=0.f,a3=0.f;
#pragma unroll
      for (int q = 0; q < 32; q += 4){
        a0 = fmaf(r1a[q],   Wst[k][q],   a0);
        a1 = fmaf(r1a[q+1], Wst[k][q+1], a1);
        a2 = fmaf(r1a[q+2], Wst[k][q+2], a2);
        a3 = fmaf(r1a[q+3], Wst[k][q+3], a3);
      }
      float v = b2s[k] + ((a0+a1)+(a2+a3));
      r2a[k] = v > 0.f ? v : 0.f;
    }
    float v = fc3b[n];
#pragma unroll
    for (int k = 0; k < 32; ++k) v = fmaf(r2a[k], w3s[k], v);
    ct[n*64 + tid] = v;
  }
}

// ---- k8a: Wh (transposed) + f1/f2 for out & out1. grid 8 = gat*4 + row-quarter ----
__global__ __launch_bounds__(256) void k8a(const float* __restrict__ ct,
                                           const float* __restrict__ W0,
                                           const float* __restrict__ a0,
                                           const float* __restrict__ W1,
                                           const float* __restrict__ a1,
                                           float* __restrict__ WhABt,
                                           float* __restrict__ OF1,
                                           float* __restrict__ OF2){
  const int gat = blockIdx.x >> 2, rq = blockIdx.x & 3, r0 = rq*64;
  const int tid = threadIdx.x;
  const int ii = tid & 63, cq = tid >> 6;
  __shared__ float ctl[64][65];
  __shared__ float Wl[64][68];
  __shared__ float a1s[64], a2s[64];
  __shared__ float red[64][4][2];
  const float* W = gat ? W1 : W0;
  const float* aa = gat ? a1 : a0;
  for (int idx = tid; idx < 4096; idx += 256){
    int i2 = idx >> 6, k = idx & 63;
    ctl[i2][k] = ct[(r0 + i2)*64 + k];
  }
  for (int idx = tid; idx < 4096; idx += 256){
    int k = idx >> 6, c = idx & 63;
    Wl[k][c] = W[k*64 + c];
  }
  if (tid < 64){ a1s[tid] = aa[tid]; a2s[tid] = aa[64 + tid]; }
  __syncthreads();
  float acc[16];
#pragma unroll
  for (int c = 0; c < 16; ++c) acc[c] = 0.f;
#pragma unroll 2
  for (int k = 0; k < 64; ++k){
    float v = ctl[ii][k];
    const float* wr = &Wl[k][cq*16];
#pragma unroll
    for (int c = 0; c < 16; ++c) acc[c] = fmaf(v, wr[c], acc[c]);
  }
  float p1 = 0.f, p2 = 0.f;
#pragma unroll
  for (int c = 0; c < 16; ++c){
    p1 = fmaf(acc[c], a1s[cq*16 + c], p1);
    p2 = fmaf(acc[c], a2s[cq*16 + c], p2);
  }
  red[ii][cq][0] = p1; red[ii][cq][1] = p2;
  float* o = WhABt + gat*16384;
#pragma unroll
  for (int c = 0; c < 16; ++c) o[(cq*16 + c)*256 + r0 + ii] = acc[c];
  __syncthreads();
  if (cq == 0){
    OF1[gat*256 + r0 + ii] = red[ii][0][0] + red[ii][1][0] + red[ii][2][0] + red[ii][3][0];
    OF2[gat*256 + r0 + ii] = red[ii][0][1] + red[ii][1][1] + red[ii][2][1] + red[ii][3][1];
  }
}

// ---- k8b: out/out1 attention. grid 8 = gat*4 + c-tile(16) ----
__global__ __launch_bounds__(256) void k8b(const float* __restrict__ WhABt,
                                           const float* __restrict__ OF1,
                                           const float* __restrict__ OF2,
                                           const unsigned* __restrict__ maskA,
                                           float* __restrict__ OUTT){
  const int gat = blockIdx.x >> 2, c0 = (blockIdx.x & 3) * 16;
  const int i = threadIdx.x;
  __shared__ float f2s[256];
  __shared__ float wt[64][36];
  const float f1 = OF1[gat*256 + i];
  f2s[i] = OF2[gat*256 + i];
  unsigned mw[8];
#pragma unroll
  for (int w = 0; w < 8; ++w) mw[w] = maskA[i*8 + w];
  __syncthreads();
  float m = -INFINITY;
  for (int w = 0; w < 8; ++w){
    const unsigned mk = mw[w];
#pragma unroll
    for (int bb = 0; bb < 32; ++bb){
      float e = f1 + f2s[(w<<5)+bb]; e = (e > 0.f) ? e : ALPHA*e;
      e = ((mk >> bb) & 1u) ? e : NEGV;
      m = fmaxf(m, e);
    }
  }
  float s = 0.f;
  for (int w = 0; w < 8; ++w){
    const unsigned mk = mw[w];
#pragma unroll
    for (int bb = 0; bb < 32; ++bb){
      float e = f1 + f2s[(w<<5)+bb]; e = (e > 0.f) ? e : ALPHA*e;
      e = ((mk >> bb) & 1u) ? e : NEGV;
      s += __expf(e - m);
    }
  }
  const float inv = 1.f / s;
  float acc[16];
#pragma unroll
  for (int c = 0; c < 16; ++c) acc[c] = 0.f;
  for (int jt = 0; jt < 4; ++jt){
    __syncthreads();
    for (int idx = i; idx < 1024; idx += 256){
      int cc = idx >> 6, jj = idx & 63;
      wt[jj][cc] = WhABt[gat*16384 + (c0+cc)*256 + (jt<<6) + jj];
    }
    __syncthreads();
    for (int jj = 0; jj < 64; ++jj){
      const int j = (jt<<6) + jj;
      float e = f1 + f2s[j]; e = (e > 0.f) ? e : ALPHA*e;
      e = ((mw[j>>5] >> (j & 31)) & 1u) ? e : NEGV;
      const float p = __expf(e - m) * inv;
      const float* wr = &wt[jj][0];
#pragma unroll
      for (int c = 0; c < 16; ++c) acc[c] = fmaf(p, wr[c], acc[c]);
    }
  }
#pragma unroll
  for (int c = 0; c < 16; ++c) OUTT[gat*16384 + (c0+c)*256 + i] = acc[c];
}

// ---- k8c: Wh2 (transposed) + F1B/F2B. grid 8 = 32-row chunks ----
__global__ __launch_bounds__(256) void k8c(const float* __restrict__ OUTT,
                                           const float* __restrict__ W2,
                                           const float* __restrict__ a2,
                                           float* __restrict__ Wh2,
                                           float* __restrict__ F1B,
                                           float* __restrict__ F2B){
  const int r0 = blockIdx.x * 32;
  const int tid = threadIdx.x;
  const int ii = tid & 31, cq = tid >> 5;      // 8 groups x 8 cols
  __shared__ float W2l[128][68];
  __shared__ float a1s[64], a2s[64];
  __shared__ float red[32][8][2];
  for (int idx = tid; idx < 8192; idx += 256){
    int k = idx >> 6, c = idx & 63;
    W2l[k][c] = W2[k*64 + c];
  }
  if (tid < 64){ a1s[tid] = a2[tid]; a2s[tid] = a2[64 + tid]; }
  __syncthreads();
  float acc[8];
#pragma unroll
  for (int c = 0; c < 8; ++c) acc[c] = 0.f;
#pragma unroll 2
  for (int k = 0; k < 128; ++k){
    float v = OUTT[(k >> 6)*16384 + (k & 63)*256 + r0 + ii];
    const float* wr = &W2l[k][cq*8];
#pragma unroll
    for (int c = 0; c < 8; ++c) acc[c] = fmaf(v, wr[c], acc[c]);
  }
  float p1 = 0.f, p2 = 0.f;
#pragma unroll
  for (int c = 0; c < 8; ++c){
    p1 = fmaf(acc[c], a1s[cq*8 + c], p1);
    p2 = fmaf(acc[c], a2s[cq*8 + c], p2);
  }
  red[ii][cq][0] = p1; red[ii][cq][1] = p2;
#pragma unroll
  for (int c = 0; c < 8; ++c) Wh2[(cq*8 + c)*256 + r0 + ii] = acc[c];
  __syncthreads();
  if (cq == 0){
    float s1 = 0.f, s2 = 0.f;
#pragma unroll
    for (int q = 0; q < 8; ++q){ s1 += red[ii][q][0]; s2 += red[ii][q][1]; }
    F1B[r0 + ii] = s1; F2B[r0 + ii] = s2;
  }
}

// ---- k8d: final GAT -> d_out. grid 4 = c-tiles(16) ----
__global__ __launch_bounds__(256) void k8d(const float* __restrict__ Wh2,
                                           const float* __restrict__ F1B,
                                           const float* __restrict__ F2B,
                                           const unsigned* __restrict__ maskA,
                                           float* __restrict__ dOut){
  const int c0 = blockIdx.x * 16;
  const int i = threadIdx.x;
  __shared__ float f2s[256];
  __shared__ float wt[64][36];
  const float f1 = F1B[i];
  f2s[i] = F2B[i];
  unsigned mw[8];
#pragma unroll
  for (int w = 0; w < 8; ++w) mw[w] = maskA[i*8 + w];
  __syncthreads();
  float m = -INFINITY;
  for (int w = 0; w < 8; ++w){
    const unsigned mk = mw[w];
#pragma unroll
    for (int bb = 0; bb < 32; ++bb){
      float e = f1 + f2s[(w<<5)+bb]; e = (e > 0.f) ? e : ALPHA*e;
      e = ((mk >> bb) & 1u) ? e : NEGV;
      m = fmaxf(m, e);
    }
  }
  float s = 0.f;
  for (int w = 0; w < 8; ++w){
    const unsigned mk = mw[w];
#pragma unroll
    for (int bb = 0; bb < 32; ++bb){
      float e = f1 + f2s[(w<<5)+bb]; e = (e > 0.f) ? e : ALPHA*e;
      e = ((mk >> bb) & 1u) ? e : NEGV;
      s += __expf(e - m);
    }
  }
  const float inv = 1.f / s;
  float acc[16];
#pragma unroll
  for (int c = 0; c < 16; ++c) acc[c] = 0.f;
  for (int jt = 0; jt < 4; ++jt){
    __syncthreads();
    for (int idx = i; idx < 1024; idx += 256){
      int cc = idx >> 6, jj = idx & 63;
      wt[jj][cc] = Wh2[(c0+cc)*256 + (jt<<6) + jj];
    }
    __syncthreads();
    for (int jj = 0; jj < 64; ++jj){
      const int j = (jt<<6) + jj;
      float e = f1 + f2s[j]; e = (e > 0.f) ? e : ALPHA*e;
      e = ((mw[j>>5] >> (j & 31)) & 1u) ? e : NEGV;
      const float p = __expf(e - m) * inv;
      const float* wr = &wt[jj][0];
#pragma unroll
      for (int c = 0; c < 16; ++c) acc[c] = fmaf(p, wr[c], acc[c]);
    }
  }
#pragma unroll
  for (int c = 0; c < 16; ++c) dOut[i*64 + c0 + c] = acc[c];
}

extern "C" void kernel_launch(void* const* d_in, const int* in_sizes, int n_in,
                              void* d_out, int out_size, void* d_ws, size_t ws_size,
                              hipStream_t stream){
  (void)in_sizes; (void)n_in; (void)out_size; (void)ws_size;
  const float* x     = (const float*)d_in[0];
  const float* Fadj  = (const float*)d_in[1];
  const float* Tadj  = (const float*)d_in[2];
  const float* adj   = (const float*)d_in[3];
  const float* Hpre  = (const float*)d_in[4];
  const float* FattW = (const float*)d_in[5];
  const float* Fatta = (const float*)d_in[6];
  const float* TattW = (const float*)d_in[7];
  const float* Tatta = (const float*)d_in[8];
  const float* Wih0  = (const float*)d_in[9];
  const float* Whh0  = (const float*)d_in[10];
  const float* bih0  = (const float*)d_in[11];
  const float* bhh0  = (const float*)d_in[12];
  const float* Wih1  = (const float*)d_in[13];
  const float* Whh1  = (const float*)d_in[14];
  const float* bih1  = (const float*)d_in[15];
  const float* bhh1  = (const float*)d_in[16];
  const float* fc1w  = (const float*)d_in[17];
  const float* fc1b  = (const float*)d_in[18];
  const float* fc2w  = (const float*)d_in[19];
  const float* fc2b  = (const float*)d_in[20];
  const float* fc3w  = (const float*)d_in[21];
  const float* fc3b  = (const float*)d_in[22];
  const float* oW    = (const float*)d_in[23];
  const float* oa    = (const float*)d_in[24];
  const float* o1W   = (const float*)d_in[25];
  const float* o1a   = (const float*)d_in[26];
  const float* o2W   = (const float*)d_in[27];
  const float* o2a   = (const float*)d_in[28];
  float* out = (float*)d_out;

  float* ws = (float*)d_ws;
  float* R0 = ws;
  float* R1 = ws + 4194304;
  float* R2 = ws + 8388608;
  unsigned* maskT = (unsigned*)R2;             // 524288 words
  float* Tf1p = R2 + 524288;                   // 2 x 65536
  float* Tf2p = R2 + 655360;                   // 2 x 65536
  unsigned* maskA = (unsigned*)(ws + 12582912);// 2048 words
  float* WhTt = R0;
  float* WhF  = R0;
  float* TatT = R1;
  float* Fat  = R2;
  float* P0 = R2;
  float* P1 = R1;
  float* P2 = R0;
  float* ctb   = R0 + 2097152;                 // above P2's span
  float* WhABt = R1 + 16384;
  float* OF1   = R1 + 49152;
  float* OF2   = R1 + 49664;
  float* OUTT  = R1 + 50176;
  float* WH2   = R1 + 82944;
  float* F1B   = R1 + 99328;
  float* F2B   = R1 + 99584;

  k_mask<<<1024, 256, 0, stream>>>(Tadj, maskT, 16777216);
  k_mask<<<32, 256, 0, stream>>>(adj, maskA, 65536);
  k3_wht<<<512, 256, 0, stream>>>(x, TattW, Tatta, WhTt, Tf1p, Tf2p);
  k4_tat<<<512, 256, 0, stream>>>(WhTt, Tf1p, Tf2p, maskT, TatT);
  k1_whf<<<512, 256, 0, stream>>>(x, FattW, WhF);
  k2_fat<<<256, 512, 0, stream>>>(WhF, Fatta, Fadj, Fat);
  k5_gi0<<<768, 256, 0, stream>>>(Fat, TatT, x, Wih0, P0, P1, P2);
  k6_gru<<<256, 128, 0, stream>>>(P0, P1, P2, Hpre, Whh0, bih0, bhh0, Wih1, Whh1, bih1, bhh1,
                                  fc1w, fc1b, fc2w, fc2b, fc3w, fc3b, ctb, out);
  k8a<<<8, 256, 0, stream>>>(ctb, oW, oa, o1W, o1a, WhABt, OF1, OF2);
  k8b<<<8, 256, 0, stream>>>(WhABt, OF1, OF2, maskA, OUTT);
  k8c<<<8, 256, 0, stream>>>(OUTT, o2W, o2a, WH2, F1B, F2B);
  k8d<<<4, 256, 0, stream>>>(WH2, F1B, F2B, maskA, out);
}

// Round 4
// 631.446 us; speedup vs baseline: 1.3678x; 1.0653x over previous
//
#include <hip/hip_runtime.h>
#include <hip/hip_bf16.h>

__device__ __forceinline__ float sigf(float x){ return __builtin_amdgcn_rcpf(1.f+__expf(-x)); }
__device__ __forceinline__ float tanhfa(float x){
  return 1.f - 2.f*__builtin_amdgcn_rcpf(1.f + __expf(2.f*x));
}

#define ALPHA 0.2f
#define NEGV  -9e15f

// N=256 nodes, S=64 sensors, W=256 window, H=32 hidden. All fp32.

__device__ __forceinline__ void gl2lds16(const float* g, float* l){
  __builtin_amdgcn_global_load_lds(
      (const __attribute__((address_space(1))) void*)g,
      (__attribute__((address_space(3))) void*)l, 16, 0, 0);
}

// ---- k_mask: pack adjacency fp32 (0/1) -> bitmask via wave ballot ----
__global__ __launch_bounds__(256) void k_mask(const float* __restrict__ src,
                                              unsigned* __restrict__ dst, int nelem){
  const int stride = gridDim.x * blockDim.x;
  const int lane = threadIdx.x & 63;
  for (int e = blockIdx.x*blockDim.x + threadIdx.x; e < nelem; e += stride){
    unsigned long long m = __ballot(src[e] > 0.f);
    if (lane == 0)       dst[e >> 5] = (unsigned)m;
    else if (lane == 32) dst[e >> 5] = (unsigned)(m >> 32);
  }
}

// ---- k3: Wh_T (transposed store) + Tf1/Tf2 partials. grid 512 = n*2 + c-half ----
__global__ __launch_bounds__(256) void k3_wht(const float* __restrict__ x,
                                              const float* __restrict__ TW,
                                              const float* __restrict__ Ta,
                                              float* __restrict__ WhTt,
                                              float* __restrict__ Tf1p,
                                              float* __restrict__ Tf2p){
  const int n = blockIdx.x >> 1, ch = blockIdx.x & 1, c0 = ch*32;
  const int tid = threadIdx.x;
  __shared__ float Wm[64][36];
  __shared__ float as1[32], as2[32];
  for (int idx = tid; idx < 2048; idx += 256){
    int k = idx >> 5, cc = idx & 31;
    Wm[k][cc] = TW[n*4096 + k*64 + c0 + cc];
  }
  if (tid < 32){ as1[tid] = Ta[n*128 + c0 + tid]; as2[tid] = Ta[n*128 + 64 + c0 + tid]; }
  __syncthreads();
  const int i = tid;
  const float* xn = x + n*16384;
  float acc[32];
#pragma unroll
  for (int c = 0; c < 32; ++c) acc[c] = 0.f;
#pragma unroll 2
  for (int k = 0; k < 64; ++k){
    float xv = xn[k*256 + i];                  // coalesced
    const float* wr = &Wm[k][0];               // broadcast b128
#pragma unroll
    for (int c = 0; c < 32; ++c) acc[c] = fmaf(xv, wr[c], acc[c]);
  }
  float f1 = 0.f, f2 = 0.f;
#pragma unroll
  for (int c = 0; c < 32; ++c){ f1 = fmaf(acc[c], as1[c], f1); f2 = fmaf(acc[c], as2[c], f2); }
  Tf1p[ch*65536 + n*256 + i] = f1;
  Tf2p[ch*65536 + n*256 + i] = f2;
  float* o = WhTt + n*16384;
#pragma unroll
  for (int c = 0; c < 32; ++c) o[(c0+c)*256 + i] = acc[c];
}

// ---- k4: time-GAT attention, single-pass online softmax. grid 512 = n*2+ch ----
// m bound: leaky is monotone -> m_i = leaky(f1_i + max_j f2) >= all e; softmax
// shift-invariant. wt staged [c][j] linear via global_load_lds (coalesced, no
// conflicts); PV reads are wave-uniform b128 broadcasts. 1 barrier total.
__global__ __launch_bounds__(256) void k4_tat(const float* __restrict__ WhTt,
                                              const float* __restrict__ Tf1p,
                                              const float* __restrict__ Tf2p,
                                              const unsigned* __restrict__ maskT,
                                              float* __restrict__ TatT){
  const int n = blockIdx.x >> 1, ch = blockIdx.x & 1, c0 = ch*32;
  const int i = threadIdx.x;
  __shared__ float wt[8192];                   // [32 c][256 j], 32 KB
  __shared__ float f2s[256];
  __shared__ float wmax[4];
  {
    const int w = i >> 6, l = i & 63;
    const float* src = WhTt + n*16384 + c0*256 + w*2048 + l*4;
    float* dst = &wt[w*2048];
#pragma unroll
    for (int r = 0; r < 8; ++r) gl2lds16(src + r*256, dst + r*256);
  }
  const float f1  = Tf1p[n*256 + i] + Tf1p[65536 + n*256 + i];
  const float f2v = Tf2p[n*256 + i] + Tf2p[65536 + n*256 + i];
  f2s[i] = f2v;
  unsigned mw[8];
#pragma unroll
  for (int w = 0; w < 8; ++w) mw[w] = maskT[n*2048 + i*8 + w];
  float wm = f2v;
#pragma unroll
  for (int d = 1; d < 64; d <<= 1) wm = fmaxf(wm, __shfl_xor(wm, d));
  if ((i & 63) == 0) wmax[i >> 6] = wm;
  asm volatile("s_waitcnt vmcnt(0)" ::: "memory");
  __syncthreads();
  const float mb = fmaxf(fmaxf(wmax[0], wmax[1]), fmaxf(wmax[2], wmax[3]));
  const float tm = f1 + mb;
  const float m  = (tm > 0.f) ? tm : ALPHA*tm;
  float acc[32];
#pragma unroll
  for (int c = 0; c < 32; ++c) acc[c] = 0.f;
  float s = 0.f;
#pragma unroll 2
  for (int jb = 0; jb < 64; ++jb){
    const float4 f2q = *(const float4*)&f2s[jb*4];
    const unsigned mk = mw[jb >> 3];
    const int sh = (jb & 7) * 4;
    float t0 = f1 + f2q.x; t0 = (t0 > 0.f) ? t0 : ALPHA*t0;
    float t1 = f1 + f2q.y; t1 = (t1 > 0.f) ? t1 : ALPHA*t1;
    float t2 = f1 + f2q.z; t2 = (t2 > 0.f) ? t2 : ALPHA*t2;
    float t3 = f1 + f2q.w; t3 = (t3 > 0.f) ? t3 : ALPHA*t3;
    const float e0 = ((mk >> (sh+0)) & 1u) ? __expf(t0 - m) : 0.f;
    const float e1 = ((mk >> (sh+1)) & 1u) ? __expf(t1 - m) : 0.f;
    const float e2 = ((mk >> (sh+2)) & 1u) ? __expf(t2 - m) : 0.f;
    const float e3 = ((mk >> (sh+3)) & 1u) ? __expf(t3 - m) : 0.f;
    s += (e0 + e1) + (e2 + e3);
#pragma unroll
    for (int c = 0; c < 32; ++c){
      const float4 wv = *(const float4*)&wt[c*256 + jb*4];   // broadcast b128
      acc[c] = fmaf(e0, wv.x, fmaf(e1, wv.y, fmaf(e2, wv.z, fmaf(e3, wv.w, acc[c]))));
    }
  }
  const float inv = (s > 0.f) ? __builtin_amdgcn_rcpf(s) : 0.f;
  float* o = TatT + n*16384;
#pragma unroll
  for (int c = 0; c < 32; ++c) o[(c0+c)*256 + i] = acc[c] * inv;
}

// ---- k1: Wh_F = x @ Fatt_W. grid 512 = n*2 + c-half(128), block 256 ----
__global__ __launch_bounds__(256) void k1_whf(const float* __restrict__ x,
                                              const float* __restrict__ FW,
                                              float* __restrict__ WhF){
  const int n = blockIdx.x >> 1, ch = blockIdx.x & 1, c0 = ch*128;
  const int tid = threadIdx.x;
  __shared__ float xt[16384];                  // [i][k] linear, 64 KB
  {
    const int w = tid >> 6, l = tid & 63;
    const float* xg = x + n*16384 + w*4096 + l*4;
    float* ld = &xt[w*4096];
#pragma unroll
    for (int j = 0; j < 16; ++j) gl2lds16(xg + j*256, ld + j*256);
  }
  asm volatile("s_waitcnt vmcnt(0)" ::: "memory");
  __syncthreads();
  const int cq = tid & 31, iq = tid >> 5;      // c-quad, i-group(8 rows)
  const int cc = c0 + cq*4;
  const float* Wn = FW + (size_t)n*65536 + cc;
  const float* xrow = &xt[iq*8*256];
  float acc[8][4];
#pragma unroll
  for (int i = 0; i < 8; ++i)
#pragma unroll
    for (int c = 0; c < 4; ++c) acc[i][c] = 0.f;
#pragma unroll 2
  for (int k4 = 0; k4 < 64; ++k4){
    const float4 w0 = *(const float4*)&Wn[(4*k4+0)*256];
    const float4 w1 = *(const float4*)&Wn[(4*k4+1)*256];
    const float4 w2 = *(const float4*)&Wn[(4*k4+2)*256];
    const float4 w3 = *(const float4*)&Wn[(4*k4+3)*256];
#pragma unroll
    for (int i = 0; i < 8; ++i){
      const float4 xv = *(const float4*)&xrow[i*256 + 4*k4];
      acc[i][0] = fmaf(xv.x, w0.x, acc[i][0]); acc[i][0] = fmaf(xv.y, w1.x, acc[i][0]);
      acc[i][0] = fmaf(xv.z, w2.x, acc[i][0]); acc[i][0] = fmaf(xv.w, w3.x, acc[i][0]);
      acc[i][1] = fmaf(xv.x, w0.y, acc[i][1]); acc[i][1] = fmaf(xv.y, w1.y, acc[i][1]);
      acc[i][1] = fmaf(xv.z, w2.y, acc[i][1]); acc[i][1] = fmaf(xv.w, w3.y, acc[i][1]);
      acc[i][2] = fmaf(xv.x, w0.z, acc[i][2]); acc[i][2] = fmaf(xv.y, w1.z, acc[i][2]);
      acc[i][2] = fmaf(xv.z, w2.z, acc[i][2]); acc[i][2] = fmaf(xv.w, w3.z, acc[i][2]);
      acc[i][3] = fmaf(xv.x, w0.w, acc[i][3]); acc[i][3] = fmaf(xv.y, w1.w, acc[i][3]);
      acc[i][3] = fmaf(xv.z, w2.w, acc[i][3]); acc[i][3] = fmaf(xv.w, w3.w, acc[i][3]);
    }
  }
  float* o = WhF + n*16384 + cc;
#pragma unroll
  for (int i = 0; i < 8; ++i)
    *(float4*)&o[(iq*8 + i)*256] = make_float4(acc[i][0], acc[i][1], acc[i][2], acc[i][3]);
}

// ---- k2: feature-GAT softmax + Fat = att @ Wh. grid 256, block 512 (i-split) ----
__global__ __launch_bounds__(512) void k2_fat(const float* __restrict__ WhF,
                                              const float* __restrict__ Fa,
                                              const float* __restrict__ Fadj,
                                              float* __restrict__ Fat){
  const int n = blockIdx.x, tid = threadIdx.x;
  __shared__ float attT[64][68];               // attT[j][i]
  __shared__ float f1s[64], f2s[64];
  __shared__ float part[64][8][2];
  const float* Wh = WhF + n*16384;
  { // f1/f2: thread (i=tid>>3, q=tid&7) partial over 32 cols
    int i = tid >> 3, q = tid & 7;
    const float* an = Fa + n*512;
    float p1 = 0.f, p2 = 0.f;
    for (int cc = 0; cc < 32; ++cc){
      int c2 = q*32 + cc;
      float w = Wh[i*256 + c2];
      p1 = fmaf(w, an[c2], p1);
      p2 = fmaf(w, an[256 + c2], p2);
    }
    part[i][q][0] = p1; part[i][q][1] = p2;
  }
  __syncthreads();
  if (tid < 64){
    float s1 = 0.f, s2 = 0.f;
#pragma unroll
    for (int q = 0; q < 8; ++q){ s1 += part[tid][q][0]; s2 += part[tid][q][1]; }
    f1s[tid] = s1; f2s[tid] = s2;
  }
  __syncthreads();
  if (tid < 64){                               // masked softmax row -> attT column
    const int r = tid;
    const float f1 = f1s[r];
    const float* adjr = Fadj + n*4096 + r*64;
    unsigned m0 = 0, m1 = 0;
#pragma unroll
    for (int j = 0; j < 32; ++j) if (adjr[j] > 0.f) m0 |= (1u << j);
#pragma unroll
    for (int j = 0; j < 32; ++j) if (adjr[32+j] > 0.f) m1 |= (1u << j);
    float m = -INFINITY;
#pragma unroll
    for (int j = 0; j < 64; ++j){
      float e = f1 + f2s[j]; e = (e > 0.f) ? e : ALPHA*e;
      unsigned bit = (j < 32) ? ((m0 >> j) & 1u) : ((m1 >> (j-32)) & 1u);
      e = bit ? e : NEGV;
      m = fmaxf(m, e);
    }
    float s = 0.f;
#pragma unroll
    for (int j = 0; j < 64; ++j){
      float e = f1 + f2s[j]; e = (e > 0.f) ? e : ALPHA*e;
      unsigned bit = (j < 32) ? ((m0 >> j) & 1u) : ((m1 >> (j-32)) & 1u);
      e = bit ? e : NEGV;
      s += __expf(e - m);
    }
    const float inv = 1.f / s;
#pragma unroll
    for (int j = 0; j < 64; ++j){
      float e = f1 + f2s[j]; e = (e > 0.f) ? e : ALPHA*e;
      unsigned bit = (j < 32) ? ((m0 >> j) & 1u) : ((m1 >> (j-32)) & 1u);
      e = bit ? e : NEGV;
      attT[j][r] = __expf(e - m) * inv;
    }
  }
  __syncthreads();
  const int c = tid & 255, ih = tid >> 8;      // ih: 32-row half of output
  float acc[32];
#pragma unroll
  for (int i = 0; i < 32; ++i) acc[i] = 0.f;
#pragma unroll 2
  for (int j = 0; j < 64; ++j){
    float w = Wh[j*256 + c];                   // coalesced, L2-hot
    const float* ar = &attT[j][ih*32];         // broadcast b128 (16B-aligned)
#pragma unroll
    for (int i = 0; i < 32; ++i) acc[i] = fmaf(ar[i], w, acc[i]);
  }
  float* o = Fat + n*16384;
#pragma unroll
  for (int i = 0; i < 32; ++i) o[(ih*32 + i)*256 + c] = acc[i];
}

// ---- k5: partial Gi0 = cat_seg @ Wih0_seg^T. grid 768 = s*256 + n ----
__global__ __launch_bounds__(256) void k5_gi0(const float* __restrict__ Fat,
                                              const float* __restrict__ TatT,
                                              const float* __restrict__ x,
                                              const float* __restrict__ Wih0,
                                              float* __restrict__ P0,
                                              float* __restrict__ P1,
                                              float* __restrict__ P2){
  const int n = blockIdx.x & 255, s = blockIdx.x >> 8;
  const int tid = threadIdx.x;
  const int l = tid & 63, w = tid >> 6;        // lane, wave
  const int a = tid & 31, b = tid >> 5;        // t-pair lane, gate group (0..7)
  __shared__ float cl[2][2048];                // cat tile [64 t][32 k], dbuf, 16 KB
  __shared__ float wl[2][3072];                // W tile  [96 g][32 k], dbuf, 24 KB
  const float* src = (s == 0) ? (Fat + n*16384)
                   : (s == 1) ? (TatT + n*16384)
                              : (x + n*16384);
  const float* Wseg = Wih0 + (size_t)n*73728 + s*256;
  const int lr = l >> 3, lc = l & 7, sc = lc ^ lr;       // sc: swizzled cat col4
  const float* cg0 = src + (16*w + lr)*256 + sc*4;       // cat rows 16w..16w+7
  const float* cg1 = cg0 + 8*256;                        // cat rows +8
  const float* wg0 = Wseg + (size_t)(24*w + lr)*768 + lc*4;  // W rows 24w..+7
  const float* wg1 = wg0 + (size_t)8*768;
  const float* wg2 = wg0 + (size_t)16*768;

#define K5_STAGE(BF, K0) do {                       \
    gl2lds16(cg0 + (K0), &cl[BF][512*w]);           \
    gl2lds16(cg1 + (K0), &cl[BF][512*w + 256]);     \
    gl2lds16(wg0 + (K0), &wl[BF][768*w]);           \
    gl2lds16(wg1 + (K0), &wl[BF][768*w + 256]);     \
    gl2lds16(wg2 + (K0), &wl[BF][768*w + 512]);     \
  } while (0)

  float acc[12][2];
#pragma unroll
  for (int gi = 0; gi < 12; ++gi){ acc[gi][0] = 0.f; acc[gi][1] = 0.f; }

  int bf = 0;
  K5_STAGE(0, 0);
  const int ax4 = (a & 7) << 2;
#pragma unroll 1
  for (int kt = 0; kt < 8; ++kt){
    if (kt < 7){
      K5_STAGE(bf ^ 1, (kt + 1) * 32);
      asm volatile("s_waitcnt vmcnt(5)" ::: "memory");  // current tile landed
    } else {
      asm volatile("s_waitcnt vmcnt(0)" ::: "memory");
    }
    __builtin_amdgcn_s_barrier();
    const float* clb  = &cl[bf][a*32];
    const float* clb2 = &cl[bf][(a+32)*32];
    const float* wlb  = &wl[bf][b*384];
#pragma unroll
    for (int k4 = 0; k4 < 8; ++k4){
      const int j4 = (k4 << 2) ^ ax4;                   // swizzled read col
      const float4 c0 = *(const float4*)&clb[j4];
      const float4 c1 = *(const float4*)&clb2[j4];
#pragma unroll
      for (int gi = 0; gi < 12; ++gi){
        const float4 wv = *(const float4*)&wlb[gi*32 + (k4 << 2)];
        float a0 = acc[gi][0], a1 = acc[gi][1];
        a0 = fmaf(wv.x, c0.x, a0); a1 = fmaf(wv.x, c1.x, a1);
        a0 = fmaf(wv.y, c0.y, a0); a1 = fmaf(wv.y, c1.y, a1);
        a0 = fmaf(wv.z, c0.z, a0); a1 = fmaf(wv.z, c1.z, a1);
        a0 = fmaf(wv.w, c0.w, a0); a1 = fmaf(wv.w, c1.w, a1);
        acc[gi][0] = a0; acc[gi][1] = a1;
      }
    }
    __builtin_amdgcn_s_barrier();
    bf ^= 1;
  }
#undef K5_STAGE
  float* o = (s == 0) ? (P0 + n*16384)
           : (s == 1) ? (P1 + n*16384)
                      : (P2 + n*8192);
#pragma unroll
  for (int q = 0; q < 3; ++q){
    *(float4*)&o[a*96 + b*12 + q*4] =
        make_float4(acc[4*q][0], acc[4*q+1][0], acc[4*q+2][0], acc[4*q+3][0]);
    *(float4*)&o[(a+32)*96 + b*12 + q*4] =
        make_float4(acc[4*q][1], acc[4*q+1][1], acc[4*q+2][1], acc[4*q+3][1]);
  }
}

// ---- k6: 2-layer GRU, wave-pipelined. block 128 = wave0 (layer0) + wave1
// (layer1, one step behind). Handoff via double-buffered 32-float LDS slots.
__global__ __launch_bounds__(128) void k6_gru(const float* __restrict__ G0,
                                              const float* __restrict__ G1,
                                              const float* __restrict__ G2,
                                              const float* __restrict__ Hpre,
                                              const float* __restrict__ Whh0,
                                              const float* __restrict__ bih0,
                                              const float* __restrict__ bhh0,
                                              const float* __restrict__ Wih1,
                                              const float* __restrict__ Whh1,
                                              const float* __restrict__ bih1,
                                              const float* __restrict__ bhh1,
                                              const float* __restrict__ fc1w,
                                              const float* __restrict__ fc1b,
                                              const float* __restrict__ fc2w,
                                              const float* __restrict__ fc2b,
                                              const float* __restrict__ fc3w,
                                              const float* __restrict__ fc3b,
                                              float* __restrict__ ct,
                                              float* __restrict__ dout){
  const int n = blockIdx.x, tid = threadIdx.x;
  const int wid = tid >> 6, l = tid & 63;
  const int g2 = l & 31, co = (l >> 5) * 16;
  __shared__ float ginS[6144];                 // 24 KB summed gate inputs [t][96]
  __shared__ float h0buf[2][32];
  __shared__ float h1buf[2][32];
  __shared__ float hist[64][33];
  __shared__ float Wst[32][33];
  __shared__ float b1s[32], b2s[32], w3s[32];
  // ---- stage gin = G0+G1+G2 (128 threads, 12 float4 each) ----
  {
    const float4* p0 = (const float4*)(G0 + n*16384);
    const float4* p1 = (const float4*)(G1 + n*16384);
    const float4* p2 = (const float4*)(G2 + n*8192);
    float4* gs = (float4*)ginS;
#pragma unroll
    for (int j = 0; j < 12; ++j){
      int idx = j*128 + tid;
      float4 a = p0[idx], b = p1[idx], c = p2[idx];
      gs[idx] = make_float4(a.x+b.x+c.x, a.y+b.y+c.y, a.z+b.z+c.z, a.w+b.w+c.w);
    }
  }
  // ---- FC-head staging ----
  if (tid < 32){
    b1s[tid] = fc1b[n*32 + tid];
    b2s[tid] = fc2b[n*32 + tid];
    w3s[tid] = fc3w[n*32 + tid];
  }
  for (int idx = tid; idx < 1024; idx += 128) Wst[idx>>5][idx&31] = fc1w[n*1024 + idx];
  // ---- per-wave weights (wave0: Whh0; wave1: Wih1 + Whh1) ----
  float wr_[16], wz_[16], wn_[16];
  float ur_[16], uz_[16], un_[16];
  {
    const float* WA = (wid == 0) ? (Whh0 + n*3072) : (Wih1 + n*3072);
#pragma unroll
    for (int q = 0; q < 4; ++q){
      float4 v;
      v = *(const float4*)(WA + g2*32 + co + 4*q);       wr_[4*q]=v.x; wr_[4*q+1]=v.y; wr_[4*q+2]=v.z; wr_[4*q+3]=v.w;
      v = *(const float4*)(WA + (32+g2)*32 + co + 4*q);  wz_[4*q]=v.x; wz_[4*q+1]=v.y; wz_[4*q+2]=v.z; wz_[4*q+3]=v.w;
      v = *(const float4*)(WA + (64+g2)*32 + co + 4*q);  wn_[4*q]=v.x; wn_[4*q+1]=v.y; wn_[4*q+2]=v.z; wn_[4*q+3]=v.w;
    }
    if (wid == 1){
      const float* WB = Whh1 + n*3072;
#pragma unroll
      for (int q = 0; q < 4; ++q){
        float4 v;
        v = *(const float4*)(WB + g2*32 + co + 4*q);       ur_[4*q]=v.x; ur_[4*q+1]=v.y; ur_[4*q+2]=v.z; ur_[4*q+3]=v.w;
        v = *(const float4*)(WB + (32+g2)*32 + co + 4*q);  uz_[4*q]=v.x; uz_[4*q+1]=v.y; uz_[4*q+2]=v.z; uz_[4*q+3]=v.w;
        v = *(const float4*)(WB + (64+g2)*32 + co + 4*q);  un_[4*q]=v.x; un_[4*q+1]=v.y; un_[4*q+2]=v.z; un_[4*q+3]=v.w;
      }
    }
  }
  const float* bip = (wid == 0) ? bih0 : bih1;
  const float* bhp = (wid == 0) ? bhh0 : bhh1;
  const float br = bip[n*96 + g2], bz = bip[n*96 + 32 + g2], bn = bip[n*96 + 64 + g2];
  const float cr = bhp[n*96 + g2], cz = bhp[n*96 + 32 + g2], cn = bhp[n*96 + 64 + g2];
  // ---- initial state ----
  const float* hp = (wid == 0) ? (Hpre + n*32) : (Hpre + 8192 + n*32);
  float hown = hp[g2];
  float hs[16];
#pragma unroll
  for (int q = 0; q < 4; ++q){
    float4 v = *(const float4*)&hp[co + 4*q];
    hs[4*q]=v.x; hs[4*q+1]=v.y; hs[4*q+2]=v.z; hs[4*q+3]=v.w;
  }
  // ---- pipelined slot loop: wave0 computes h0(s) for s<64; wave1 h1(s-1) ----
  for (int s = 0; s < 65; ++s){
    __syncthreads();
    if (wid == 0){
      if (s < 64){
        const float gr = ginS[s*96 + g2], gz = ginS[s*96 + 32 + g2], gn = ginS[s*96 + 64 + g2];
        if (s > 0){
#pragma unroll
          for (int q = 0; q < 4; ++q){
            float4 v = *(const float4*)&h0buf[(s-1)&1][co + 4*q];
            hs[4*q]=v.x; hs[4*q+1]=v.y; hs[4*q+2]=v.z; hs[4*q+3]=v.w;
          }
        }
        float pr = 0.f, pz = 0.f, pn = 0.f;
#pragma unroll
        for (int j = 0; j < 16; ++j){
          pr = fmaf(wr_[j], hs[j], pr);
          pz = fmaf(wz_[j], hs[j], pz);
          pn = fmaf(wn_[j], hs[j], pn);
        }
        pr += __shfl_xor(pr, 32);
        pz += __shfl_xor(pz, 32);
        pn += __shfl_xor(pn, 32);
        const float r = sigf(gr + br + pr + cr);
        const float z = sigf(gz + bz + pz + cz);
        const float nn = tanhfa(gn + bn + r*(pn + cn));
        hown = (1.f - z)*nn + z*hown;
        if (l < 32) h0buf[s & 1][g2] = hown;
      }
    } else {
      if (s >= 1){
        const int t = s - 1;
        if (s > 1){
#pragma unroll
          for (int q = 0; q < 4; ++q){
            float4 v = *(const float4*)&h1buf[(s-1)&1][co + 4*q];
            hs[4*q]=v.x; hs[4*q+1]=v.y; hs[4*q+2]=v.z; hs[4*q+3]=v.w;
          }
        }
        float hx[16];
#pragma unroll
        for (int q = 0; q < 4; ++q){
          float4 v = *(const float4*)&h0buf[(s-1)&1][co + 4*q];
          hx[4*q]=v.x; hx[4*q+1]=v.y; hx[4*q+2]=v.z; hx[4*q+3]=v.w;
        }
        float qr = 0.f, qz = 0.f, qn = 0.f, sr = 0.f, sz = 0.f, sn = 0.f;
#pragma unroll
        for (int j = 0; j < 16; ++j){
          qr = fmaf(wr_[j], hx[j], qr);  sr = fmaf(ur_[j], hs[j], sr);
          qz = fmaf(wz_[j], hx[j], qz);  sz = fmaf(uz_[j], hs[j], sz);
          qn = fmaf(wn_[j], hx[j], qn);  sn = fmaf(un_[j], hs[j], sn);
        }
        float vr = qr + sr; vr += __shfl_xor(vr, 32);
        float vz = qz + sz; vz += __shfl_xor(vz, 32);
        qn += __shfl_xor(qn, 32);
        sn += __shfl_xor(sn, 32);
        const float r1 = sigf(vr + br + cr);
        const float z1 = sigf(vz + bz + cz);
        const float n1 = tanhfa(qn + bn + r1*(sn + cn));
        hown = (1.f - z1)*n1 + z1*hown;
        if (l < 32){ h1buf[s & 1][g2] = hown; hist[t][g2] = hown; }
      }
    }
  }
  if (wid == 0 && l < 32) dout[16384 + n*32 + g2] = hown;
  if (wid == 1 && l < 32) dout[16384 + 8192 + n*32 + g2] = hown;
  __syncthreads();
  // ---- fused FC head on first 64 threads (sensor = tid) ----
  float r1a[32];
  if (tid < 64){
    float hr[32];
#pragma unroll
    for (int k = 0; k < 32; ++k) hr[k] = hist[tid][k];
#pragma unroll
    for (int k = 0; k < 32; ++k){
      float a0=0.f,a1=0.f,a2=0.f,a3=0.f;
#pragma unroll
      for (int q = 0; q < 32; q += 4){
        a0 = fmaf(hr[q],   Wst[k][q],   a0);
        a1 = fmaf(hr[q+1], Wst[k][q+1], a1);
        a2 = fmaf(hr[q+2], Wst[k][q+2], a2);
        a3 = fmaf(hr[q+3], Wst[k][q+3], a3);
      }
      float v = b1s[k] + ((a0+a1)+(a2+a3));
      r1a[k] = v > 0.f ? v : 0.f;
    }
  }
  __syncthreads();
  for (int idx = tid; idx < 1024; idx += 128) Wst[idx>>5][idx&31] = fc2w[n*1024 + idx];
  __syncthreads();
  if (tid < 64){
    float r2a[32];
#pragma unroll
    for (int k = 0; k < 32; ++k){
      float a0=0.f,a1=0.f,a2=0.f,a3=0.f;
#pragma unroll
      for (int q = 0; q < 32; q += 4){
        a0 = fmaf(r1a[q],   Wst[k][q],   a0);
        a1 = fmaf(r1a[q+1], Wst[k][q+1], a1);
        a2 = fmaf(r1a[q+2], Wst[k][q+2], a2);
        a3 = fmaf(r1a[q+3], Wst[k][q+3], a3);
      }
      float v = b2s[k] + ((a0+a1)+(a2+a3));
      r2a[k] = v > 0.f ? v : 0.f;
    }
    float v = fc3b[n];
#pragma unroll
    for (int k = 0; k < 32; ++k) v = fmaf(r2a[k], w3s[k], v);
    ct[n*64 + tid] = v;
  }
}

// ---- k8a: Wh (transposed) + f1/f2 for out & out1. grid 8 = gat*4 + row-quarter ----
__global__ __launch_bounds__(256) void k8a(const float* __restrict__ ct,
                                           const float* __restrict__ W0,
                                           const float* __restrict__ a0,
                                           const float* __restrict__ W1,
                                           const float* __restrict__ a1,
                                           float* __restrict__ WhABt,
                                           float* __restrict__ OF1,
                                           float* __restrict__ OF2){
  const int gat = blockIdx.x >> 2, rq = blockIdx.x & 3, r0 = rq*64;
  const int tid = threadIdx.x;
  const int ii = tid & 63, cq = tid >> 6;
  __shared__ float ctl[64][65];
  __shared__ float Wl[64][68];
  __shared__ float a1s[64], a2s[64];
  __shared__ float red[64][4][2];
  const float* W = gat ? W1 : W0;
  const float* aa = gat ? a1 : a0;
  for (int idx = tid; idx < 4096; idx += 256){
    int i2 = idx >> 6, k = idx & 63;
    ctl[i2][k] = ct[(r0 + i2)*64 + k];
  }
  for (int idx = tid; idx < 4096; idx += 256){
    int k = idx >> 6, c = idx & 63;
    Wl[k][c] = W[k*64 + c];
  }
  if (tid < 64){ a1s[tid] = aa[tid]; a2s[tid] = aa[64 + tid]; }
  __syncthreads();
  float acc[16];
#pragma unroll
  for (int c = 0; c < 16; ++c) acc[c] = 0.f;
#pragma unroll 2
  for (int k = 0; k < 64; ++k){
    float v = ctl[ii][k];
    const float* wr = &Wl[k][cq*16];
#pragma unroll
    for (int c = 0; c < 16; ++c) acc[c] = fmaf(v, wr[c], acc[c]);
  }
  float p1 = 0.f, p2 = 0.f;
#pragma unroll
  for (int c = 0; c < 16; ++c){
    p1 = fmaf(acc[c], a1s[cq*16 + c], p1);
    p2 = fmaf(acc[c], a2s[cq*16 + c], p2);
  }
  red[ii][cq][0] = p1; red[ii][cq][1] = p2;
  float* o = WhABt + gat*16384;
#pragma unroll
  for (int c = 0; c < 16; ++c) o[(cq*16 + c)*256 + r0 + ii] = acc[c];
  __syncthreads();
  if (cq == 0){
    OF1[gat*256 + r0 + ii] = red[ii][0][0] + red[ii][1][0] + red[ii][2][0] + red[ii][3][0];
    OF2[gat*256 + r0 + ii] = red[ii][0][1] + red[ii][1][1] + red[ii][2][1] + red[ii][3][1];
  }
}

// ---- k8b: out/out1 attention, single-pass online softmax. grid 8 ----
__global__ __launch_bounds__(256) void k8b(const float* __restrict__ WhABt,
                                           const float* __restrict__ OF1,
                                           const float* __restrict__ OF2,
                                           const unsigned* __restrict__ maskA,
                                           float* __restrict__ OUTT){
  const int gat = blockIdx.x >> 2, c0 = (blockIdx.x & 3) * 16;
  const int i = threadIdx.x;
  __shared__ float wt[4096];                   // [16 c][256 j]
  __shared__ float f2s[256];
  __shared__ float wmax[4];
  {
    const int w = i >> 6, l = i & 63;
    const float* src = WhABt + gat*16384 + c0*256 + w*1024 + l*4;
    float* dst = &wt[w*1024];
#pragma unroll
    for (int r = 0; r < 4; ++r) gl2lds16(src + r*256, dst + r*256);
  }
  const float f1  = OF1[gat*256 + i];
  const float f2v = OF2[gat*256 + i];
  f2s[i] = f2v;
  unsigned mw[8];
#pragma unroll
  for (int w = 0; w < 8; ++w) mw[w] = maskA[i*8 + w];
  float wm = f2v;
#pragma unroll
  for (int d = 1; d < 64; d <<= 1) wm = fmaxf(wm, __shfl_xor(wm, d));
  if ((i & 63) == 0) wmax[i >> 6] = wm;
  asm volatile("s_waitcnt vmcnt(0)" ::: "memory");
  __syncthreads();
  const float mb = fmaxf(fmaxf(wmax[0], wmax[1]), fmaxf(wmax[2], wmax[3]));
  const float tm = f1 + mb;
  const float m  = (tm > 0.f) ? tm : ALPHA*tm;
  float acc[16];
#pragma unroll
  for (int c = 0; c < 16; ++c) acc[c] = 0.f;
  float s = 0.f;
#pragma unroll 2
  for (int jb = 0; jb < 64; ++jb){
    const float4 f2q = *(const float4*)&f2s[jb*4];
    const unsigned mk = mw[jb >> 3];
    const int sh = (jb & 7) * 4;
    float t0 = f1 + f2q.x; t0 = (t0 > 0.f) ? t0 : ALPHA*t0;
    float t1 = f1 + f2q.y; t1 = (t1 > 0.f) ? t1 : ALPHA*t1;
    float t2 = f1 + f2q.z; t2 = (t2 > 0.f) ? t2 : ALPHA*t2;
    float t3 = f1 + f2q.w; t3 = (t3 > 0.f) ? t3 : ALPHA*t3;
    const float e0 = ((mk >> (sh+0)) & 1u) ? __expf(t0 - m) : 0.f;
    const float e1 = ((mk >> (sh+1)) & 1u) ? __expf(t1 - m) : 0.f;
    const float e2 = ((mk >> (sh+2)) & 1u) ? __expf(t2 - m) : 0.f;
    const float e3 = ((mk >> (sh+3)) & 1u) ? __expf(t3 - m) : 0.f;
    s += (e0 + e1) + (e2 + e3);
#pragma unroll
    for (int c = 0; c < 16; ++c){
      const float4 wv = *(const float4*)&wt[c*256 + jb*4];
      acc[c] = fmaf(e0, wv.x, fmaf(e1, wv.y, fmaf(e2, wv.z, fmaf(e3, wv.w, acc[c]))));
    }
  }
  const float inv = (s > 0.f) ? __builtin_amdgcn_rcpf(s) : 0.f;
#pragma unroll
  for (int c = 0; c < 16; ++c) OUTT[gat*16384 + (c0+c)*256 + i] = acc[c] * inv;
}

// ---- k8c: Wh2 (transposed) + F1B/F2B. grid 8 = 32-row chunks ----
__global__ __launch_bounds__(256) void k8c(const float* __restrict__ OUTT,
                                           const float* __restrict__ W2,
                                           const float* __restrict__ a2,
                                           float* __restrict__ Wh2,
                                           float* __restrict__ F1B,
                                           float* __restrict__ F2B){
  const int r0 = blockIdx.x * 32;
  const int tid = threadIdx.x;
  const int ii = tid & 31, cq = tid >> 5;      // 8 groups x 8 cols
  __shared__ float W2l[128][68];
  __shared__ float a1s[64], a2s[64];
  __shared__ float red[32][8][2];
  for (int idx = tid; idx < 8192; idx += 256){
    int k = idx >> 6, c = idx & 63;
    W2l[k][c] = W2[k*64 + c];
  }
  if (tid < 64){ a1s[tid] = a2[tid]; a2s[tid] = a2[64 + tid]; }
  __syncthreads();
  float acc[8];
#pragma unroll
  for (int c = 0; c < 8; ++c) acc[c] = 0.f;
#pragma unroll 2
  for (int k = 0; k < 128; ++k){
    float v = OUTT[(k >> 6)*16384 + (k & 63)*256 + r0 + ii];
    const float* wr = &W2l[k][cq*8];
#pragma unroll
    for (int c = 0; c < 8; ++c) acc[c] = fmaf(v, wr[c], acc[c]);
  }
  float p1 = 0.f, p2 = 0.f;
#pragma unroll
  for (int c = 0; c < 8; ++c){
    p1 = fmaf(acc[c], a1s[cq*8 + c], p1);
    p2 = fmaf(acc[c], a2s[cq*8 + c], p2);
  }
  red[ii][cq][0] = p1; red[ii][cq][1] = p2;
#pragma unroll
  for (int c = 0; c < 8; ++c) Wh2[(cq*8 + c)*256 + r0 + ii] = acc[c];
  __syncthreads();
  if (cq == 0){
    float s1 = 0.f, s2 = 0.f;
#pragma unroll
    for (int q = 0; q < 8; ++q){ s1 += red[ii][q][0]; s2 += red[ii][q][1]; }
    F1B[r0 + ii] = s1; F2B[r0 + ii] = s2;
  }
}

// ---- k8d: final GAT -> d_out, single-pass online softmax. grid 4 ----
__global__ __launch_bounds__(256) void k8d(const float* __restrict__ Wh2,
                                           const float* __restrict__ F1B,
                                           const float* __restrict__ F2B,
                                           const unsigned* __restrict__ maskA,
                                           float* __restrict__ dOut){
  const int c0 = blockIdx.x * 16;
  const int i = threadIdx.x;
  __shared__ float wt[4096];                   // [16 c][256 j]
  __shared__ float f2s[256];
  __shared__ float wmax[4];
  {
    const int w = i >> 6, l = i & 63;
    const float* src = Wh2 + c0*256 + w*1024 + l*4;
    float* dst = &wt[w*1024];
#pragma unroll
    for (int r = 0; r < 4; ++r) gl2lds16(src + r*256, dst + r*256);
  }
  const float f1  = F1B[i];
  const float f2v = F2B[i];
  f2s[i] = f2v;
  unsigned mw[8];
#pragma unroll
  for (int w = 0; w < 8; ++w) mw[w] = maskA[i*8 + w];
  float wm = f2v;
#pragma unroll
  for (int d = 1; d < 64; d <<= 1) wm = fmaxf(wm, __shfl_xor(wm, d));
  if ((i & 63) == 0) wmax[i >> 6] = wm;
  asm volatile("s_waitcnt vmcnt(0)" ::: "memory");
  __syncthreads();
  const float mb = fmaxf(fmaxf(wmax[0], wmax[1]), fmaxf(wmax[2], wmax[3]));
  const float tm = f1 + mb;
  const float m  = (tm > 0.f) ? tm : ALPHA*tm;
  float acc[16];
#pragma unroll
  for (int c = 0; c < 16; ++c) acc[c] = 0.f;
  float s = 0.f;
#pragma unroll 2
  for (int jb = 0; jb < 64; ++jb){
    const float4 f2q = *(const float4*)&f2s[jb*4];
    const unsigned mk = mw[jb >> 3];
    const int sh = (jb & 7) * 4;
    float t0 = f1 + f2q.x; t0 = (t0 > 0.f) ? t0 : ALPHA*t0;
    float t1 = f1 + f2q.y; t1 = (t1 > 0.f) ? t1 : ALPHA*t1;
    float t2 = f1 + f2q.z; t2 = (t2 > 0.f) ? t2 : ALPHA*t2;
    float t3 = f1 + f2q.w; t3 = (t3 > 0.f) ? t3 : ALPHA*t3;
    const float e0 = ((mk >> (sh+0)) & 1u) ? __expf(t0 - m) : 0.f;
    const float e1 = ((mk >> (sh+1)) & 1u) ? __expf(t1 - m) : 0.f;
    const float e2 = ((mk >> (sh+2)) & 1u) ? __expf(t2 - m) : 0.f;
    const float e3 = ((mk >> (sh+3)) & 1u) ? __expf(t3 - m) : 0.f;
    s += (e0 + e1) + (e2 + e3);
#pragma unroll
    for (int c = 0; c < 16; ++c){
      const float4 wv = *(const float4*)&wt[c*256 + jb*4];
      acc[c] = fmaf(e0, wv.x, fmaf(e1, wv.y, fmaf(e2, wv.z, fmaf(e3, wv.w, acc[c]))));
    }
  }
  const float inv = (s > 0.f) ? __builtin_amdgcn_rcpf(s) : 0.f;
#pragma unroll
  for (int c = 0; c < 16; ++c) dOut[i*64 + c0 + c] = acc[c] * inv;
}

extern "C" void kernel_launch(void* const* d_in, const int* in_sizes, int n_in,
                              void* d_out, int out_size, void* d_ws, size_t ws_size,
                              hipStream_t stream){
  (void)in_sizes; (void)n_in; (void)out_size; (void)ws_size;
  const float* x     = (const float*)d_in[0];
  const float* Fadj  = (const float*)d_in[1];
  const float* Tadj  = (const float*)d_in[2];
  const float* adj   = (const float*)d_in[3];
  const float* Hpre  = (const float*)d_in[4];
  const float* FattW = (const float*)d_in[5];
  const float* Fatta = (const float*)d_in[6];
  const float* TattW = (const float*)d_in[7];
  const float* Tatta = (const float*)d_in[8];
  const float* Wih0  = (const float*)d_in[9];
  const float* Whh0  = (const float*)d_in[10];
  const float* bih0  = (const float*)d_in[11];
  const float* bhh0  = (const float*)d_in[12];
  const float* Wih1  = (const float*)d_in[13];
  const float* Whh1  = (const float*)d_in[14];
  const float* bih1  = (const float*)d_in[15];
  const float* bhh1  = (const float*)d_in[16];
  const float* fc1w  = (const float*)d_in[17];
  const float* fc1b  = (const float*)d_in[18];
  const float* fc2w  = (const float*)d_in[19];
  const float* fc2b  = (const float*)d_in[20];
  const float* fc3w  = (const float*)d_in[21];
  const float* fc3b  = (const float*)d_in[22];
  const float* oW    = (const float*)d_in[23];
  const float* oa    = (const float*)d_in[24];
  const float* o1W   = (const float*)d_in[25];
  const float* o1a   = (const float*)d_in[26];
  const float* o2W   = (const float*)d_in[27];
  const float* o2a   = (const float*)d_in[28];
  float* out = (float*)d_out;

  float* ws = (float*)d_ws;
  float* R0 = ws;
  float* R1 = ws + 4194304;
  float* R2 = ws + 8388608;
  unsigned* maskT = (unsigned*)R2;             // 524288 words
  float* Tf1p = R2 + 524288;                   // 2 x 65536
  float* Tf2p = R2 + 655360;                   // 2 x 65536
  unsigned* maskA = (unsigned*)(ws + 12582912);// 2048 words
  float* WhTt = R0;
  float* WhF  = R0;
  float* TatT = R1;
  float* Fat  = R2;
  float* P0 = R2;
  float* P1 = R1;
  float* P2 = R0;
  float* ctb   = R0 + 2097152;                 // above P2's span
  float* WhABt = R1 + 16384;
  float* OF1   = R1 + 49152;
  float* OF2   = R1 + 49664;
  float* OUTT  = R1 + 50176;
  float* WH2   = R1 + 82944;
  float* F1B   = R1 + 99328;
  float* F2B   = R1 + 99584;

  k_mask<<<1024, 256, 0, stream>>>(Tadj, maskT, 16777216);
  k_mask<<<32, 256, 0, stream>>>(adj, maskA, 65536);
  k3_wht<<<512, 256, 0, stream>>>(x, TattW, Tatta, WhTt, Tf1p, Tf2p);
  k4_tat<<<512, 256, 0, stream>>>(WhTt, Tf1p, Tf2p, maskT, TatT);
  k1_whf<<<512, 256, 0, stream>>>(x, FattW, WhF);
  k2_fat<<<256, 512, 0, stream>>>(WhF, Fatta, Fadj, Fat);
  k5_gi0<<<768, 256, 0, stream>>>(Fat, TatT, x, Wih0, P0, P1, P2);
  k6_gru<<<256, 128, 0, stream>>>(P0, P1, P2, Hpre, Whh0, bih0, bhh0, Wih1, Whh1, bih1, bhh1,
                                  fc1w, fc1b, fc2w, fc2b, fc3w, fc3b, ctb, out);
  k8a<<<8, 256, 0, stream>>>(ctb, oW, oa, o1W, o1a, WhABt, OF1, OF2);
  k8b<<<8, 256, 0, stream>>>(WhABt, OF1, OF2, maskA, OUTT);
  k8c<<<8, 256, 0, stream>>>(OUTT, o2W, o2a, WH2, F1B, F2B);
  k8d<<<4, 256, 0, stream>>>(WH2, F1B, F2B, maskA, out);
}

// Round 5
// 605.192 us; speedup vs baseline: 1.4271x; 1.0434x over previous
//
#include <hip/hip_runtime.h>
#include <hip/hip_bf16.h>

__device__ __forceinline__ float sigf(float x){ return __builtin_amdgcn_rcpf(1.f+__expf(-x)); }
__device__ __forceinline__ float tanhfa(float x){
  return 1.f - 2.f*__builtin_amdgcn_rcpf(1.f + __expf(2.f*x));
}

#define ALPHA 0.2f
#define NEGV  -9e15f

// N=256 nodes, S=64 sensors, W=256 window, H=32 hidden. All fp32.

__device__ __forceinline__ void gl2lds16(const float* g, float* l){
  __builtin_amdgcn_global_load_lds(
      (const __attribute__((address_space(1))) void*)g,
      (__attribute__((address_space(3))) void*)l, 16, 0, 0);
}

// ---- k_mask: pack adjacency fp32 (0/1) -> bitmask via wave ballot ----
__global__ __launch_bounds__(256) void k_mask(const float* __restrict__ src,
                                              unsigned* __restrict__ dst, int nelem){
  const int stride = gridDim.x * blockDim.x;
  const int lane = threadIdx.x & 63;
  for (int e = blockIdx.x*blockDim.x + threadIdx.x; e < nelem; e += stride){
    unsigned long long m = __ballot(src[e] > 0.f);
    if (lane == 0)       dst[e >> 5] = (unsigned)m;
    else if (lane == 32) dst[e >> 5] = (unsigned)(m >> 32);
  }
}

// ---- k3: Wh_T + Tf1/Tf2 partials. grid 512 = n*2 + c-half ----
// NOTE: WhTt now stored i-major: WhTt[n][i][64 c] (k4 stages [j][c] tiles linearly).
__global__ __launch_bounds__(256) void k3_wht(const float* __restrict__ x,
                                              const float* __restrict__ TW,
                                              const float* __restrict__ Ta,
                                              float* __restrict__ WhTt,
                                              float* __restrict__ Tf1p,
                                              float* __restrict__ Tf2p){
  const int n = blockIdx.x >> 1, ch = blockIdx.x & 1, c0 = ch*32;
  const int tid = threadIdx.x;
  __shared__ float Wm[64][36];
  __shared__ float as1[32], as2[32];
  for (int idx = tid; idx < 2048; idx += 256){
    int k = idx >> 5, cc = idx & 31;
    Wm[k][cc] = TW[n*4096 + k*64 + c0 + cc];
  }
  if (tid < 32){ as1[tid] = Ta[n*128 + c0 + tid]; as2[tid] = Ta[n*128 + 64 + c0 + tid]; }
  __syncthreads();
  const int i = tid;
  const float* xn = x + n*16384;
  float acc[32];
#pragma unroll
  for (int c = 0; c < 32; ++c) acc[c] = 0.f;
#pragma unroll 2
  for (int k = 0; k < 64; ++k){
    float xv = xn[k*256 + i];                  // coalesced
    const float* wr = &Wm[k][0];               // broadcast b128
#pragma unroll
    for (int c = 0; c < 32; ++c) acc[c] = fmaf(xv, wr[c], acc[c]);
  }
  float f1 = 0.f, f2 = 0.f;
#pragma unroll
  for (int c = 0; c < 32; ++c){ f1 = fmaf(acc[c], as1[c], f1); f2 = fmaf(acc[c], as2[c], f2); }
  Tf1p[ch*65536 + n*256 + i] = f1;
  Tf2p[ch*65536 + n*256 + i] = f2;
  float* o = WhTt + n*16384 + i*64 + c0;       // i-major store
#pragma unroll
  for (int q = 0; q < 8; ++q)
    *(float4*)&o[4*q] = make_float4(acc[4*q], acc[4*q+1], acc[4*q+2], acc[4*q+3]);
}

// ---- k4: time-GAT attention, two-phase register-tiled PV. grid 512 = n*2+ch ----
// Phase A (thread=row i): compute 32-j P-tile once -> LDS ptb[jj][i]; s in reg.
// Phase B (thread=(iq,cq), acc[4][8]): per jj: 1 distinct b128 p-read + 2
// broadcast b128 wt-reads + 32 FMA. wt staged [j][32c] linearly via gl2lds.
__global__ __launch_bounds__(256) void k4_tat(const float* __restrict__ WhTt,
                                              const float* __restrict__ Tf1p,
                                              const float* __restrict__ Tf2p,
                                              const unsigned* __restrict__ maskT,
                                              float* __restrict__ TatT){
  const int n = blockIdx.x >> 1, ch = blockIdx.x & 1, c0 = ch*32;
  const int tid = threadIdx.x;
  __shared__ float wtL[8192];                  // [256 j][32 c], 32 KB
  __shared__ float ptb[8192];                  // [32 jj][256 i], 32 KB
  __shared__ float f2s[256];
  __shared__ float ssum[256];
  __shared__ float wmax[4];
  {                                            // stage wt: lane = (row l>>3, quad l&7)
    const int w = tid >> 6, l = tid & 63;
    const float* src = WhTt + n*16384 + (w*64 + (l>>3))*64 + c0 + (l&7)*4;
    float* dst = &wtL[w*2048];
#pragma unroll
    for (int r = 0; r < 8; ++r) gl2lds16(src + r*512, dst + r*256);
  }
  const float f1  = Tf1p[n*256 + tid] + Tf1p[65536 + n*256 + tid];
  const float f2v = Tf2p[n*256 + tid] + Tf2p[65536 + n*256 + tid];
  f2s[tid] = f2v;
  unsigned mw[8];
#pragma unroll
  for (int w = 0; w < 8; ++w) mw[w] = maskT[n*2048 + tid*8 + w];
  float wm = f2v;
#pragma unroll
  for (int d = 1; d < 64; d <<= 1) wm = fmaxf(wm, __shfl_xor(wm, d));
  if ((tid & 63) == 0) wmax[tid >> 6] = wm;
  asm volatile("s_waitcnt vmcnt(0)" ::: "memory");
  __syncthreads();
  const float mb = fmaxf(fmaxf(wmax[0], wmax[1]), fmaxf(wmax[2], wmax[3]));
  const float tm = f1 + mb;
  const float m  = (tm > 0.f) ? tm : ALPHA*tm;
  const int iq = tid & 63, cq = tid >> 6;
  float acc[4][8];
#pragma unroll
  for (int r = 0; r < 4; ++r)
#pragma unroll
    for (int c = 0; c < 8; ++c) acc[r][c] = 0.f;
  float sloc = 0.f;
  for (int jt = 0; jt < 8; ++jt){
    const int j0 = jt*32;
    // ---- phase A: P-tile row tid ----
#pragma unroll
    for (int jj = 0; jj < 32; jj += 4){
      const float4 f2q = *(const float4*)&f2s[j0 + jj];
      const unsigned mk = mw[(j0 + jj) >> 5];
      const int sh = (j0 + jj) & 31;
      float t0 = f1 + f2q.x; t0 = (t0 > 0.f) ? t0 : ALPHA*t0;
      float t1 = f1 + f2q.y; t1 = (t1 > 0.f) ? t1 : ALPHA*t1;
      float t2 = f1 + f2q.z; t2 = (t2 > 0.f) ? t2 : ALPHA*t2;
      float t3 = f1 + f2q.w; t3 = (t3 > 0.f) ? t3 : ALPHA*t3;
      const float e0 = ((mk >> (sh+0)) & 1u) ? __expf(t0 - m) : 0.f;
      const float e1 = ((mk >> (sh+1)) & 1u) ? __expf(t1 - m) : 0.f;
      const float e2 = ((mk >> (sh+2)) & 1u) ? __expf(t2 - m) : 0.f;
      const float e3 = ((mk >> (sh+3)) & 1u) ? __expf(t3 - m) : 0.f;
      sloc += (e0 + e1) + (e2 + e3);
      ptb[(jj+0)*256 + tid] = e0;
      ptb[(jj+1)*256 + tid] = e1;
      ptb[(jj+2)*256 + tid] = e2;
      ptb[(jj+3)*256 + tid] = e3;
    }
    __syncthreads();
    // ---- phase B: acc[4 rows][8 c] ----
#pragma unroll 4
    for (int jj = 0; jj < 32; ++jj){
      const float4 p4 = *(const float4*)&ptb[jj*256 + 4*iq];      // distinct lanes
      const float4 w0 = *(const float4*)&wtL[(j0+jj)*32 + cq*8];  // broadcast
      const float4 w1 = *(const float4*)&wtL[(j0+jj)*32 + cq*8 + 4];
#pragma unroll
      for (int r = 0; r < 4; ++r){
        const float pv = (r == 0) ? p4.x : (r == 1) ? p4.y : (r == 2) ? p4.z : p4.w;
        acc[r][0] = fmaf(pv, w0.x, acc[r][0]);
        acc[r][1] = fmaf(pv, w0.y, acc[r][1]);
        acc[r][2] = fmaf(pv, w0.z, acc[r][2]);
        acc[r][3] = fmaf(pv, w0.w, acc[r][3]);
        acc[r][4] = fmaf(pv, w1.x, acc[r][4]);
        acc[r][5] = fmaf(pv, w1.y, acc[r][5]);
        acc[r][6] = fmaf(pv, w1.z, acc[r][6]);
        acc[r][7] = fmaf(pv, w1.w, acc[r][7]);
      }
    }
    __syncthreads();
  }
  ssum[tid] = sloc;
  __syncthreads();
  float* o = TatT + n*16384;
#pragma unroll
  for (int r = 0; r < 4; ++r){
    const int i2 = 4*iq + r;
    const float sv = ssum[i2];
    const float inv = (sv > 0.f) ? __builtin_amdgcn_rcpf(sv) : 0.f;
#pragma unroll
    for (int cc = 0; cc < 8; ++cc)
      o[(c0 + cq*8 + cc)*256 + i2] = acc[r][cc] * inv;
  }
}

// ---- k1: Wh_F = x @ Fatt_W. grid 512 = n*2 + c-half(128), block 256 ----
__global__ __launch_bounds__(256) void k1_whf(const float* __restrict__ x,
                                              const float* __restrict__ FW,
                                              float* __restrict__ WhF){
  const int n = blockIdx.x >> 1, ch = blockIdx.x & 1, c0 = ch*128;
  const int tid = threadIdx.x;
  __shared__ float xt[16384];                  // [i][k] linear, 64 KB
  {
    const int w = tid >> 6, l = tid & 63;
    const float* xg = x + n*16384 + w*4096 + l*4;
    float* ld = &xt[w*4096];
#pragma unroll
    for (int j = 0; j < 16; ++j) gl2lds16(xg + j*256, ld + j*256);
  }
  asm volatile("s_waitcnt vmcnt(0)" ::: "memory");
  __syncthreads();
  const int cq = tid & 31, iq = tid >> 5;      // c-quad, i-group(8 rows)
  const int cc = c0 + cq*4;
  const float* Wn = FW + (size_t)n*65536 + cc;
  const float* xrow = &xt[iq*8*256];
  float acc[8][4];
#pragma unroll
  for (int i = 0; i < 8; ++i)
#pragma unroll
    for (int c = 0; c < 4; ++c) acc[i][c] = 0.f;
#pragma unroll 2
  for (int k4 = 0; k4 < 64; ++k4){
    const float4 w0 = *(const float4*)&Wn[(4*k4+0)*256];
    const float4 w1 = *(const float4*)&Wn[(4*k4+1)*256];
    const float4 w2 = *(const float4*)&Wn[(4*k4+2)*256];
    const float4 w3 = *(const float4*)&Wn[(4*k4+3)*256];
#pragma unroll
    for (int i = 0; i < 8; ++i){
      const float4 xv = *(const float4*)&xrow[i*256 + 4*k4];
      acc[i][0] = fmaf(xv.x, w0.x, acc[i][0]); acc[i][0] = fmaf(xv.y, w1.x, acc[i][0]);
      acc[i][0] = fmaf(xv.z, w2.x, acc[i][0]); acc[i][0] = fmaf(xv.w, w3.x, acc[i][0]);
      acc[i][1] = fmaf(xv.x, w0.y, acc[i][1]); acc[i][1] = fmaf(xv.y, w1.y, acc[i][1]);
      acc[i][1] = fmaf(xv.z, w2.y, acc[i][1]); acc[i][1] = fmaf(xv.w, w3.y, acc[i][1]);
      acc[i][2] = fmaf(xv.x, w0.z, acc[i][2]); acc[i][2] = fmaf(xv.y, w1.z, acc[i][2]);
      acc[i][2] = fmaf(xv.z, w2.z, acc[i][2]); acc[i][2] = fmaf(xv.w, w3.z, acc[i][2]);
      acc[i][3] = fmaf(xv.x, w0.w, acc[i][3]); acc[i][3] = fmaf(xv.y, w1.w, acc[i][3]);
      acc[i][3] = fmaf(xv.z, w2.w, acc[i][3]); acc[i][3] = fmaf(xv.w, w3.w, acc[i][3]);
    }
  }
  float* o = WhF + n*16384 + cc;
#pragma unroll
  for (int i = 0; i < 8; ++i)
    *(float4*)&o[(iq*8 + i)*256] = make_float4(acc[i][0], acc[i][1], acc[i][2], acc[i][3]);
}

// ---- k2: feature-GAT softmax + Fat = att @ Wh. grid 256, block 512 (i-split) ----
__global__ __launch_bounds__(512) void k2_fat(const float* __restrict__ WhF,
                                              const float* __restrict__ Fa,
                                              const float* __restrict__ Fadj,
                                              float* __restrict__ Fat){
  const int n = blockIdx.x, tid = threadIdx.x;
  __shared__ float attT[64][68];               // attT[j][i]
  __shared__ float f1s[64], f2s[64];
  __shared__ float part[64][8][2];
  const float* Wh = WhF + n*16384;
  { // f1/f2: thread (i=tid>>3, q=tid&7) partial over 32 cols
    int i = tid >> 3, q = tid & 7;
    const float* an = Fa + n*512;
    float p1 = 0.f, p2 = 0.f;
    for (int cc = 0; cc < 32; ++cc){
      int c2 = q*32 + cc;
      float w = Wh[i*256 + c2];
      p1 = fmaf(w, an[c2], p1);
      p2 = fmaf(w, an[256 + c2], p2);
    }
    part[i][q][0] = p1; part[i][q][1] = p2;
  }
  __syncthreads();
  if (tid < 64){
    float s1 = 0.f, s2 = 0.f;
#pragma unroll
    for (int q = 0; q < 8; ++q){ s1 += part[tid][q][0]; s2 += part[tid][q][1]; }
    f1s[tid] = s1; f2s[tid] = s2;
  }
  __syncthreads();
  if (tid < 64){                               // masked softmax row -> attT column
    const int r = tid;
    const float f1 = f1s[r];
    const float* adjr = Fadj + n*4096 + r*64;
    unsigned m0 = 0, m1 = 0;
#pragma unroll
    for (int j = 0; j < 32; ++j) if (adjr[j] > 0.f) m0 |= (1u << j);
#pragma unroll
    for (int j = 0; j < 32; ++j) if (adjr[32+j] > 0.f) m1 |= (1u << j);
    float m = -INFINITY;
#pragma unroll
    for (int j = 0; j < 64; ++j){
      float e = f1 + f2s[j]; e = (e > 0.f) ? e : ALPHA*e;
      unsigned bit = (j < 32) ? ((m0 >> j) & 1u) : ((m1 >> (j-32)) & 1u);
      e = bit ? e : NEGV;
      m = fmaxf(m, e);
    }
    float s = 0.f;
#pragma unroll
    for (int j = 0; j < 64; ++j){
      float e = f1 + f2s[j]; e = (e > 0.f) ? e : ALPHA*e;
      unsigned bit = (j < 32) ? ((m0 >> j) & 1u) : ((m1 >> (j-32)) & 1u);
      e = bit ? e : NEGV;
      s += __expf(e - m);
    }
    const float inv = 1.f / s;
#pragma unroll
    for (int j = 0; j < 64; ++j){
      float e = f1 + f2s[j]; e = (e > 0.f) ? e : ALPHA*e;
      unsigned bit = (j < 32) ? ((m0 >> j) & 1u) : ((m1 >> (j-32)) & 1u);
      e = bit ? e : NEGV;
      attT[j][r] = __expf(e - m) * inv;
    }
  }
  __syncthreads();
  const int c = tid & 255, ih = tid >> 8;      // ih: 32-row half of output
  float acc[32];
#pragma unroll
  for (int i = 0; i < 32; ++i) acc[i] = 0.f;
#pragma unroll 2
  for (int j = 0; j < 64; ++j){
    float w = Wh[j*256 + c];                   // coalesced, L2-hot
    const float* ar = &attT[j][ih*32];         // broadcast b128 (16B-aligned)
#pragma unroll
    for (int i = 0; i < 32; ++i) acc[i] = fmaf(ar[i], w, acc[i]);
  }
  float* o = Fat + n*16384;
#pragma unroll
  for (int i = 0; i < 32; ++i) o[(ih*32 + i)*256 + c] = acc[i];
}

// ---- k5: partial Gi0 = cat_seg @ Wih0_seg^T. grid 768 = s*256 + n ----
__global__ __launch_bounds__(256) void k5_gi0(const float* __restrict__ Fat,
                                              const float* __restrict__ TatT,
                                              const float* __restrict__ x,
                                              const float* __restrict__ Wih0,
                                              float* __restrict__ P0,
                                              float* __restrict__ P1,
                                              float* __restrict__ P2){
  const int n = blockIdx.x & 255, s = blockIdx.x >> 8;
  const int tid = threadIdx.x;
  const int l = tid & 63, w = tid >> 6;        // lane, wave
  const int a = tid & 31, b = tid >> 5;        // t-pair lane, gate group (0..7)
  __shared__ float cl[2][2048];                // cat tile [64 t][32 k], dbuf, 16 KB
  __shared__ float wl[2][3072];                // W tile  [96 g][32 k], dbuf, 24 KB
  const float* src = (s == 0) ? (Fat + n*16384)
                   : (s == 1) ? (TatT + n*16384)
                              : (x + n*16384);
  const float* Wseg = Wih0 + (size_t)n*73728 + s*256;
  const int lr = l >> 3, lc = l & 7, sc = lc ^ lr;       // sc: swizzled cat col4
  const float* cg0 = src + (16*w + lr)*256 + sc*4;       // cat rows 16w..16w+7
  const float* cg1 = cg0 + 8*256;                        // cat rows +8
  const float* wg0 = Wseg + (size_t)(24*w + lr)*768 + lc*4;  // W rows 24w..+7
  const float* wg1 = wg0 + (size_t)8*768;
  const float* wg2 = wg0 + (size_t)16*768;

#define K5_STAGE(BF, K0) do {                       \
    gl2lds16(cg0 + (K0), &cl[BF][512*w]);           \
    gl2lds16(cg1 + (K0), &cl[BF][512*w + 256]);     \
    gl2lds16(wg0 + (K0), &wl[BF][768*w]);           \
    gl2lds16(wg1 + (K0), &wl[BF][768*w + 256]);     \
    gl2lds16(wg2 + (K0), &wl[BF][768*w + 512]);     \
  } while (0)

  float acc[12][2];
#pragma unroll
  for (int gi = 0; gi < 12; ++gi){ acc[gi][0] = 0.f; acc[gi][1] = 0.f; }

  int bf = 0;
  K5_STAGE(0, 0);
  const int ax4 = (a & 7) << 2;
#pragma unroll 1
  for (int kt = 0; kt < 8; ++kt){
    if (kt < 7){
      K5_STAGE(bf ^ 1, (kt + 1) * 32);
      asm volatile("s_waitcnt vmcnt(5)" ::: "memory");  // current tile landed
    } else {
      asm volatile("s_waitcnt vmcnt(0)" ::: "memory");
    }
    __builtin_amdgcn_s_barrier();
    const float* clb  = &cl[bf][a*32];
    const float* clb2 = &cl[bf][(a+32)*32];
    const float* wlb  = &wl[bf][b*384];
#pragma unroll
    for (int k4 = 0; k4 < 8; ++k4){
      const int j4 = (k4 << 2) ^ ax4;                   // swizzled read col
      const float4 c0 = *(const float4*)&clb[j4];
      const float4 c1 = *(const float4*)&clb2[j4];
#pragma unroll
      for (int gi = 0; gi < 12; ++gi){
        const float4 wv = *(const float4*)&wlb[gi*32 + (k4 << 2)];
        float a0 = acc[gi][0], a1 = acc[gi][1];
        a0 = fmaf(wv.x, c0.x, a0); a1 = fmaf(wv.x, c1.x, a1);
        a0 = fmaf(wv.y, c0.y, a0); a1 = fmaf(wv.y, c1.y, a1);
        a0 = fmaf(wv.z, c0.z, a0); a1 = fmaf(wv.z, c1.z, a1);
        a0 = fmaf(wv.w, c0.w, a0); a1 = fmaf(wv.w, c1.w, a1);
        acc[gi][0] = a0; acc[gi][1] = a1;
      }
    }
    __builtin_amdgcn_s_barrier();
    bf ^= 1;
  }
#undef K5_STAGE
  float* o = (s == 0) ? (P0 + n*16384)
           : (s == 1) ? (P1 + n*16384)
                      : (P2 + n*8192);
#pragma unroll
  for (int q = 0; q < 3; ++q){
    *(float4*)&o[a*96 + b*12 + q*4] =
        make_float4(acc[4*q][0], acc[4*q+1][0], acc[4*q+2][0], acc[4*q+3][0]);
    *(float4*)&o[(a+32)*96 + b*12 + q*4] =
        make_float4(acc[4*q][1], acc[4*q+1][1], acc[4*q+2][1], acc[4*q+3][1]);
  }
}

// ---- k6: 2-layer GRU, wave-pipelined. block 128 = wave0 (layer0) + wave1
// (layer1, one step behind). Handoff via double-buffered 32-float LDS slots.
__global__ __launch_bounds__(128) void k6_gru(const float* __restrict__ G0,
                                              const float* __restrict__ G1,
                                              const float* __restrict__ G2,
                                              const float* __restrict__ Hpre,
                                              const float* __restrict__ Whh0,
                                              const float* __restrict__ bih0,
                                              const float* __restrict__ bhh0,
                                              const float* __restrict__ Wih1,
                                              const float* __restrict__ Whh1,
                                              const float* __restrict__ bih1,
                                              const float* __restrict__ bhh1,
                                              const float* __restrict__ fc1w,
                                              const float* __restrict__ fc1b,
                                              const float* __restrict__ fc2w,
                                              const float* __restrict__ fc2b,
                                              const float* __restrict__ fc3w,
                                              const float* __restrict__ fc3b,
                                              float* __restrict__ ct,
                                              float* __restrict__ dout){
  const int n = blockIdx.x, tid = threadIdx.x;
  const int wid = tid >> 6, l = tid & 63;
  const int g2 = l & 31, co = (l >> 5) * 16;
  __shared__ float ginS[6144];                 // 24 KB summed gate inputs [t][96]
  __shared__ float h0buf[2][32];
  __shared__ float h1buf[2][32];
  __shared__ float hist[64][33];
  __shared__ float Wst[32][33];
  __shared__ float b1s[32], b2s[32], w3s[32];
  // ---- stage gin = G0+G1+G2 (128 threads, 12 float4 each) ----
  {
    const float4* p0 = (const float4*)(G0 + n*16384);
    const float4* p1 = (const float4*)(G1 + n*16384);
    const float4* p2 = (const float4*)(G2 + n*8192);
    float4* gs = (float4*)ginS;
#pragma unroll
    for (int j = 0; j < 12; ++j){
      int idx = j*128 + tid;
      float4 a = p0[idx], b = p1[idx], c = p2[idx];
      gs[idx] = make_float4(a.x+b.x+c.x, a.y+b.y+c.y, a.z+b.z+c.z, a.w+b.w+c.w);
    }
  }
  // ---- FC-head staging ----
  if (tid < 32){
    b1s[tid] = fc1b[n*32 + tid];
    b2s[tid] = fc2b[n*32 + tid];
    w3s[tid] = fc3w[n*32 + tid];
  }
  for (int idx = tid; idx < 1024; idx += 128) Wst[idx>>5][idx&31] = fc1w[n*1024 + idx];
  // ---- per-wave weights (wave0: Whh0; wave1: Wih1 + Whh1) ----
  float wr_[16], wz_[16], wn_[16];
  float ur_[16], uz_[16], un_[16];
  {
    const float* WA = (wid == 0) ? (Whh0 + n*3072) : (Wih1 + n*3072);
#pragma unroll
    for (int q = 0; q < 4; ++q){
      float4 v;
      v = *(const float4*)(WA + g2*32 + co + 4*q);       wr_[4*q]=v.x; wr_[4*q+1]=v.y; wr_[4*q+2]=v.z; wr_[4*q+3]=v.w;
      v = *(const float4*)(WA + (32+g2)*32 + co + 4*q);  wz_[4*q]=v.x; wz_[4*q+1]=v.y; wz_[4*q+2]=v.z; wz_[4*q+3]=v.w;
      v = *(const float4*)(WA + (64+g2)*32 + co + 4*q);  wn_[4*q]=v.x; wn_[4*q+1]=v.y; wn_[4*q+2]=v.z; wn_[4*q+3]=v.w;
    }
    if (wid == 1){
      const float* WB = Whh1 + n*3072;
#pragma unroll
      for (int q = 0; q < 4; ++q){
        float4 v;
        v = *(const float4*)(WB + g2*32 + co + 4*q);       ur_[4*q]=v.x; ur_[4*q+1]=v.y; ur_[4*q+2]=v.z; ur_[4*q+3]=v.w;
        v = *(const float4*)(WB + (32+g2)*32 + co + 4*q);  uz_[4*q]=v.x; uz_[4*q+1]=v.y; uz_[4*q+2]=v.z; uz_[4*q+3]=v.w;
        v = *(const float4*)(WB + (64+g2)*32 + co + 4*q);  un_[4*q]=v.x; un_[4*q+1]=v.y; un_[4*q+2]=v.z; un_[4*q+3]=v.w;
      }
    }
  }
  const float* bip = (wid == 0) ? bih0 : bih1;
  const float* bhp = (wid == 0) ? bhh0 : bhh1;
  const float br = bip[n*96 + g2], bz = bip[n*96 + 32 + g2], bn = bip[n*96 + 64 + g2];
  const float cr = bhp[n*96 + g2], cz = bhp[n*96 + 32 + g2], cn = bhp[n*96 + 64 + g2];
  // ---- initial state ----
  const float* hp = (wid == 0) ? (Hpre + n*32) : (Hpre + 8192 + n*32);
  float hown = hp[g2];
  float hs[16];
#pragma unroll
  for (int q = 0; q < 4; ++q){
    float4 v = *(const float4*)&hp[co + 4*q];
    hs[4*q]=v.x; hs[4*q+1]=v.y; hs[4*q+2]=v.z; hs[4*q+3]=v.w;
  }
  // ---- pipelined slot loop: wave0 computes h0(s) for s<64; wave1 h1(s-1) ----
  for (int s = 0; s < 65; ++s){
    __syncthreads();
    if (wid == 0){
      if (s < 64){
        const float gr = ginS[s*96 + g2], gz = ginS[s*96 + 32 + g2], gn = ginS[s*96 + 64 + g2];
        if (s > 0){
#pragma unroll
          for (int q = 0; q < 4; ++q){
            float4 v = *(const float4*)&h0buf[(s-1)&1][co + 4*q];
            hs[4*q]=v.x; hs[4*q+1]=v.y; hs[4*q+2]=v.z; hs[4*q+3]=v.w;
          }
        }
        float pr = 0.f, pz = 0.f, pn = 0.f;
#pragma unroll
        for (int j = 0; j < 16; ++j){
          pr = fmaf(wr_[j], hs[j], pr);
          pz = fmaf(wz_[j], hs[j], pz);
          pn = fmaf(wn_[j], hs[j], pn);
        }
        pr += __shfl_xor(pr, 32);
        pz += __shfl_xor(pz, 32);
        pn += __shfl_xor(pn, 32);
        const float r = sigf(gr + br + pr + cr);
        const float z = sigf(gz + bz + pz + cz);
        const float nn = tanhfa(gn + bn + r*(pn + cn));
        hown = (1.f - z)*nn + z*hown;
        if (l < 32) h0buf[s & 1][g2] = hown;
      }
    } else {
      if (s >= 1){
        const int t = s - 1;
        if (s > 1){
#pragma unroll
          for (int q = 0; q < 4; ++q){
            float4 v = *(const float4*)&h1buf[(s-1)&1][co + 4*q];
            hs[4*q]=v.x; hs[4*q+1]=v.y; hs[4*q+2]=v.z; hs[4*q+3]=v.w;
          }
        }
        float hx[16];
#pragma unroll
        for (int q = 0; q < 4; ++q){
          float4 v = *(const float4*)&h0buf[(s-1)&1][co + 4*q];
          hx[4*q]=v.x; hx[4*q+1]=v.y; hx[4*q+2]=v.z; hx[4*q+3]=v.w;
        }
        float qr = 0.f, qz = 0.f, qn = 0.f, sr = 0.f, sz = 0.f, sn = 0.f;
#pragma unroll
        for (int j = 0; j < 16; ++j){
          qr = fmaf(wr_[j], hx[j], qr);  sr = fmaf(ur_[j], hs[j], sr);
          qz = fmaf(wz_[j], hx[j], qz);  sz = fmaf(uz_[j], hs[j], sz);
          qn = fmaf(wn_[j], hx[j], qn);  sn = fmaf(un_[j], hs[j], sn);
        }
        float vr = qr + sr; vr += __shfl_xor(vr, 32);
        float vz = qz + sz; vz += __shfl_xor(vz, 32);
        qn += __shfl_xor(qn, 32);
        sn += __shfl_xor(sn, 32);
        const float r1 = sigf(vr + br + cr);
        const float z1 = sigf(vz + bz + cz);
        const float n1 = tanhfa(qn + bn + r1*(sn + cn));
        hown = (1.f - z1)*n1 + z1*hown;
        if (l < 32){ h1buf[s & 1][g2] = hown; hist[t][g2] = hown; }
      }
    }
  }
  if (wid == 0 && l < 32) dout[16384 + n*32 + g2] = hown;
  if (wid == 1 && l < 32) dout[16384 + 8192 + n*32 + g2] = hown;
  __syncthreads();
  // ---- fused FC head on first 64 threads (sensor = tid) ----
  float r1a[32];
  if (tid < 64){
    float hr[32];
#pragma unroll
    for (int k = 0; k < 32; ++k) hr[k] = hist[tid][k];
#pragma unroll
    for (int k = 0; k < 32; ++k){
      float a0=0.f,a1=0.f,a2=0.f,a3=0.f;
#pragma unroll
      for (int q = 0; q < 32; q += 4){
        a0 = fmaf(hr[q],   Wst[k][q],   a0);
        a1 = fmaf(hr[q+1], Wst[k][q+1], a1);
        a2 = fmaf(hr[q+2], Wst[k][q+2], a2);
        a3 = fmaf(hr[q+3], Wst[k][q+3], a3);
      }
      float v = b1s[k] + ((a0+a1)+(a2+a3));
      r1a[k] = v > 0.f ? v : 0.f;
    }
  }
  __syncthreads();
  for (int idx = tid; idx < 1024; idx += 128) Wst[idx>>5][idx&31] = fc2w[n*1024 + idx];
  __syncthreads();
  if (tid < 64){
    float r2a[32];
#pragma unroll
    for (int k = 0; k < 32; ++k){
      float a0=0.f,a1=0.f,a2=0.f,a3=0.f;
#pragma unroll
      for (int q = 0; q < 32; q += 4){
        a0 = fmaf(r1a[q],   Wst[k][q],   a0);
        a1 = fmaf(r1a[q+1], Wst[k][q+1], a1);
        a2 = fmaf(r1a[q+2], Wst[k][q+2], a2);
        a3 = fmaf(r1a[q+3], Wst[k][q+3], a3);
      }
      float v = b2s[k] + ((a0+a1)+(a2+a3));
      r2a[k] = v > 0.f ? v : 0.f;
    }
    float v = fc3b[n];
#pragma unroll
    for (int k = 0; k < 32; ++k) v = fmaf(r2a[k], w3s[k], v);
    ct[n*64 + tid] = v;
  }
}

// ---- k8a: Wh (transposed) + f1/f2 for out & out1. grid 8 = gat*4 + row-quarter ----
__global__ __launch_bounds__(256) void k8a(const float* __restrict__ ct,
                                           const float* __restrict__ W0,
                                           const float* __restrict__ a0,
                                           const float* __restrict__ W1,
                                           const float* __restrict__ a1,
                                           float* __restrict__ WhABt,
                                           float* __restrict__ OF1,
                                           float* __restrict__ OF2){
  const int gat = blockIdx.x >> 2, rq = blockIdx.x & 3, r0 = rq*64;
  const int tid = threadIdx.x;
  const int ii = tid & 63, cq = tid >> 6;
  __shared__ float ctl[64][65];
  __shared__ float Wl[64][68];
  __shared__ float a1s[64], a2s[64];
  __shared__ float red[64][4][2];
  const float* W = gat ? W1 : W0;
  const float* aa = gat ? a1 : a0;
  for (int idx = tid; idx < 4096; idx += 256){
    int i2 = idx >> 6, k = idx & 63;
    ctl[i2][k] = ct[(r0 + i2)*64 + k];
  }
  for (int idx = tid; idx < 4096; idx += 256){
    int k = idx >> 6, c = idx & 63;
    Wl[k][c] = W[k*64 + c];
  }
  if (tid < 64){ a1s[tid] = aa[tid]; a2s[tid] = aa[64 + tid]; }
  __syncthreads();
  float acc[16];
#pragma unroll
  for (int c = 0; c < 16; ++c) acc[c] = 0.f;
#pragma unroll 2
  for (int k = 0; k < 64; ++k){
    float v = ctl[ii][k];
    const float* wr = &Wl[k][cq*16];
#pragma unroll
    for (int c = 0; c < 16; ++c) acc[c] = fmaf(v, wr[c], acc[c]);
  }
  float p1 = 0.f, p2 = 0.f;
#pragma unroll
  for (int c = 0; c < 16; ++c){
    p1 = fmaf(acc[c], a1s[cq*16 + c], p1);
    p2 = fmaf(acc[c], a2s[cq*16 + c], p2);
  }
  red[ii][cq][0] = p1; red[ii][cq][1] = p2;
  float* o = WhABt + gat*16384;
#pragma unroll
  for (int c = 0; c < 16; ++c) o[(cq*16 + c)*256 + r0 + ii] = acc[c];
  __syncthreads();
  if (cq == 0){
    OF1[gat*256 + r0 + ii] = red[ii][0][0] + red[ii][1][0] + red[ii][2][0] + red[ii][3][0];
    OF2[gat*256 + r0 + ii] = red[ii][0][1] + red[ii][1][1] + red[ii][2][1] + red[ii][3][1];
  }
}

// ---- k8b: out/out1 attention, single-pass online softmax. grid 8 ----
__global__ __launch_bounds__(256) void k8b(const float* __restrict__ WhABt,
                                           const float* __restrict__ OF1,
                                           const float* __restrict__ OF2,
                                           const unsigned* __restrict__ maskA,
                                           float* __restrict__ OUTT){
  const int gat = blockIdx.x >> 2, c0 = (blockIdx.x & 3) * 16;
  const int i = threadIdx.x;
  __shared__ float wt[4096];                   // [16 c][256 j]
  __shared__ float f2s[256];
  __shared__ float wmax[4];
  {
    const int w = i >> 6, l = i & 63;
    const float* src = WhABt + gat*16384 + c0*256 + w*1024 + l*4;
    float* dst = &wt[w*1024];
#pragma unroll
    for (int r = 0; r < 4; ++r) gl2lds16(src + r*256, dst + r*256);
  }
  const float f1  = OF1[gat*256 + i];
  const float f2v = OF2[gat*256 + i];
  f2s[i] = f2v;
  unsigned mw[8];
#pragma unroll
  for (int w = 0; w < 8; ++w) mw[w] = maskA[i*8 + w];
  float wm = f2v;
#pragma unroll
  for (int d = 1; d < 64; d <<= 1) wm = fmaxf(wm, __shfl_xor(wm, d));
  if ((i & 63) == 0) wmax[i >> 6] = wm;
  asm volatile("s_waitcnt vmcnt(0)" ::: "memory");
  __syncthreads();
  const float mb = fmaxf(fmaxf(wmax[0], wmax[1]), fmaxf(wmax[2], wmax[3]));
  const float tm = f1 + mb;
  const float m  = (tm > 0.f) ? tm : ALPHA*tm;
  float acc[16];
#pragma unroll
  for (int c = 0; c < 16; ++c) acc[c] = 0.f;
  float s = 0.f;
#pragma unroll 2
  for (int jb = 0; jb < 64; ++jb){
    const float4 f2q = *(const float4*)&f2s[jb*4];
    const unsigned mk = mw[jb >> 3];
    const int sh = (jb & 7) * 4;
    float t0 = f1 + f2q.x; t0 = (t0 > 0.f) ? t0 : ALPHA*t0;
    float t1 = f1 + f2q.y; t1 = (t1 > 0.f) ? t1 : ALPHA*t1;
    float t2 = f1 + f2q.z; t2 = (t2 > 0.f) ? t2 : ALPHA*t2;
    float t3 = f1 + f2q.w; t3 = (t3 > 0.f) ? t3 : ALPHA*t3;
    const float e0 = ((mk >> (sh+0)) & 1u) ? __expf(t0 - m) : 0.f;
    const float e1 = ((mk >> (sh+1)) & 1u) ? __expf(t1 - m) : 0.f;
    const float e2 = ((mk >> (sh+2)) & 1u) ? __expf(t2 - m) : 0.f;
    const float e3 = ((mk >> (sh+3)) & 1u) ? __expf(t3 - m) : 0.f;
    s += (e0 + e1) + (e2 + e3);
#pragma unroll
    for (int c = 0; c < 16; ++c){
      const float4 wv = *(const float4*)&wt[c*256 + jb*4];
      acc[c] = fmaf(e0, wv.x, fmaf(e1, wv.y, fmaf(e2, wv.z, fmaf(e3, wv.w, acc[c]))));
    }
  }
  const float inv = (s > 0.f) ? __builtin_amdgcn_rcpf(s) : 0.f;
#pragma unroll
  for (int c = 0; c < 16; ++c) OUTT[gat*16384 + (c0+c)*256 + i] = acc[c] * inv;
}

// ---- k8c: Wh2 (transposed) + F1B/F2B. grid 8 = 32-row chunks ----
__global__ __launch_bounds__(256) void k8c(const float* __restrict__ OUTT,
                                           const float* __restrict__ W2,
                                           const float* __restrict__ a2,
                                           float* __restrict__ Wh2,
                                           float* __restrict__ F1B,
                                           float* __restrict__ F2B){
  const int r0 = blockIdx.x * 32;
  const int tid = threadIdx.x;
  const int ii = tid & 31, cq = tid >> 5;      // 8 groups x 8 cols
  __shared__ float W2l[128][68];
  __shared__ float a1s[64], a2s[64];
  __shared__ float red[32][8][2];
  for (int idx = tid; idx < 8192; idx += 256){
    int k = idx >> 6, c = idx & 63;
    W2l[k][c] = W2[k*64 + c];
  }
  if (tid < 64){ a1s[tid] = a2[tid]; a2s[tid] = a2[64 + tid]; }
  __syncthreads();
  float acc[8];
#pragma unroll
  for (int c = 0; c < 8; ++c) acc[c] = 0.f;
#pragma unroll 2
  for (int k = 0; k < 128; ++k){
    float v = OUTT[(k >> 6)*16384 + (k & 63)*256 + r0 + ii];
    const float* wr = &W2l[k][cq*8];
#pragma unroll
    for (int c = 0; c < 8; ++c) acc[c] = fmaf(v, wr[c], acc[c]);
  }
  float p1 = 0.f, p2 = 0.f;
#pragma unroll
  for (int c = 0; c < 8; ++c){
    p1 = fmaf(acc[c], a1s[cq*8 + c], p1);
    p2 = fmaf(acc[c], a2s[cq*8 + c], p2);
  }
  red[ii][cq][0] = p1; red[ii][cq][1] = p2;
#pragma unroll
  for (int c = 0; c < 8; ++c) Wh2[(cq*8 + c)*256 + r0 + ii] = acc[c];
  __syncthreads();
  if (cq == 0){
    float s1 = 0.f, s2 = 0.f;
#pragma unroll
    for (int q = 0; q < 8; ++q){ s1 += red[ii][q][0]; s2 += red[ii][q][1]; }
    F1B[r0 + ii] = s1; F2B[r0 + ii] = s2;
  }
}

// ---- k8d: final GAT -> d_out, single-pass online softmax. grid 4 ----
__global__ __launch_bounds__(256) void k8d(const float* __restrict__ Wh2,
                                           const float* __restrict__ F1B,
                                           const float* __restrict__ F2B,
                                           const unsigned* __restrict__ maskA,
                                           float* __restrict__ dOut){
  const int c0 = blockIdx.x * 16;
  const int i = threadIdx.x;
  __shared__ float wt[4096];                   // [16 c][256 j]
  __shared__ float f2s[256];
  __shared__ float wmax[4];
  {
    const int w = i >> 6, l = i & 63;
    const float* src = Wh2 + c0*256 + w*1024 + l*4;
    float* dst = &wt[w*1024];
#pragma unroll
    for (int r = 0; r < 4; ++r) gl2lds16(src + r*256, dst + r*256);
  }
  const float f1  = F1B[i];
  const float f2v = F2B[i];
  f2s[i] = f2v;
  unsigned mw[8];
#pragma unroll
  for (int w = 0; w < 8; ++w) mw[w] = maskA[i*8 + w];
  float wm = f2v;
#pragma unroll
  for (int d = 1; d < 64; d <<= 1) wm = fmaxf(wm, __shfl_xor(wm, d));
  if ((i & 63) == 0) wmax[i >> 6] = wm;
  asm volatile("s_waitcnt vmcnt(0)" ::: "memory");
  __syncthreads();
  const float mb = fmaxf(fmaxf(wmax[0], wmax[1]), fmaxf(wmax[2], wmax[3]));
  const float tm = f1 + mb;
  const float m  = (tm > 0.f) ? tm : ALPHA*tm;
  float acc[16];
#pragma unroll
  for (int c = 0; c < 16; ++c) acc[c] = 0.f;
  float s = 0.f;
#pragma unroll 2
  for (int jb = 0; jb < 64; ++jb){
    const float4 f2q = *(const float4*)&f2s[jb*4];
    const unsigned mk = mw[jb >> 3];
    const int sh = (jb & 7) * 4;
    float t0 = f1 + f2q.x; t0 = (t0 > 0.f) ? t0 : ALPHA*t0;
    float t1 = f1 + f2q.y; t1 = (t1 > 0.f) ? t1 : ALPHA*t1;
    float t2 = f1 + f2q.z; t2 = (t2 > 0.f) ? t2 : ALPHA*t2;
    float t3 = f1 + f2q.w; t3 = (t3 > 0.f) ? t3 : ALPHA*t3;
    const float e0 = ((mk >> (sh+0)) & 1u) ? __expf(t0 - m) : 0.f;
    const float e1 = ((mk >> (sh+1)) & 1u) ? __expf(t1 - m) : 0.f;
    const float e2 = ((mk >> (sh+2)) & 1u) ? __expf(t2 - m) : 0.f;
    const float e3 = ((mk >> (sh+3)) & 1u) ? __expf(t3 - m) : 0.f;
    s += (e0 + e1) + (e2 + e3);
#pragma unroll
    for (int c = 0; c < 16; ++c){
      const float4 wv = *(const float4*)&wt[c*256 + jb*4];
      acc[c] = fmaf(e0, wv.x, fmaf(e1, wv.y, fmaf(e2, wv.z, fmaf(e3, wv.w, acc[c]))));
    }
  }
  const float inv = (s > 0.f) ? __builtin_amdgcn_rcpf(s) : 0.f;
#pragma unroll
  for (int c = 0; c < 16; ++c) dOut[i*64 + c0 + c] = acc[c] * inv;
}

extern "C" void kernel_launch(void* const* d_in, const int* in_sizes, int n_in,
                              void* d_out, int out_size, void* d_ws, size_t ws_size,
                              hipStream_t stream){
  (void)in_sizes; (void)n_in; (void)out_size; (void)ws_size;
  const float* x     = (const float*)d_in[0];
  const float* Fadj  = (const float*)d_in[1];
  const float* Tadj  = (const float*)d_in[2];
  const float* adj   = (const float*)d_in[3];
  const float* Hpre  = (const float*)d_in[4];
  const float* FattW = (const float*)d_in[5];
  const float* Fatta = (const float*)d_in[6];
  const float* TattW = (const float*)d_in[7];
  const float* Tatta = (const float*)d_in[8];
  const float* Wih0  = (const float*)d_in[9];
  const float* Whh0  = (const float*)d_in[10];
  const float* bih0  = (const float*)d_in[11];
  const float* bhh0  = (const float*)d_in[12];
  const float* Wih1  = (const float*)d_in[13];
  const float* Whh1  = (const float*)d_in[14];
  const float* bih1  = (const float*)d_in[15];
  const float* bhh1  = (const float*)d_in[16];
  const float* fc1w  = (const float*)d_in[17];
  const float* fc1b  = (const float*)d_in[18];
  const float* fc2w  = (const float*)d_in[19];
  const float* fc2b  = (const float*)d_in[20];
  const float* fc3w  = (const float*)d_in[21];
  const float* fc3b  = (const float*)d_in[22];
  const float* oW    = (const float*)d_in[23];
  const float* oa    = (const float*)d_in[24];
  const float* o1W   = (const float*)d_in[25];
  const float* o1a   = (const float*)d_in[26];
  const float* o2W   = (const float*)d_in[27];
  const float* o2a   = (const float*)d_in[28];
  float* out = (float*)d_out;

  float* ws = (float*)d_ws;
  float* R0 = ws;
  float* R1 = ws + 4194304;
  float* R2 = ws + 8388608;
  unsigned* maskT = (unsigned*)R2;             // 524288 words
  float* Tf1p = R2 + 524288;                   // 2 x 65536
  float* Tf2p = R2 + 655360;                   // 2 x 65536
  unsigned* maskA = (unsigned*)(ws + 12582912);// 2048 words
  float* WhTt = R0;
  float* WhF  = R0;
  float* TatT = R1;
  float* Fat  = R2;
  float* P0 = R2;
  float* P1 = R1;
  float* P2 = R0;
  float* ctb   = R0 + 2097152;                 // above P2's span
  float* WhABt = R1 + 16384;
  float* OF1   = R1 + 49152;
  float* OF2   = R1 + 49664;
  float* OUTT  = R1 + 50176;
  float* WH2   = R1 + 82944;
  float* F1B   = R1 + 99328;
  float* F2B   = R1 + 99584;

  k_mask<<<1024, 256, 0, stream>>>(Tadj, maskT, 16777216);
  k_mask<<<32, 256, 0, stream>>>(adj, maskA, 65536);
  k3_wht<<<512, 256, 0, stream>>>(x, TattW, Tatta, WhTt, Tf1p, Tf2p);
  k4_tat<<<512, 256, 0, stream>>>(WhTt, Tf1p, Tf2p, maskT, TatT);
  k1_whf<<<512, 256, 0, stream>>>(x, FattW, WhF);
  k2_fat<<<256, 512, 0, stream>>>(WhF, Fatta, Fadj, Fat);
  k5_gi0<<<768, 256, 0, stream>>>(Fat, TatT, x, Wih0, P0, P1, P2);
  k6_gru<<<256, 128, 0, stream>>>(P0, P1, P2, Hpre, Whh0, bih0, bhh0, Wih1, Whh1, bih1, bhh1,
                                  fc1w, fc1b, fc2w, fc2b, fc3w, fc3b, ctb, out);
  k8a<<<8, 256, 0, stream>>>(ctb, oW, oa, o1W, o1a, WhABt, OF1, OF2);
  k8b<<<8, 256, 0, stream>>>(WhABt, OF1, OF2, maskA, OUTT);
  k8c<<<8, 256, 0, stream>>>(OUTT, o2W, o2a, WH2, F1B, F2B);
  k8d<<<4, 256, 0, stream>>>(WH2, F1B, F2B, maskA, out);
}